// Round 1
// baseline (566.893 us; speedup 1.0000x reference)
//
#include <hip/hip_runtime.h>
#include <math.h>

// Problem constants (from setup_inputs): s_len=t_len=4, B=8, C=64, T=256, D=16
static constexpr int NL = 4;
static constexpr int NB = 8;
static constexpr int NC = 64;
static constexpr int NT = 256;
static constexpr int ND = 16;
static constexpr int NH = 512;
static constexpr int NF = 32;
static constexpr float REPS = 1e-6f;

// ---------------------------------------------------------------------------
// k_gram: sim[l,b,t,s] = sum_{c,d} feat[l,b,c,t,d]*feat[l,b,c,s,d]
// Both tensors in one launch: grid (64, 4); blockIdx.x = tensor*32 + l*8 + b.
// Per c: stage [256 t][16 d] block (16KB) in LDS as [dgroup][t] float4s.
// Thread tile: 4 rows x 16 cols, block covers 64 rows x 256 cols.
// ---------------------------------------------------------------------------
__global__ __launch_bounds__(256) void k_gram(const float* __restrict__ fs,
                                              const float* __restrict__ ft,
                                              float* __restrict__ sim) {
  __shared__ float4 Y4[1024];  // [dg 4][t 256]
  int lbg = blockIdx.x;        // 0..63
  int strip = blockIdx.y;      // 0..3
  int tid = threadIdx.x;
  int tx = tid & 15, ty = tid >> 4;
  const float* fbase = ((lbg < 32) ? fs : ft) + (size_t)(lbg & 31) * (NC * NT * ND);
  float* simb = sim + (size_t)lbg * (NT * NT);
  int row0 = strip * 64 + ty * 4;
  float acc[4][16];
#pragma unroll
  for (int i = 0; i < 4; i++)
#pragma unroll
    for (int j = 0; j < 16; j++) acc[i][j] = 0.f;

  for (int c = 0; c < NC; c++) {
    const float4* src = reinterpret_cast<const float4*>(fbase + (size_t)c * (NT * ND));
    __syncthreads();
#pragma unroll
    for (int q = 0; q < 4; q++) {
      int fi = q * 256 + tid;                  // float4 idx in [256t][16d] block
      float4 v = src[fi];
      Y4[(fi & 3) * 256 + (fi >> 2)] = v;      // [dgroup][t]
    }
    __syncthreads();
#pragma unroll
    for (int dg = 0; dg < 4; dg++) {
      float4 a4[4];
#pragma unroll
      for (int i = 0; i < 4; i++) a4[i] = Y4[dg * 256 + row0 + i];
#pragma unroll
      for (int j = 0; j < 16; j++) {
        float4 b4 = Y4[dg * 256 + tx + 16 * j];
#pragma unroll
        for (int i = 0; i < 4; i++)
          acc[i][j] += a4[i].x * b4.x + a4[i].y * b4.y + a4[i].z * b4.z + a4[i].w * b4.w;
      }
    }
  }
#pragma unroll
  for (int i = 0; i < 4; i++)
#pragma unroll
    for (int j = 0; j < 16; j++)
      simb[(size_t)(row0 + i) * NT + tx + 16 * j] = acc[i][j];
}

// ---------------------------------------------------------------------------
// k_gram_freq: simg[l,b,t,a] = sum_{c,d} feat[l,b,c,t,d]*feat[l,a,c,t,d]
// grid 2048 = tensor*1024 + l*256 + t; stage [8 b][1024 k] in LDS.
// ---------------------------------------------------------------------------
__global__ __launch_bounds__(256) void k_gram_freq(const float* __restrict__ fs,
                                                   const float* __restrict__ ft,
                                                   float* __restrict__ simg) {
  __shared__ float X[8 * 1032];
  int idx = blockIdx.x;  // 0..2047
  const float* feat = (idx < 1024) ? fs : ft;
  int li = (idx >> 8) & 3;
  int t = idx & 255;
  int tid = threadIdx.x;
#pragma unroll
  for (int q = 0; q < 8; q++) {
    int fi = q * 256 + tid;       // float4 idx over [8b][64c][4 d-quads]
    int b = fi >> 8;
    int rem = fi & 255;
    int c = rem >> 2, d0 = (rem & 3) * 4;
    float4 v = *reinterpret_cast<const float4*>(
        feat + (size_t)(li * 8 + b) * (NC * NT * ND) + (size_t)c * (NT * ND) + t * ND + d0);
    *reinterpret_cast<float4*>(&X[b * 1032 + c * 16 + d0]) = v;
  }
  __syncthreads();
  if (tid < 64) {
    int bb = tid >> 3, aa = tid & 7;
    float acc = 0.f;
    for (int k = 0; k < 1024; k += 4) {
      float4 xa = *reinterpret_cast<const float4*>(&X[bb * 1032 + k]);
      float4 xb = *reinterpret_cast<const float4*>(&X[aa * 1032 + k]);
      acc += xa.x * xb.x + xa.y * xb.y + xa.z * xb.z + xa.w * xb.w;
    }
    simg[(size_t)(idx >> 10) * (32 * 256 * 8) +
         ((size_t)(li * 8 + bb) * 256 + t) * 8 + aa] = acc;
  }
}

// n[lbg*256+t] = sqrt(sim[lbg][t][t]) ; grid 64, both tensors (sim_s|sim_t adjacent)
__global__ void k_diag_norm(const float* __restrict__ sim, float* __restrict__ n) {
  int lb = blockIdx.x;
  int t = threadIdx.x;
  n[lb * 256 + t] = sqrtf(sim[((size_t)lb * 256 + t) * 256 + t]);
}

// ---------------------------------------------------------------------------
// k_cos_time: per row (l,b,t): v = (sim/( (nt+e)(ns+e) ) + 1)/2, v /= rowsum,
// write 4 broadcast copies. mode 0 = student (vary j), 1 = teacher (vary i).
// ---------------------------------------------------------------------------
__global__ __launch_bounds__(256) void k_cos_time(const float* __restrict__ sim,
                                                  const float* __restrict__ n,
                                                  float* __restrict__ out, int mode) {
  __shared__ float red[4];
  __shared__ float rs;
  int bid = blockIdx.x;  // lb*256 + t  (lb within tensor, 0..31)
  int t = bid & 255;
  int lb = bid >> 8;
  int l = lb >> 3, b = lb & 7;
  int s = threadIdx.x;
  float nt = n[lb * 256 + t] + REPS;
  float ns = n[lb * 256 + s] + REPS;
  float v = (sim[(size_t)bid * 256 + s] / (nt * ns) + 1.f) * 0.5f;
  float w = v;
  for (int m = 32; m >= 1; m >>= 1) w += __shfl_xor(w, m);
  if ((threadIdx.x & 63) == 0) red[threadIdx.x >> 6] = w;
  __syncthreads();
  if (threadIdx.x == 0) rs = red[0] + red[1] + red[2] + red[3];
  __syncthreads();
  v /= rs;
  size_t inner = ((size_t)(b * 256 + t)) * 256 + s;
  if (mode == 0) {
    size_t base = (size_t)l * 4 * 524288;
#pragma unroll
    for (int j = 0; j < 4; j++) out[base + (size_t)j * 524288 + inner] = v;
  } else {
#pragma unroll
    for (int i = 0; i < 4; i++) out[((size_t)(i * 4 + l)) * 524288 + inner] = v;
  }
}

// cos_freq: per (l,b,t): row over a (8), normalize, 4 broadcast writes. grid 32.
__global__ __launch_bounds__(256) void k_cos_freq(const float* __restrict__ simg,
                                                  const float* __restrict__ n,
                                                  float* __restrict__ out, int mode) {
  int lb = blockIdx.x;
  int l = lb >> 3, b = lb & 7;
  int tid = threadIdx.x;
  int a = tid & 7;
  for (int tc = 0; tc < 8; tc++) {
    int t = tc * 32 + (tid >> 3);
    float nb = n[lb * 256 + t] + REPS;
    float na = n[(l * 8 + a) * 256 + t] + REPS;
    float v = (simg[((size_t)lb * 256 + t) * 8 + a] / (nb * na) + 1.f) * 0.5f;
    float w = v;
    for (int m = 1; m < 8; m <<= 1) w += __shfl_xor(w, m);
    v /= w;
    size_t inner = ((size_t)(b * 256 + t)) * 8 + a;
    if (mode == 0) {
#pragma unroll
      for (int j = 0; j < 4; j++) out[((size_t)(l * 4 + j)) * 16384 + inner] = v;
    } else {
#pragma unroll
      for (int i = 0; i < 4; i++) out[((size_t)(i * 4 + l)) * 16384 + inner] = v;
    }
  }
}

// ---------------------------------------------------------------------------
// Generic tiled GEMM with per-layer batching: C[l] = (A[l] @ W[l] + bias[l]),
// optional ReLU. 64x64 tile, k-tile 16, thread tile 4x4.
// ---------------------------------------------------------------------------
template <bool RELU>
__global__ __launch_bounds__(256) void k_gemm(const float* __restrict__ A,
                                              const float* __restrict__ W,
                                              const float* __restrict__ bias,
                                              float* __restrict__ Cout,
                                              int M, int N, int K) {
  __shared__ float As[16 * 68];  // [kk][m]
  __shared__ float Ws[16 * 68];  // [kk][n]
  int bx = blockIdx.y, by = blockIdx.x, l = blockIdx.z;
  int tid = threadIdx.x;
  int tx = tid & 15, ty = tid >> 4;
  const float* Ab = A + (size_t)l * M * K;
  const float* Wb = W + (size_t)l * K * N;
  float acc[4][4];
#pragma unroll
  for (int i = 0; i < 4; i++)
#pragma unroll
    for (int j = 0; j < 4; j++) acc[i][j] = 0.f;

  int arow = tid >> 2, akq = tid & 3;
  int wkk = tid >> 4, wcol = (tid & 15) * 4;
  for (int k0 = 0; k0 < K; k0 += 16) {
    __syncthreads();
    {
      float4 va = *reinterpret_cast<const float4*>(Ab + (size_t)(by * 64 + arow) * K + k0 + akq * 4);
      As[(akq * 4 + 0) * 68 + arow] = va.x;
      As[(akq * 4 + 1) * 68 + arow] = va.y;
      As[(akq * 4 + 2) * 68 + arow] = va.z;
      As[(akq * 4 + 3) * 68 + arow] = va.w;
      float4 vw = *reinterpret_cast<const float4*>(Wb + (size_t)(k0 + wkk) * N + bx * 64 + wcol);
      *reinterpret_cast<float4*>(&Ws[wkk * 68 + wcol]) = vw;
    }
    __syncthreads();
#pragma unroll
    for (int kk = 0; kk < 16; kk++) {
      float4 a4 = *reinterpret_cast<const float4*>(&As[kk * 68 + ty * 4]);
      float4 b4 = *reinterpret_cast<const float4*>(&Ws[kk * 68 + tx * 4]);
      acc[0][0] += a4.x * b4.x; acc[0][1] += a4.x * b4.y; acc[0][2] += a4.x * b4.z; acc[0][3] += a4.x * b4.w;
      acc[1][0] += a4.y * b4.x; acc[1][1] += a4.y * b4.y; acc[1][2] += a4.y * b4.z; acc[1][3] += a4.y * b4.w;
      acc[2][0] += a4.z * b4.x; acc[2][1] += a4.z * b4.y; acc[2][2] += a4.z * b4.z; acc[2][3] += a4.z * b4.w;
      acc[3][0] += a4.w * b4.x; acc[3][1] += a4.w * b4.y; acc[3][2] += a4.w * b4.z; acc[3][3] += a4.w * b4.w;
    }
  }
  int col0 = bx * 64 + tx * 4;
  float4 b4 = *reinterpret_cast<const float4*>(bias + (size_t)l * N + col0);
#pragma unroll
  for (int i = 0; i < 4; i++) {
    float4 o;
    o.x = acc[i][0] + b4.x;
    o.y = acc[i][1] + b4.y;
    o.z = acc[i][2] + b4.z;
    o.w = acc[i][3] + b4.w;
    if (RELU) {
      o.x = fmaxf(o.x, 0.f); o.y = fmaxf(o.y, 0.f);
      o.z = fmaxf(o.z, 0.f); o.w = fmaxf(o.w, 0.f);
    }
    *reinterpret_cast<float4*>(Cout + (size_t)l * M * N + (size_t)(by * 64 + ty * 4 + i) * N + col0) = o;
  }
}

// column sumsq partials over t (axis-1 l2norm denominators)
__global__ void k_colnorm_part(const float* __restrict__ Z, float* __restrict__ part) {
  int lb = blockIdx.x;  // l*8+b, 0..31
  int tq = blockIdx.y;  // 0..3
  int s = threadIdx.x;
  float acc = 0.f;
  for (int t = tq * 64; t < tq * 64 + 64; t++) {
    float v = Z[((size_t)lb * 256 + t) * 256 + s];
    acc += v * v;
  }
  part[(lb * 4 + tq) * 256 + s] = acc;
}
__global__ void k_colnorm_fin(const float* __restrict__ part, float* __restrict__ cn) {
  int lb = blockIdx.x;
  int s = threadIdx.x;
  cn[lb * 256 + s] = sqrtf(part[(lb * 4 + 0) * 256 + s] + part[(lb * 4 + 1) * 256 + s] +
                           part[(lb * 4 + 2) * 256 + s] + part[(lb * 4 + 3) * 256 + s]);
}

// ---------------------------------------------------------------------------
// Fused small (freq) MLP: [B,T,8] -> relu@w1 -> [.,32] -> @w2 -> l2norm(axis t)
// One block per (l,b) = all 256 t rows -> fully fused incl. normalization.
// ---------------------------------------------------------------------------
__global__ __launch_bounds__(256) void k_fmlp(const float* __restrict__ simg,
                                              const float* __restrict__ w1,
                                              const float* __restrict__ b1,
                                              const float* __restrict__ w2,
                                              const float* __restrict__ b2,
                                              float* __restrict__ outp) {
  __shared__ float sw1[8 * 32], sb1[32], sw2[32 * 32], sb2[32];
  __shared__ float zs[256][33];
  __shared__ float cn[32];
  int lb = blockIdx.x;  // 0..31
  int l = lb >> 3;
  int t = threadIdx.x;
  sw1[t] = w1[l * 256 + t];
  if (t < 32) { sb1[t] = b1[l * 32 + t]; sb2[t] = b2[l * 32 + t]; }
  for (int q = t; q < 1024; q += 256) sw2[q] = w2[l * 1024 + q];
  __syncthreads();
  float x[8];
#pragma unroll
  for (int a = 0; a < 8; a++) x[a] = simg[((size_t)lb * 256 + t) * 8 + a];
  float h[32];
#pragma unroll
  for (int f = 0; f < 32; f++) {
    float acc = sb1[f];
#pragma unroll
    for (int a = 0; a < 8; a++) acc += x[a] * sw1[a * 32 + f];
    h[f] = fmaxf(acc, 0.f);
  }
#pragma unroll
  for (int g = 0; g < 32; g++) {
    float acc = sb2[g];
#pragma unroll
    for (int f = 0; f < 32; f++) acc += h[f] * sw2[f * 32 + g];
    zs[t][g] = acc;
  }
  __syncthreads();
  if (t < 32) {
    float s = 0.f;
    for (int tt = 0; tt < 256; tt++) { float v = zs[tt][t]; s += v * v; }
    cn[t] = sqrtf(s);
  }
  __syncthreads();
#pragma unroll
  for (int g = 0; g < 32; g++)
    outp[((size_t)lb * 256 + t) * 32 + g] = zs[t][g] / cn[g];
}

// time attention: att[b,t,i,j] = softmax_j( sum_s (tqZ/qcn)(tkZ/kcn) )
__global__ __launch_bounds__(64) void k_att_time(const float* __restrict__ tqZ,
                                                 const float* __restrict__ tkZ,
                                                 const float* __restrict__ qcn,
                                                 const float* __restrict__ kcn,
                                                 float* __restrict__ outp) {
  int bt = blockIdx.x;  // b*256+t
  int b = bt >> 8, t = bt & 255;
  int lane = threadIdx.x;
  float acc[4][4];
#pragma unroll
  for (int i = 0; i < 4; i++)
#pragma unroll
    for (int j = 0; j < 4; j++) acc[i][j] = 0.f;
  for (int it = 0; it < 4; it++) {
    int s = lane + it * 64;
    float qv[4], kv[4];
#pragma unroll
    for (int i = 0; i < 4; i++) {
      size_t lbO = (size_t)(i * 8 + b);
      qv[i] = tqZ[(lbO * 256 + t) * 256 + s] / qcn[lbO * 256 + s];
      kv[i] = tkZ[(lbO * 256 + t) * 256 + s] / kcn[lbO * 256 + s];
    }
#pragma unroll
    for (int i = 0; i < 4; i++)
#pragma unroll
      for (int j = 0; j < 4; j++) acc[i][j] += qv[i] * kv[j];
  }
#pragma unroll
  for (int i = 0; i < 4; i++)
#pragma unroll
    for (int j = 0; j < 4; j++)
      for (int m = 32; m >= 1; m >>= 1) acc[i][j] += __shfl_xor(acc[i][j], m);
  if (lane < 16) {
    int i = lane >> 2, j = lane & 3;
    float mx = fmaxf(fmaxf(acc[i][0], acc[i][1]), fmaxf(acc[i][2], acc[i][3]));
    float sum = expf(acc[i][0] - mx) + expf(acc[i][1] - mx) + expf(acc[i][2] - mx) + expf(acc[i][3] - mx);
    outp[(size_t)bt * 16 + lane] = expf(acc[i][j] - mx) / sum;
  }
}

// freq attention: dot over f=32 of already-normalized fq/fk; 2 t per block
__global__ __launch_bounds__(64) void k_att_freq(const float* __restrict__ fq,
                                                 const float* __restrict__ fk,
                                                 float* __restrict__ outp) {
  int pair = blockIdx.x;  // b*128 + tp
  int b = pair >> 7, tp = pair & 127;
  int lane = threadIdx.x;
  int t = tp * 2 + (lane >> 5);
  int f = lane & 31;
  float qv[4], kv[4];
#pragma unroll
  for (int i = 0; i < 4; i++) {
    size_t lbO = (size_t)(i * 8 + b);
    qv[i] = fq[(lbO * 256 + t) * 32 + f];
    kv[i] = fk[(lbO * 256 + t) * 32 + f];
  }
  float acc[4][4];
#pragma unroll
  for (int i = 0; i < 4; i++)
#pragma unroll
    for (int j = 0; j < 4; j++) acc[i][j] = qv[i] * kv[j];
#pragma unroll
  for (int i = 0; i < 4; i++)
#pragma unroll
    for (int j = 0; j < 4; j++)
      for (int m = 16; m >= 1; m >>= 1) acc[i][j] += __shfl_xor(acc[i][j], m);
  int fl = lane & 31;
  if (fl < 16) {
    int i = fl >> 2, j = fl & 3;
    float mx = fmaxf(fmaxf(acc[i][0], acc[i][1]), fmaxf(acc[i][2], acc[i][3]));
    float sum = expf(acc[i][0] - mx) + expf(acc[i][1] - mx) + expf(acc[i][2] - mx) + expf(acc[i][3] - mx);
    outp[((size_t)(b * 256 + t)) * 16 + fl] = expf(acc[i][j] - mx) / sum;
  }
}

// ---------------------------------------------------------------------------
extern "C" void kernel_launch(void* const* d_in, const int* in_sizes, int n_in,
                              void* d_out, int out_size, void* d_ws, size_t ws_size,
                              hipStream_t stream) {
  (void)in_sizes; (void)n_in; (void)out_size; (void)ws_size;
  const float* feat_s = (const float*)d_in[0];
  const float* feat_t = (const float*)d_in[1];
  const float* tk_w1 = (const float*)d_in[2];
  const float* tk_b1 = (const float*)d_in[3];
  const float* tk_w2 = (const float*)d_in[4];
  const float* tk_b2 = (const float*)d_in[5];
  const float* fk_w1 = (const float*)d_in[6];
  const float* fk_b1 = (const float*)d_in[7];
  const float* fk_w2 = (const float*)d_in[8];
  const float* fk_b2 = (const float*)d_in[9];
  const float* tq_w1 = (const float*)d_in[10];
  const float* tq_b1 = (const float*)d_in[11];
  const float* tq_w2 = (const float*)d_in[12];
  const float* tq_b2 = (const float*)d_in[13];
  const float* fq_w1 = (const float*)d_in[14];
  const float* fq_b1 = (const float*)d_in[15];
  const float* fq_w2 = (const float*)d_in[16];
  const float* fq_b2 = (const float*)d_in[17];

  float* ws = (float*)d_ws;
  float* sim_s  = ws;                 // 2,097,152  (sim_t must be adjacent)
  float* sim_t  = ws + 2097152;       // 2,097,152
  float* simg_s = ws + 4194304;       //    65,536  (simg_t adjacent)
  float* simg_t = ws + 4259840;       //    65,536
  float* n_s    = ws + 4325376;       //     8,192  (n_t adjacent)
  float* n_t    = ws + 4333568;       //     8,192
  float* hbuf   = ws + 4341760;       // 4,194,304
  float* tkZ    = ws + 8536064;       // 2,097,152
  float* tqZ    = ws + 10633216;      // 2,097,152
  float* partb  = ws + 12730368;      //    32,768 (reused)
  float* tk_cn  = ws + 12763136;      //     8,192
  float* tq_cn  = ws + 12771328;      //     8,192
  float* fkb    = ws + 12779520;      //   262,144
  float* fqb    = ws + 13041664;      //   262,144  -> total 13,303,808 floats (~53.2 MB)

  float* out = (float*)d_out;
  float* out_stu_time = out;              // [4,4,8,256,256]
  float* out_stu_freq = out + 8388608;    // [4,4,8,256,8]
  float* out_tea_time = out + 8650752;    // [4,4,8,256,256]
  float* out_tea_freq = out + 17039360;   // [4,4,8,256,8]
  float* out_time_att = out + 17301504;   // [8,256,4,4]
  float* out_freq_att = out + 17334272;   // [8,256,4,4]

  // 1) gram matrices (both tensors per launch)
  hipLaunchKernelGGL(k_gram, dim3(64, 4), dim3(256), 0, stream, feat_s, feat_t, sim_s);
  hipLaunchKernelGGL(k_gram_freq, dim3(2048), dim3(256), 0, stream, feat_s, feat_t, simg_s);
  hipLaunchKernelGGL(k_diag_norm, dim3(64), dim3(256), 0, stream, sim_s, n_s);

  // 2) cosine-sim outputs (broadcast writes)
  hipLaunchKernelGGL(k_cos_time, dim3(8192), dim3(256), 0, stream, sim_s, n_s, out_stu_time, 0);
  hipLaunchKernelGGL(k_cos_time, dim3(8192), dim3(256), 0, stream, sim_t, n_t, out_tea_time, 1);
  hipLaunchKernelGGL(k_cos_freq, dim3(32), dim3(256), 0, stream, simg_s, n_s, out_stu_freq, 0);
  hipLaunchKernelGGL(k_cos_freq, dim3(32), dim3(256), 0, stream, simg_t, n_t, out_tea_freq, 1);

  // 3) frame MLPs (tk from sim_t, tq from sim_s); raw outputs + column norms
  hipLaunchKernelGGL(k_gemm<true>,  dim3(32, 8, 4), dim3(256), 0, stream, sim_t, tk_w1, tk_b1, hbuf, 2048, 512, 256);
  hipLaunchKernelGGL(k_gemm<false>, dim3(32, 4, 4), dim3(256), 0, stream, hbuf, tk_w2, tk_b2, tkZ, 2048, 256, 512);
  hipLaunchKernelGGL(k_colnorm_part, dim3(32, 4), dim3(256), 0, stream, tkZ, partb);
  hipLaunchKernelGGL(k_colnorm_fin, dim3(32), dim3(256), 0, stream, partb, tk_cn);
  hipLaunchKernelGGL(k_gemm<true>,  dim3(32, 8, 4), dim3(256), 0, stream, sim_s, tq_w1, tq_b1, hbuf, 2048, 512, 256);
  hipLaunchKernelGGL(k_gemm<false>, dim3(32, 4, 4), dim3(256), 0, stream, hbuf, tq_w2, tq_b2, tqZ, 2048, 256, 512);
  hipLaunchKernelGGL(k_colnorm_part, dim3(32, 4), dim3(256), 0, stream, tqZ, partb);
  hipLaunchKernelGGL(k_colnorm_fin, dim3(32), dim3(256), 0, stream, partb, tq_cn);

  // 4) freq MLPs (fully fused incl. axis-1 l2norm)
  hipLaunchKernelGGL(k_fmlp, dim3(32), dim3(256), 0, stream, simg_t, fk_w1, fk_b1, fk_w2, fk_b2, fkb);
  hipLaunchKernelGGL(k_fmlp, dim3(32), dim3(256), 0, stream, simg_s, fq_w1, fq_b1, fq_w2, fq_b2, fqb);

  // 5) attention outputs
  hipLaunchKernelGGL(k_att_time, dim3(2048), dim3(64), 0, stream, tqZ, tkZ, tq_cn, tk_cn, out_time_att);
  hipLaunchKernelGGL(k_att_freq, dim3(1024), dim3(64), 0, stream, fqb, fkb, out_freq_att);
}

// Round 2
// 212.113 us; speedup vs baseline: 2.6726x; 2.6726x over previous
//
#include <hip/hip_runtime.h>
#include <math.h>

// Problem constants: s_len=t_len=4, B=8, C=64, T=256, D=16, H=512, F=32
typedef _Float16 half_t;
typedef _Float16 h8 __attribute__((ext_vector_type(8)));
typedef float f4 __attribute__((ext_vector_type(4)));
static constexpr float REPS = 1e-6f;

// ---------------------------------------------------------------------------
// k_wconv: transpose+convert weights to fp16 [z][N][K] (z = tk l0-3, tq l0-3)
// and concat biases to fp32 [z][N]. blocks 0-255: W1; 256-511: W2; 512: biases.
// ---------------------------------------------------------------------------
__global__ __launch_bounds__(256) void k_wconv(const float* __restrict__ tkw1, const float* __restrict__ tqw1,
                                               const float* __restrict__ tkw2, const float* __restrict__ tqw2,
                                               const float* __restrict__ tkb1, const float* __restrict__ tqb1,
                                               const float* __restrict__ tkb2, const float* __restrict__ tqb2,
                                               half_t* __restrict__ W1t, half_t* __restrict__ W2t,
                                               float* __restrict__ Bc1, float* __restrict__ Bc2) {
  __shared__ float T[64][65];
  int bid = blockIdx.x;
  int tid = threadIdx.x;
  if (bid < 256) {  // W1: [l][256 k][512 n] -> [z][512 n][256 k]
    int z = bid >> 5, tile = bid & 31;
    int kt = tile >> 3, ntile = tile & 7;
    const float* src = (z < 4 ? tkw1 : tqw1) + (size_t)(z & 3) * 256 * 512;
#pragma unroll
    for (int q = 0; q < 16; q++) {
      int e = q * 256 + tid;
      int r = e >> 6, c = e & 63;
      T[r][c] = src[(size_t)(kt * 64 + r) * 512 + ntile * 64 + c];
    }
    __syncthreads();
#pragma unroll
    for (int q = 0; q < 16; q++) {
      int e = q * 256 + tid;
      int nn = e >> 6, kk = e & 63;
      W1t[(size_t)z * 512 * 256 + (size_t)(ntile * 64 + nn) * 256 + kt * 64 + kk] = (half_t)T[kk][nn];
    }
  } else if (bid < 512) {  // W2: [l][512 k][256 n] -> [z][256 n][512 k]
    int bb = bid - 256;
    int z = bb >> 5, tile = bb & 31;
    int kt = tile >> 2, ntile = tile & 3;
    const float* src = (z < 4 ? tkw2 : tqw2) + (size_t)(z & 3) * 512 * 256;
#pragma unroll
    for (int q = 0; q < 16; q++) {
      int e = q * 256 + tid;
      int r = e >> 6, c = e & 63;
      T[r][c] = src[(size_t)(kt * 64 + r) * 256 + ntile * 64 + c];
    }
    __syncthreads();
#pragma unroll
    for (int q = 0; q < 16; q++) {
      int e = q * 256 + tid;
      int nn = e >> 6, kk = e & 63;
      W2t[(size_t)z * 256 * 512 + (size_t)(ntile * 64 + nn) * 512 + kt * 64 + kk] = (half_t)T[kk][nn];
    }
  } else {
    for (int e = tid; e < 4096; e += 256) {
      int z = e >> 9, n = e & 511;
      Bc1[e] = (z < 4 ? tkb1 : tqb1)[(z & 3) * 512 + n];
    }
    for (int e = tid; e < 2048; e += 256) {
      int z = e >> 8, n = e & 255;
      Bc2[e] = (z < 4 ? tkb2 : tqb2)[(z & 3) * 256 + n];
    }
  }
}

// ---------------------------------------------------------------------------
// k_prep: per (tensor,l,t-pair): stage feat[l,:,c,t0..t0+1,:] (8b x 2t x 1024k)
// -> write simg (8x8 gram over k), n (sqrt diag, fp32), Xh16[t][k] fp16 panel.
// grid 1024 = tensor*512 + l*128 + tp
// ---------------------------------------------------------------------------
__global__ __launch_bounds__(256) void k_prep(const float* __restrict__ fs,
                                              const float* __restrict__ ft,
                                              float* __restrict__ simg,
                                              float* __restrict__ nrm,
                                              half_t* __restrict__ Xh) {
  __shared__ __align__(16) float X[16][1032];
  int idx = blockIdx.x;
  int tensor = idx >> 9;
  int l = (idx >> 7) & 3;
  int tp = idx & 127;
  int t0 = tp * 2;
  const float* feat = tensor ? ft : fs;
  int tid = threadIdx.x;
#pragma unroll
  for (int q = 0; q < 16; q++) {
    int f4i = q * 256 + tid;
    int pair = f4i >> 3, sub = f4i & 7;
    int b = pair >> 6, c = pair & 63;
    float4 v = *(const float4*)(feat + (size_t)((l * 8 + b) * 64 + c) * 4096 + t0 * 16 + sub * 4);
    int tt = sub >> 2, d0 = (sub & 3) * 4;
    *(float4*)(&X[b * 2 + tt][c * 16 + d0]) = v;
  }
  __syncthreads();
  {  // simg + n
    int pq = tid >> 2, ks = tid & 3;
    int b = pq >> 3, a = pq & 7;
#pragma unroll
    for (int tt = 0; tt < 2; tt++) {
      float accv = 0.f;
      const float* xa = X[b * 2 + tt];
      const float* xb = X[a * 2 + tt];
      for (int k = ks * 256; k < ks * 256 + 256; k += 4) {
        float4 va = *(const float4*)(xa + k);
        float4 vb = *(const float4*)(xb + k);
        accv += va.x * vb.x + va.y * vb.y + va.z * vb.z + va.w * vb.w;
      }
      accv += __shfl_xor(accv, 1);
      accv += __shfl_xor(accv, 2);
      if (ks == 0) {
        int lb = l * 8 + b;
        simg[(size_t)tensor * 65536 + ((size_t)lb * 256 + t0 + tt) * 8 + a] = accv;
        if (a == b) nrm[tensor * 8192 + lb * 256 + t0 + tt] = sqrtf(accv);
      }
    }
  }
  {  // Xh16 panel write: 16 rows (8b x 2t) x 1024 k fp16
    int rowi = tid >> 4;
    int b = rowi >> 1, tt = rowi & 1;
    int k0 = (tid & 15) * 64;
    size_t rowbase = ((size_t)(tensor * 32 + l * 8 + b) * 256 + t0 + tt) * 1024;
#pragma unroll
    for (int j = 0; j < 64; j += 8) {
      h8 hv;
#pragma unroll
      for (int e = 0; e < 8; e++) hv[e] = (half_t)X[b * 2 + tt][k0 + j + e];
      *(h8*)(Xh + rowbase + k0 + j) = hv;
    }
  }
}

// ---------------------------------------------------------------------------
// Unified fp16 MFMA GEMM: out = [relu](A @ Bt^T + bias), all operands row-major
// with k-contiguous rows. MODE 0: gram (A=Bt=Xh, K=1024,N=256, batch=lbg 64)
// MODE 1: h = relu(simh@W1t^T+b1)  K=256,N=512, batch z=8 (tk l0-3, tq l0-3)
// MODE 2: Z = h@W2t^T+b2           K=512,N=256, batch z=8
// 64x64 tile, BK=64, 4 waves x (32x32), XOR-swizzled LDS.
// ---------------------------------------------------------------------------
template <int MODE, bool RELU, bool BIAS>
__global__ __launch_bounds__(256) void k_mfma(const half_t* __restrict__ A,
                                              const half_t* __restrict__ Bt,
                                              const float* __restrict__ bias,
                                              half_t* __restrict__ out) {
  constexpr int K = (MODE == 0) ? 1024 : (MODE == 1) ? 256 : 512;
  constexpr int N = (MODE == 0) ? 256 : (MODE == 1) ? 512 : 256;
  __shared__ __align__(16) half_t Asm[64 * 64];
  __shared__ __align__(16) half_t Bsm[64 * 64];
  int z = blockIdx.z;
  size_t Aoff, Boff, Ooff;
  if (MODE == 0) {
    Aoff = (size_t)z * 256 * 1024; Boff = Aoff; Ooff = (size_t)z * 256 * 256;
  } else if (MODE == 1) {
    int l = z & 3, path = z >> 2;  // path0 = tk (teacher sim), path1 = tq (student)
    Aoff = ((size_t)((path == 0 ? 32 : 0) + l * 8)) * 256 * 256;
    Boff = (size_t)z * 512 * 256;
    Ooff = (size_t)z * 2048 * 512;
  } else {
    Aoff = (size_t)z * 2048 * 512; Boff = (size_t)z * 256 * 512; Ooff = (size_t)z * 2048 * 256;
  }
  const half_t* Ab = A + Aoff;
  const half_t* Bb = Bt + Boff;
  int mt = blockIdx.x, nt = blockIdx.y;
  int tid = threadIdx.x;
  int wave = tid >> 6, lane = tid & 63;
  int wm = (wave >> 1) * 32, wn = (wave & 1) * 32;
  int lr = lane & 15, lg = lane >> 4;
  f4 acc[2][2] = {};
  int r0 = tid >> 3, seg0 = tid & 7;
  int sw0 = (seg0 ^ (r0 & 7)) * 8;
  for (int kc = 0; kc < K; kc += 64) {
    h8 a0 = *(const h8*)(Ab + (size_t)(mt * 64 + r0) * K + kc + seg0 * 8);
    h8 a1 = *(const h8*)(Ab + (size_t)(mt * 64 + r0 + 32) * K + kc + seg0 * 8);
    h8 b0 = *(const h8*)(Bb + (size_t)(nt * 64 + r0) * K + kc + seg0 * 8);
    h8 b1 = *(const h8*)(Bb + (size_t)(nt * 64 + r0 + 32) * K + kc + seg0 * 8);
    __syncthreads();
    *(h8*)(Asm + r0 * 64 + sw0) = a0;
    *(h8*)(Asm + (r0 + 32) * 64 + sw0) = a1;   // (r0+32)&7 == r0&7
    *(h8*)(Bsm + r0 * 64 + sw0) = b0;
    *(h8*)(Bsm + (r0 + 32) * 64 + sw0) = b1;
    __syncthreads();
#pragma unroll
    for (int kk = 0; kk < 2; kk++) {
      h8 af[2], bf[2];
#pragma unroll
      for (int mf = 0; mf < 2; mf++) {
        int r = wm + mf * 16 + lr;
        int g = kk * 4 + lg;
        af[mf] = *(const h8*)(Asm + r * 64 + ((g ^ (r & 7)) * 8));
      }
#pragma unroll
      for (int nf = 0; nf < 2; nf++) {
        int r = wn + nf * 16 + lr;
        int g = kk * 4 + lg;
        bf[nf] = *(const h8*)(Bsm + r * 64 + ((g ^ (r & 7)) * 8));
      }
#pragma unroll
      for (int mf = 0; mf < 2; mf++)
#pragma unroll
        for (int nf = 0; nf < 2; nf++)
          acc[mf][nf] = __builtin_amdgcn_mfma_f32_16x16x32_f16(af[mf], bf[nf], acc[mf][nf], 0, 0, 0);
    }
  }
  half_t* Ob = out + Ooff;
#pragma unroll
  for (int mf = 0; mf < 2; mf++)
#pragma unroll
    for (int nf = 0; nf < 2; nf++) {
      int col = nt * 64 + wn + nf * 16 + lr;
      float bv = BIAS ? bias[z * N + col] : 0.f;
#pragma unroll
      for (int rg = 0; rg < 4; rg++) {
        int row = mt * 64 + wm + mf * 16 + lg * 4 + rg;
        float v = acc[mf][nf][rg] + bv;
        if (RELU) v = fmaxf(v, 0.f);
        Ob[(size_t)row * N + col] = (half_t)v;
      }
    }
}

// ---------------------------------------------------------------------------
// k_cos_time: per (lb,t) row: v = (simh/((nt+e)(ns+e))+1)/2, /= rowsum, 4 copies
// ---------------------------------------------------------------------------
__global__ __launch_bounds__(256) void k_cos_time(const half_t* __restrict__ simh,
                                                  const float* __restrict__ n,
                                                  float* __restrict__ out, int mode) {
  __shared__ float red[4];
  __shared__ float rs;
  int bid = blockIdx.x;  // lb*256 + t
  int t = bid & 255;
  int lb = bid >> 8;
  int l = lb >> 3, b = lb & 7;
  int s = threadIdx.x;
  float nt = n[lb * 256 + t] + REPS;
  float ns = n[lb * 256 + s] + REPS;
  float v = ((float)simh[(size_t)bid * 256 + s] / (nt * ns) + 1.f) * 0.5f;
  float w = v;
  for (int m = 32; m >= 1; m >>= 1) w += __shfl_xor(w, m);
  if ((threadIdx.x & 63) == 0) red[threadIdx.x >> 6] = w;
  __syncthreads();
  if (threadIdx.x == 0) rs = red[0] + red[1] + red[2] + red[3];
  __syncthreads();
  v /= rs;
  size_t inner = ((size_t)(b * 256 + t)) * 256 + s;
  if (mode == 0) {
    size_t base = (size_t)l * 4 * 524288;
#pragma unroll
    for (int j = 0; j < 4; j++) out[base + (size_t)j * 524288 + inner] = v;
  } else {
#pragma unroll
    for (int i = 0; i < 4; i++) out[((size_t)(i * 4 + l)) * 524288 + inner] = v;
  }
}

__global__ __launch_bounds__(256) void k_cos_freq(const float* __restrict__ simg,
                                                  const float* __restrict__ n,
                                                  float* __restrict__ out, int mode) {
  int lb = blockIdx.x;
  int l = lb >> 3, b = lb & 7;
  int tid = threadIdx.x;
  int a = tid & 7;
  for (int tc = 0; tc < 8; tc++) {
    int t = tc * 32 + (tid >> 3);
    float nb = n[lb * 256 + t] + REPS;
    float na = n[(l * 8 + a) * 256 + t] + REPS;
    float v = (simg[((size_t)lb * 256 + t) * 8 + a] / (nb * na) + 1.f) * 0.5f;
    float w = v;
    for (int m = 1; m < 8; m <<= 1) w += __shfl_xor(w, m);
    v /= w;
    size_t inner = ((size_t)(b * 256 + t)) * 8 + a;
    if (mode == 0) {
#pragma unroll
      for (int j = 0; j < 4; j++) out[((size_t)(l * 4 + j)) * 16384 + inner] = v;
    } else {
#pragma unroll
      for (int i = 0; i < 4; i++) out[((size_t)(i * 4 + l)) * 16384 + inner] = v;
    }
  }
}

// ---------------------------------------------------------------------------
// Fused freq MLP: [8 in]->relu w1->[32]->w2->[32]->l2norm over t. 1 block/(l,b)
// ---------------------------------------------------------------------------
__global__ __launch_bounds__(256) void k_fmlp(const float* __restrict__ simg,
                                              const float* __restrict__ w1,
                                              const float* __restrict__ b1,
                                              const float* __restrict__ w2,
                                              const float* __restrict__ b2,
                                              float* __restrict__ outp) {
  __shared__ float sw1[8 * 32], sb1[32], sw2[32 * 32], sb2[32];
  __shared__ float zs[256][33];
  __shared__ float pcn[8][33];
  __shared__ float cn[32];
  int lb = blockIdx.x;
  int l = lb >> 3;
  int t = threadIdx.x;
  sw1[t] = w1[l * 256 + t];
  if (t < 32) { sb1[t] = b1[l * 32 + t]; sb2[t] = b2[l * 32 + t]; }
  for (int q = t; q < 1024; q += 256) sw2[q] = w2[l * 1024 + q];
  __syncthreads();
  float x[8];
#pragma unroll
  for (int a = 0; a < 8; a++) x[a] = simg[((size_t)lb * 256 + t) * 8 + a];
  float h[32];
#pragma unroll
  for (int f = 0; f < 32; f++) {
    float acc = sb1[f];
#pragma unroll
    for (int a = 0; a < 8; a++) acc += x[a] * sw1[a * 32 + f];
    h[f] = fmaxf(acc, 0.f);
  }
#pragma unroll
  for (int g = 0; g < 32; g++) {
    float acc = sb2[g];
#pragma unroll
    for (int f = 0; f < 32; f++) acc += h[f] * sw2[f * 32 + g];
    zs[t][g] = acc;
  }
  __syncthreads();
  {
    int col = t & 31, ch = t >> 5;
    float sq = 0.f;
    for (int r = ch * 32; r < ch * 32 + 32; r++) { float v = zs[r][col]; sq += v * v; }
    pcn[ch][col] = sq;
  }
  __syncthreads();
  if (t < 32) {
    float ssum = 0.f;
#pragma unroll
    for (int c = 0; c < 8; c++) ssum += pcn[c][t];
    cn[t] = sqrtf(ssum);
  }
  __syncthreads();
#pragma unroll
  for (int g = 0; g < 32; g++)
    outp[((size_t)lb * 256 + t) * 32 + g] = zs[t][g] / cn[g];
}

// column sumsq over t (axis-1 l2norm denominators), Z fp16
__global__ void k_colnorm_part(const half_t* __restrict__ Z, float* __restrict__ part) {
  int lb = blockIdx.x;
  int tq = blockIdx.y;
  int s = threadIdx.x;
  float acc = 0.f;
  for (int t = tq * 64; t < tq * 64 + 64; t++) {
    float v = (float)Z[((size_t)lb * 256 + t) * 256 + s];
    acc += v * v;
  }
  part[(lb * 4 + tq) * 256 + s] = acc;
}
__global__ void k_colnorm_fin(const float* __restrict__ part, float* __restrict__ cn) {
  int lb = blockIdx.x;
  int s = threadIdx.x;
  cn[lb * 256 + s] = sqrtf(part[(lb * 4 + 0) * 256 + s] + part[(lb * 4 + 1) * 256 + s] +
                           part[(lb * 4 + 2) * 256 + s] + part[(lb * 4 + 3) * 256 + s]);
}

// time attention: att[b,t,i,j] = softmax_j( sum_s (Zq/qcn)(Zk/kcn) )
__global__ __launch_bounds__(64) void k_att_time(const half_t* __restrict__ Zq,
                                                 const half_t* __restrict__ Zk,
                                                 const float* __restrict__ qcn,
                                                 const float* __restrict__ kcn,
                                                 float* __restrict__ outp) {
  int bt = blockIdx.x;
  int b = bt >> 8, t = bt & 255;
  int lane = threadIdx.x;
  float acc[4][4];
#pragma unroll
  for (int i = 0; i < 4; i++)
#pragma unroll
    for (int j = 0; j < 4; j++) acc[i][j] = 0.f;
  for (int it = 0; it < 4; it++) {
    int s = lane + it * 64;
    float qv[4], kv[4];
#pragma unroll
    for (int i = 0; i < 4; i++) {
      size_t lbO = (size_t)(i * 8 + b);
      qv[i] = (float)Zq[(lbO * 256 + t) * 256 + s] / qcn[lbO * 256 + s];
      kv[i] = (float)Zk[(lbO * 256 + t) * 256 + s] / kcn[lbO * 256 + s];
    }
#pragma unroll
    for (int i = 0; i < 4; i++)
#pragma unroll
      for (int j = 0; j < 4; j++) acc[i][j] += qv[i] * kv[j];
  }
#pragma unroll
  for (int i = 0; i < 4; i++)
#pragma unroll
    for (int j = 0; j < 4; j++)
      for (int m = 32; m >= 1; m >>= 1) acc[i][j] += __shfl_xor(acc[i][j], m);
  if (lane < 16) {
    int i = lane >> 2, j = lane & 3;
    float mx = fmaxf(fmaxf(acc[i][0], acc[i][1]), fmaxf(acc[i][2], acc[i][3]));
    float sum = expf(acc[i][0] - mx) + expf(acc[i][1] - mx) + expf(acc[i][2] - mx) + expf(acc[i][3] - mx);
    outp[(size_t)bt * 16 + lane] = expf(acc[i][j] - mx) / sum;
  }
}

__global__ __launch_bounds__(64) void k_att_freq(const float* __restrict__ fq,
                                                 const float* __restrict__ fk,
                                                 float* __restrict__ outp) {
  int pair = blockIdx.x;
  int b = pair >> 7, tp = pair & 127;
  int lane = threadIdx.x;
  int t = tp * 2 + (lane >> 5);
  int f = lane & 31;
  float qv[4], kv[4];
#pragma unroll
  for (int i = 0; i < 4; i++) {
    size_t lbO = (size_t)(i * 8 + b);
    qv[i] = fq[(lbO * 256 + t) * 32 + f];
    kv[i] = fk[(lbO * 256 + t) * 32 + f];
  }
  float acc[4][4];
#pragma unroll
  for (int i = 0; i < 4; i++)
#pragma unroll
    for (int j = 0; j < 4; j++) acc[i][j] = qv[i] * kv[j];
#pragma unroll
  for (int i = 0; i < 4; i++)
#pragma unroll
    for (int j = 0; j < 4; j++)
      for (int m = 16; m >= 1; m >>= 1) acc[i][j] += __shfl_xor(acc[i][j], m);
  int fl = lane & 31;
  if (fl < 16) {
    int i = fl >> 2, j = fl & 3;
    float mx = fmaxf(fmaxf(acc[i][0], acc[i][1]), fmaxf(acc[i][2], acc[i][3]));
    float sum = expf(acc[i][0] - mx) + expf(acc[i][1] - mx) + expf(acc[i][2] - mx) + expf(acc[i][3] - mx);
    outp[((size_t)(b * 256 + t)) * 16 + fl] = expf(acc[i][j] - mx) / sum;
  }
}

// ---------------------------------------------------------------------------
extern "C" void kernel_launch(void* const* d_in, const int* in_sizes, int n_in,
                              void* d_out, int out_size, void* d_ws, size_t ws_size,
                              hipStream_t stream) {
  (void)in_sizes; (void)n_in; (void)out_size; (void)ws_size;
  const float* feat_s = (const float*)d_in[0];
  const float* feat_t = (const float*)d_in[1];
  const float* tk_w1 = (const float*)d_in[2];
  const float* tk_b1 = (const float*)d_in[3];
  const float* tk_w2 = (const float*)d_in[4];
  const float* tk_b2 = (const float*)d_in[5];
  const float* fk_w1 = (const float*)d_in[6];
  const float* fk_b1 = (const float*)d_in[7];
  const float* fk_w2 = (const float*)d_in[8];
  const float* fk_b2 = (const float*)d_in[9];
  const float* tq_w1 = (const float*)d_in[10];
  const float* tq_b1 = (const float*)d_in[11];
  const float* tq_w2 = (const float*)d_in[12];
  const float* tq_b2 = (const float*)d_in[13];
  const float* fq_w1 = (const float*)d_in[14];
  const float* fq_b1 = (const float*)d_in[15];
  const float* fq_w2 = (const float*)d_in[16];
  const float* fq_b2 = (const float*)d_in[17];

  float* ws = (float*)d_ws;
  // Xh16 region (33.5MB); after k_mfma<0> consumes it, h and Z alias into it.
  half_t* Xh   = (half_t*)ws;                 // 16.8M halves
  half_t* hbuf = (half_t*)ws;                 // 8*2048*512 halves (alias, after gram)
  half_t* Zbuf = (half_t*)(ws + 4194304);     // 8*2048*256 halves (alias, after gram)
  half_t* simh = (half_t*)(ws + 8388608);     // 64*65536 halves
  half_t* W1t  = (half_t*)(ws + 10485760);    // 8*512*256 halves
  half_t* W2t  = (half_t*)(ws + 11010048);    // 8*256*512 halves
  float* Bc1   = ws + 11534336;               // 8*512
  float* Bc2   = ws + 11538432;               // 8*256
  float* simg  = ws + 11540480;               // 2*65536
  float* nrm   = ws + 11671552;               // 2*8192
  float* partb = ws + 11687936;               // 32768
  float* tkcn  = ws + 11720704;               // 8192
  float* tqcn  = ws + 11728896;               // 8192
  float* fkb   = ws + 11737088;               // 262144
  float* fqb   = ws + 11999232;               // 262144

  float* out = (float*)d_out;
  float* out_stu_time = out;               // [4,4,8,256,256]
  float* out_stu_freq = out + 8388608;     // [4,4,8,256,8]
  float* out_tea_time = out + 8650752;     // [4,4,8,256,256]
  float* out_tea_freq = out + 17039360;    // [4,4,8,256,8]
  float* out_time_att = out + 17301504;    // [8,256,4,4]
  float* out_freq_att = out + 17334272;    // [8,256,4,4]

  // 1) weight transpose+convert, bias concat
  hipLaunchKernelGGL(k_wconv, dim3(513), dim3(256), 0, stream,
                     tk_w1, tq_w1, tk_w2, tq_w2, tk_b1, tq_b1, tk_b2, tq_b2,
                     W1t, W2t, Bc1, Bc2);
  // 2) prep: fp16 X panel + freq gram + norms
  hipLaunchKernelGGL(k_prep, dim3(1024), dim3(256), 0, stream, feat_s, feat_t, simg, nrm, Xh);
  // 3) time gram via MFMA -> simh fp16 (batch lbg 0..63: student then teacher)
  hipLaunchKernelGGL((k_mfma<0, false, false>), dim3(4, 4, 64), dim3(256), 0, stream,
                     Xh, Xh, (const float*)nullptr, simh);
  // 4) cosine outputs
  hipLaunchKernelGGL(k_cos_time, dim3(8192), dim3(256), 0, stream, simh, nrm, out_stu_time, 0);
  hipLaunchKernelGGL(k_cos_time, dim3(8192), dim3(256), 0, stream, simh + (size_t)32 * 65536,
                     nrm + 8192, out_tea_time, 1);
  hipLaunchKernelGGL(k_cos_freq, dim3(32), dim3(256), 0, stream, simg, nrm, out_stu_freq, 0);
  hipLaunchKernelGGL(k_cos_freq, dim3(32), dim3(256), 0, stream, simg + 65536, nrm + 8192, out_tea_freq, 1);
  // 5) freq MLPs
  hipLaunchKernelGGL(k_fmlp, dim3(32), dim3(256), 0, stream, simg + 65536, fk_w1, fk_b1, fk_w2, fk_b2, fkb);
  hipLaunchKernelGGL(k_fmlp, dim3(32), dim3(256), 0, stream, simg, fq_w1, fq_b1, fq_w2, fq_b2, fqb);
  // 6) frame MLPs via MFMA (h and Z alias the now-dead Xh region)
  hipLaunchKernelGGL((k_mfma<1, true, true>), dim3(32, 8, 8), dim3(256), 0, stream,
                     simh, W1t, Bc1, hbuf);
  hipLaunchKernelGGL((k_mfma<2, false, true>), dim3(32, 4, 8), dim3(256), 0, stream,
                     hbuf, W2t, Bc2, Zbuf);
  // 7) column norms (tk = path0 = Zbuf[0..], tq = path1)
  hipLaunchKernelGGL(k_colnorm_part, dim3(32, 4), dim3(256), 0, stream, Zbuf, partb);
  hipLaunchKernelGGL(k_colnorm_fin, dim3(32), dim3(256), 0, stream, partb, tkcn);
  hipLaunchKernelGGL(k_colnorm_part, dim3(32, 4), dim3(256), 0, stream, Zbuf + (size_t)4 * 2048 * 256, partb);
  hipLaunchKernelGGL(k_colnorm_fin, dim3(32), dim3(256), 0, stream, partb, tqcn);
  // 8) attention
  hipLaunchKernelGGL(k_att_time, dim3(2048), dim3(64), 0, stream,
                     Zbuf + (size_t)4 * 2048 * 256, Zbuf, tqcn, tkcn, out_time_att);
  hipLaunchKernelGGL(k_att_freq, dim3(1024), dim3(64), 0, stream, fqb, fkb, out_freq_att);
}

// Round 3
// 210.289 us; speedup vs baseline: 2.6958x; 1.0087x over previous
//
#include <hip/hip_runtime.h>
#include <math.h>

// Problem constants: s_len=t_len=4, B=8, C=64, T=256, D=16, H=512, F=32
typedef _Float16 half_t;
typedef _Float16 h4 __attribute__((ext_vector_type(4)));
typedef _Float16 h8 __attribute__((ext_vector_type(8)));
typedef float f4 __attribute__((ext_vector_type(4)));
static constexpr float REPS = 1e-6f;

// ---------------------------------------------------------------------------
// k_wconv: transpose+convert weights to fp16 [z][N][K] (z = tk l0-3, tq l4-7)
// and concat biases to fp32 [z][N]. blocks 0-255: W1; 256-511: W2; 512: biases.
// ---------------------------------------------------------------------------
__global__ __launch_bounds__(256) void k_wconv(const float* __restrict__ tkw1, const float* __restrict__ tqw1,
                                               const float* __restrict__ tkw2, const float* __restrict__ tqw2,
                                               const float* __restrict__ tkb1, const float* __restrict__ tqb1,
                                               const float* __restrict__ tkb2, const float* __restrict__ tqb2,
                                               half_t* __restrict__ W1t, half_t* __restrict__ W2t,
                                               float* __restrict__ Bc1, float* __restrict__ Bc2) {
  __shared__ float T[64][65];
  int bid = blockIdx.x;
  int tid = threadIdx.x;
  if (bid < 256) {  // W1: [l][256 k][512 n] -> [z][512 n][256 k]
    int z = bid >> 5, tile = bid & 31;
    int kt = tile >> 3, ntile = tile & 7;
    const float* src = (z < 4 ? tkw1 : tqw1) + (size_t)(z & 3) * 256 * 512;
#pragma unroll
    for (int q = 0; q < 16; q++) {
      int e = q * 256 + tid;
      int r = e >> 6, c = e & 63;
      T[r][c] = src[(size_t)(kt * 64 + r) * 512 + ntile * 64 + c];
    }
    __syncthreads();
#pragma unroll
    for (int q = 0; q < 16; q++) {
      int e = q * 256 + tid;
      int nn = e >> 6, kk = e & 63;
      W1t[(size_t)z * 512 * 256 + (size_t)(ntile * 64 + nn) * 256 + kt * 64 + kk] = (half_t)T[kk][nn];
    }
  } else if (bid < 512) {  // W2: [l][512 k][256 n] -> [z][256 n][512 k]
    int bb = bid - 256;
    int z = bb >> 5, tile = bb & 31;
    int kt = tile >> 2, ntile = tile & 3;
    const float* src = (z < 4 ? tkw2 : tqw2) + (size_t)(z & 3) * 512 * 256;
#pragma unroll
    for (int q = 0; q < 16; q++) {
      int e = q * 256 + tid;
      int r = e >> 6, c = e & 63;
      T[r][c] = src[(size_t)(kt * 64 + r) * 256 + ntile * 64 + c];
    }
    __syncthreads();
#pragma unroll
    for (int q = 0; q < 16; q++) {
      int e = q * 256 + tid;
      int nn = e >> 6, kk = e & 63;
      W2t[(size_t)z * 256 * 512 + (size_t)(ntile * 64 + nn) * 512 + kt * 64 + kk] = (half_t)T[kk][nn];
    }
  } else {
    for (int e = tid; e < 4096; e += 256) {
      int z = e >> 9, n = e & 511;
      Bc1[e] = (z < 4 ? tkb1 : tqb1)[(z & 3) * 512 + n];
    }
    for (int e = tid; e < 2048; e += 256) {
      int z = e >> 8, n = e & 255;
      Bc2[e] = (z < 4 ? tkb2 : tqb2)[(z & 3) * 256 + n];
    }
  }
}

// ---------------------------------------------------------------------------
// k_x2h: LDS-free transpose/convert feat [l,b,c,t,d] -> Xh fp16 [row][k=c*16+d]
// + fp32 sumsq per row -> nrm. Thread owns one t; lane quad covers 16 d's.
// Each instruction reads one contiguous 4KB slab (64t x 16d for one c).
// grid 256 = tensor*128 + l*32 + b*4 + tc
// ---------------------------------------------------------------------------
__global__ __launch_bounds__(256) void k_x2h(const float* __restrict__ fs,
                                             const float* __restrict__ ft,
                                             half_t* __restrict__ Xh,
                                             float* __restrict__ nrm) {
  int bid = blockIdx.x;
  int tensor = bid >> 7;
  int l = (bid >> 5) & 3;
  int b = (bid >> 2) & 7;
  int tc = bid & 3;
  int tid = threadIdx.x;
  int tl = tid >> 2;           // 0..63
  int d0 = (tid & 3) * 4;
  int t = tc * 64 + tl;
  const float* base = (tensor ? ft : fs) + (size_t)((l * 8 + b) * 64) * 4096 + t * 16 + d0;
  size_t row = (size_t)(tensor * 32 + l * 8 + b) * 256 + t;
  half_t* xrow = Xh + row * 1024 + d0;
  float acc = 0.f;
#pragma unroll 8
  for (int c = 0; c < 64; c++) {
    float4 v = *(const float4*)(base + (size_t)c * 4096);
    acc += v.x * v.x + v.y * v.y + v.z * v.z + v.w * v.w;
    h4 hv;
    hv[0] = (half_t)v.x; hv[1] = (half_t)v.y; hv[2] = (half_t)v.z; hv[3] = (half_t)v.w;
    *(h4*)(xrow + c * 16) = hv;
  }
  acc += __shfl_xor(acc, 1);
  acc += __shfl_xor(acc, 2);
  if ((tid & 3) == 0) nrm[row] = sqrtf(acc);
}

// ---------------------------------------------------------------------------
// k_simg: freq gram from fp16 panel. Block = (tensor,l,t): 8x8 pairs x 4 k-slices.
// grid 2048 = tensor*1024 + l*256 + t
// ---------------------------------------------------------------------------
__global__ __launch_bounds__(256) void k_simg(const half_t* __restrict__ Xh,
                                              float* __restrict__ simg) {
  int bid = blockIdx.x;
  int tensor = bid >> 10;
  int l = (bid >> 8) & 3;
  int t = bid & 255;
  int tid = threadIdx.x;
  int p = tid >> 2, ks = tid & 3;
  int bb = p >> 3, aa = p & 7;
  const half_t* xa = Xh + ((size_t)(tensor * 32 + l * 8 + bb) * 256 + t) * 1024 + ks * 256;
  const half_t* xb = Xh + ((size_t)(tensor * 32 + l * 8 + aa) * 256 + t) * 1024 + ks * 256;
  float acc = 0.f;
#pragma unroll 4
  for (int k = 0; k < 256; k += 8) {
    h8 va = *(const h8*)(xa + k);
    h8 vb = *(const h8*)(xb + k);
#pragma unroll
    for (int e = 0; e < 8; e++) acc += (float)va[e] * (float)vb[e];
  }
  acc += __shfl_xor(acc, 1);
  acc += __shfl_xor(acc, 2);
  if (ks == 0)
    simg[(size_t)tensor * 65536 + ((size_t)(l * 8 + bb) * 256 + t) * 8 + aa] = acc;
}

// ---------------------------------------------------------------------------
// Unified fp16 MFMA GEMM: out = [relu](A @ Bt^T + bias). MODE 0: gram
// (K=1024,N=256,batch 64); MODE 1: h=relu(simh@W1t^T+b1); MODE 2: Z=h@W2t^T+b2.
// 64x64 tile, BK=64, 4 waves x (32x32), XOR-swizzled LDS.
// ---------------------------------------------------------------------------
template <int MODE, bool RELU, bool BIAS>
__global__ __launch_bounds__(256) void k_mfma(const half_t* __restrict__ A,
                                              const half_t* __restrict__ Bt,
                                              const float* __restrict__ bias,
                                              half_t* __restrict__ out) {
  constexpr int K = (MODE == 0) ? 1024 : (MODE == 1) ? 256 : 512;
  constexpr int N = (MODE == 0) ? 256 : (MODE == 1) ? 512 : 256;
  __shared__ __align__(16) half_t Asm[64 * 64];
  __shared__ __align__(16) half_t Bsm[64 * 64];
  int z = blockIdx.z;
  size_t Aoff, Boff, Ooff;
  if (MODE == 0) {
    Aoff = (size_t)z * 256 * 1024; Boff = Aoff; Ooff = (size_t)z * 256 * 256;
  } else if (MODE == 1) {
    int l = z & 3, path = z >> 2;  // path0 = tk (teacher sim), path1 = tq (student)
    Aoff = ((size_t)((path == 0 ? 32 : 0) + l * 8)) * 256 * 256;
    Boff = (size_t)z * 512 * 256;
    Ooff = (size_t)z * 2048 * 512;
  } else {
    Aoff = (size_t)z * 2048 * 512; Boff = (size_t)z * 256 * 512; Ooff = (size_t)z * 2048 * 256;
  }
  const half_t* Ab = A + Aoff;
  const half_t* Bb = Bt + Boff;
  int mt = blockIdx.x, nt = blockIdx.y;
  int tid = threadIdx.x;
  int wave = tid >> 6, lane = tid & 63;
  int wm = (wave >> 1) * 32, wn = (wave & 1) * 32;
  int lr = lane & 15, lg = lane >> 4;
  f4 acc[2][2] = {};
  int r0 = tid >> 3, seg0 = tid & 7;
  int sw0 = (seg0 ^ (r0 & 7)) * 8;
  for (int kc = 0; kc < K; kc += 64) {
    h8 a0 = *(const h8*)(Ab + (size_t)(mt * 64 + r0) * K + kc + seg0 * 8);
    h8 a1 = *(const h8*)(Ab + (size_t)(mt * 64 + r0 + 32) * K + kc + seg0 * 8);
    h8 b0 = *(const h8*)(Bb + (size_t)(nt * 64 + r0) * K + kc + seg0 * 8);
    h8 b1 = *(const h8*)(Bb + (size_t)(nt * 64 + r0 + 32) * K + kc + seg0 * 8);
    __syncthreads();
    *(h8*)(Asm + r0 * 64 + sw0) = a0;
    *(h8*)(Asm + (r0 + 32) * 64 + sw0) = a1;
    *(h8*)(Bsm + r0 * 64 + sw0) = b0;
    *(h8*)(Bsm + (r0 + 32) * 64 + sw0) = b1;
    __syncthreads();
#pragma unroll
    for (int kk = 0; kk < 2; kk++) {
      h8 af[2], bf[2];
#pragma unroll
      for (int mf = 0; mf < 2; mf++) {
        int r = wm + mf * 16 + lr;
        int g = kk * 4 + lg;
        af[mf] = *(const h8*)(Asm + r * 64 + ((g ^ (r & 7)) * 8));
      }
#pragma unroll
      for (int nf = 0; nf < 2; nf++) {
        int r = wn + nf * 16 + lr;
        int g = kk * 4 + lg;
        bf[nf] = *(const h8*)(Bsm + r * 64 + ((g ^ (r & 7)) * 8));
      }
#pragma unroll
      for (int mf = 0; mf < 2; mf++)
#pragma unroll
        for (int nf = 0; nf < 2; nf++)
          acc[mf][nf] = __builtin_amdgcn_mfma_f32_16x16x32_f16(af[mf], bf[nf], acc[mf][nf], 0, 0, 0);
    }
  }
  half_t* Ob = out + Ooff;
#pragma unroll
  for (int mf = 0; mf < 2; mf++)
#pragma unroll
    for (int nf = 0; nf < 2; nf++) {
      int col = nt * 64 + wn + nf * 16 + lr;
      float bv = BIAS ? bias[z * N + col] : 0.f;
#pragma unroll
      for (int rg = 0; rg < 4; rg++) {
        int row = mt * 64 + wm + mf * 16 + lg * 4 + rg;
        float v = acc[mf][nf][rg] + bv;
        if (RELU) v = fmaxf(v, 0.f);
        Ob[(size_t)row * N + col] = (half_t)v;
      }
    }
}

// ---------------------------------------------------------------------------
// k_cos_time2: both tensors in one launch. grid 16384 (tensor = bid>>13).
// ---------------------------------------------------------------------------
__global__ __launch_bounds__(256) void k_cos_time2(const half_t* __restrict__ simh,
                                                   const float* __restrict__ n,
                                                   float* __restrict__ out_stu,
                                                   float* __restrict__ out_tea) {
  __shared__ float red[4];
  __shared__ float rs;
  int tensor = blockIdx.x >> 13;
  int bid = blockIdx.x & 8191;  // lb*256 + t
  const half_t* sh = simh + (size_t)tensor * 2097152;
  const float* nb2 = n + tensor * 8192;
  float* out = tensor ? out_tea : out_stu;
  int t = bid & 255;
  int lb = bid >> 8;
  int l = lb >> 3, b = lb & 7;
  int s = threadIdx.x;
  float nt = nb2[lb * 256 + t] + REPS;
  float ns = nb2[lb * 256 + s] + REPS;
  float v = ((float)sh[(size_t)bid * 256 + s] / (nt * ns) + 1.f) * 0.5f;
  float w = v;
  for (int m = 32; m >= 1; m >>= 1) w += __shfl_xor(w, m);
  if ((threadIdx.x & 63) == 0) red[threadIdx.x >> 6] = w;
  __syncthreads();
  if (threadIdx.x == 0) rs = red[0] + red[1] + red[2] + red[3];
  __syncthreads();
  v /= rs;
  size_t inner = ((size_t)(b * 256 + t)) * 256 + s;
  if (tensor == 0) {
    size_t base = (size_t)l * 4 * 524288;
#pragma unroll
    for (int j = 0; j < 4; j++) out[base + (size_t)j * 524288 + inner] = v;
  } else {
#pragma unroll
    for (int i = 0; i < 4; i++) out[((size_t)(i * 4 + l)) * 524288 + inner] = v;
  }
}

__global__ __launch_bounds__(256) void k_cos_freq2(const float* __restrict__ simg,
                                                   const float* __restrict__ n,
                                                   float* __restrict__ out_stu,
                                                   float* __restrict__ out_tea) {
  int tensor = blockIdx.x >> 5;
  int lb = blockIdx.x & 31;
  const float* sg = simg + (size_t)tensor * 65536;
  const float* nb2 = n + tensor * 8192;
  float* out = tensor ? out_tea : out_stu;
  int l = lb >> 3, b = lb & 7;
  int tid = threadIdx.x;
  int a = tid & 7;
  for (int tc = 0; tc < 8; tc++) {
    int t = tc * 32 + (tid >> 3);
    float nb = nb2[lb * 256 + t] + REPS;
    float na = nb2[(l * 8 + a) * 256 + t] + REPS;
    float v = (sg[((size_t)lb * 256 + t) * 8 + a] / (nb * na) + 1.f) * 0.5f;
    float w = v;
    for (int m = 1; m < 8; m <<= 1) w += __shfl_xor(w, m);
    v /= w;
    size_t inner = ((size_t)(b * 256 + t)) * 8 + a;
    if (tensor == 0) {
#pragma unroll
      for (int j = 0; j < 4; j++) out[((size_t)(l * 4 + j)) * 16384 + inner] = v;
    } else {
#pragma unroll
      for (int i = 0; i < 4; i++) out[((size_t)(i * 4 + l)) * 16384 + inner] = v;
    }
  }
}

// ---------------------------------------------------------------------------
// Fused freq MLP, both tensors: tensor0 = student->fq weights, 1 = teacher->fk.
// ---------------------------------------------------------------------------
__global__ __launch_bounds__(256) void k_fmlp2(const float* __restrict__ simg,
                                               const float* __restrict__ qw1, const float* __restrict__ qb1,
                                               const float* __restrict__ qw2, const float* __restrict__ qb2,
                                               const float* __restrict__ kw1, const float* __restrict__ kb1,
                                               const float* __restrict__ kw2, const float* __restrict__ kb2,
                                               float* __restrict__ qout, float* __restrict__ kout) {
  __shared__ float sw1[8 * 32], sb1[32], sw2[32 * 32], sb2[32];
  __shared__ float zs[256][33];
  __shared__ float pcn[8][33];
  __shared__ float cn[32];
  int tensor = blockIdx.x >> 5;
  int lb = blockIdx.x & 31;
  int l = lb >> 3;
  const float* w1 = tensor ? kw1 : qw1;
  const float* b1 = tensor ? kb1 : qb1;
  const float* w2 = tensor ? kw2 : qw2;
  const float* b2 = tensor ? kb2 : qb2;
  const float* sg = simg + (size_t)tensor * 65536;
  float* outp = tensor ? kout : qout;
  int t = threadIdx.x;
  sw1[t] = w1[l * 256 + t];
  if (t < 32) { sb1[t] = b1[l * 32 + t]; sb2[t] = b2[l * 32 + t]; }
  for (int q = t; q < 1024; q += 256) sw2[q] = w2[l * 1024 + q];
  __syncthreads();
  float x[8];
#pragma unroll
  for (int a = 0; a < 8; a++) x[a] = sg[((size_t)lb * 256 + t) * 8 + a];
  float h[32];
#pragma unroll
  for (int f = 0; f < 32; f++) {
    float acc = sb1[f];
#pragma unroll
    for (int a = 0; a < 8; a++) acc += x[a] * sw1[a * 32 + f];
    h[f] = fmaxf(acc, 0.f);
  }
#pragma unroll
  for (int g = 0; g < 32; g++) {
    float acc = sb2[g];
#pragma unroll
    for (int f = 0; f < 32; f++) acc += h[f] * sw2[f * 32 + g];
    zs[t][g] = acc;
  }
  __syncthreads();
  {
    int col = t & 31, ch = t >> 5;
    float sq = 0.f;
    for (int r = ch * 32; r < ch * 32 + 32; r++) { float v = zs[r][col]; sq += v * v; }
    pcn[ch][col] = sq;
  }
  __syncthreads();
  if (t < 32) {
    float ssum = 0.f;
#pragma unroll
    for (int c = 0; c < 8; c++) ssum += pcn[c][t];
    cn[t] = sqrtf(ssum);
  }
  __syncthreads();
#pragma unroll
  for (int g = 0; g < 32; g++)
    outp[((size_t)lb * 256 + t) * 32 + g] = zs[t][g] / cn[g];
}

// Fused column sumsq + sqrt over t for both paths; grid 64 (lb<32 = tk, else tq)
__global__ __launch_bounds__(256) void k_colnorm(const half_t* __restrict__ Z, float* __restrict__ cn) {
  int lbg = blockIdx.x;
  int path = lbg >> 5, lb = lbg & 31;
  const half_t* Zb = Z + (size_t)path * 4 * 2048 * 256;
  int s = threadIdx.x;
  float acc = 0.f;
  for (int t = 0; t < 256; t++) {
    float v = (float)Zb[((size_t)lb * 256 + t) * 256 + s];
    acc += v * v;
  }
  cn[lbg * 256 + s] = sqrtf(acc);
}

// time attention: att[b,t,i,j] = softmax_j( sum_s (Zq/qcn)(Zk/kcn) )
__global__ __launch_bounds__(64) void k_att_time(const half_t* __restrict__ Zq,
                                                 const half_t* __restrict__ Zk,
                                                 const float* __restrict__ qcn,
                                                 const float* __restrict__ kcn,
                                                 float* __restrict__ outp) {
  int bt = blockIdx.x;
  int b = bt >> 8, t = bt & 255;
  int lane = threadIdx.x;
  float acc[4][4];
#pragma unroll
  for (int i = 0; i < 4; i++)
#pragma unroll
    for (int j = 0; j < 4; j++) acc[i][j] = 0.f;
  for (int it = 0; it < 4; it++) {
    int s = lane + it * 64;
    float qv[4], kv[4];
#pragma unroll
    for (int i = 0; i < 4; i++) {
      size_t lbO = (size_t)(i * 8 + b);
      qv[i] = (float)Zq[(lbO * 256 + t) * 256 + s] / qcn[lbO * 256 + s];
      kv[i] = (float)Zk[(lbO * 256 + t) * 256 + s] / kcn[lbO * 256 + s];
    }
#pragma unroll
    for (int i = 0; i < 4; i++)
#pragma unroll
      for (int j = 0; j < 4; j++) acc[i][j] += qv[i] * kv[j];
  }
#pragma unroll
  for (int i = 0; i < 4; i++)
#pragma unroll
    for (int j = 0; j < 4; j++)
      for (int m = 32; m >= 1; m >>= 1) acc[i][j] += __shfl_xor(acc[i][j], m);
  if (lane < 16) {
    int i = lane >> 2, j = lane & 3;
    float mx = fmaxf(fmaxf(acc[i][0], acc[i][1]), fmaxf(acc[i][2], acc[i][3]));
    float sum = expf(acc[i][0] - mx) + expf(acc[i][1] - mx) + expf(acc[i][2] - mx) + expf(acc[i][3] - mx);
    outp[(size_t)bt * 16 + lane] = expf(acc[i][j] - mx) / sum;
  }
}

__global__ __launch_bounds__(64) void k_att_freq(const float* __restrict__ fq,
                                                 const float* __restrict__ fk,
                                                 float* __restrict__ outp) {
  int pair = blockIdx.x;
  int b = pair >> 7, tp = pair & 127;
  int lane = threadIdx.x;
  int t = tp * 2 + (lane >> 5);
  int f = lane & 31;
  float qv[4], kv[4];
#pragma unroll
  for (int i = 0; i < 4; i++) {
    size_t lbO = (size_t)(i * 8 + b);
    qv[i] = fq[(lbO * 256 + t) * 32 + f];
    kv[i] = fk[(lbO * 256 + t) * 32 + f];
  }
  float acc[4][4];
#pragma unroll
  for (int i = 0; i < 4; i++)
#pragma unroll
    for (int j = 0; j < 4; j++) acc[i][j] = qv[i] * kv[j];
#pragma unroll
  for (int i = 0; i < 4; i++)
#pragma unroll
    for (int j = 0; j < 4; j++)
      for (int m = 16; m >= 1; m >>= 1) acc[i][j] += __shfl_xor(acc[i][j], m);
  int fl = lane & 31;
  if (fl < 16) {
    int i = fl >> 2, j = fl & 3;
    float mx = fmaxf(fmaxf(acc[i][0], acc[i][1]), fmaxf(acc[i][2], acc[i][3]));
    float sum = expf(acc[i][0] - mx) + expf(acc[i][1] - mx) + expf(acc[i][2] - mx) + expf(acc[i][3] - mx);
    outp[((size_t)(b * 256 + t)) * 16 + fl] = expf(acc[i][j] - mx) / sum;
  }
}

// ---------------------------------------------------------------------------
extern "C" void kernel_launch(void* const* d_in, const int* in_sizes, int n_in,
                              void* d_out, int out_size, void* d_ws, size_t ws_size,
                              hipStream_t stream) {
  (void)in_sizes; (void)n_in; (void)out_size; (void)ws_size;
  const float* feat_s = (const float*)d_in[0];
  const float* feat_t = (const float*)d_in[1];
  const float* tk_w1 = (const float*)d_in[2];
  const float* tk_b1 = (const float*)d_in[3];
  const float* tk_w2 = (const float*)d_in[4];
  const float* tk_b2 = (const float*)d_in[5];
  const float* fk_w1 = (const float*)d_in[6];
  const float* fk_b1 = (const float*)d_in[7];
  const float* fk_w2 = (const float*)d_in[8];
  const float* fk_b2 = (const float*)d_in[9];
  const float* tq_w1 = (const float*)d_in[10];
  const float* tq_b1 = (const float*)d_in[11];
  const float* tq_w2 = (const float*)d_in[12];
  const float* tq_b2 = (const float*)d_in[13];
  const float* fq_w1 = (const float*)d_in[14];
  const float* fq_b1 = (const float*)d_in[15];
  const float* fq_w2 = (const float*)d_in[16];
  const float* fq_b2 = (const float*)d_in[17];

  float* ws = (float*)d_ws;
  // Xh16 region (33.5MB); after k_mfma<0>+k_simg consume it, h and Z alias it.
  half_t* Xh   = (half_t*)ws;                 // 16.8M halves
  half_t* hbuf = (half_t*)ws;                 // 8*2048*512 halves (alias, after gram)
  half_t* Zbuf = (half_t*)(ws + 4194304);     // 8*2048*256 halves (alias, after gram)
  half_t* simh = (half_t*)(ws + 8388608);     // 64*65536 halves
  half_t* W1t  = (half_t*)(ws + 10485760);    // 8*512*256 halves
  half_t* W2t  = (half_t*)(ws + 11010048);    // 8*256*512 halves
  float* Bc1   = ws + 11534336;               // 8*512
  float* Bc2   = ws + 11538432;               // 8*256
  float* simg  = ws + 11540480;               // 2*65536
  float* nrm   = ws + 11671552;               // 2*8192
  float* cnbuf = ws + 11687936;               // 64*256 (tk then tq)
  float* fkb   = ws + 11704320;               // 262144
  float* fqb   = ws + 11966464;               // 262144

  float* tkcn = cnbuf;
  float* tqcn = cnbuf + 8192;

  float* out = (float*)d_out;
  float* out_stu_time = out;               // [4,4,8,256,256]
  float* out_stu_freq = out + 8388608;     // [4,4,8,256,8]
  float* out_tea_time = out + 8650752;     // [4,4,8,256,256]
  float* out_tea_freq = out + 17039360;    // [4,4,8,256,8]
  float* out_time_att = out + 17301504;    // [8,256,4,4]
  float* out_freq_att = out + 17334272;    // [8,256,4,4]

  // 1) weight transpose+convert, bias concat
  hipLaunchKernelGGL(k_wconv, dim3(513), dim3(256), 0, stream,
                     tk_w1, tq_w1, tk_w2, tq_w2, tk_b1, tq_b1, tk_b2, tq_b2,
                     W1t, W2t, Bc1, Bc2);
  // 2) transpose/convert feat -> Xh fp16 + norms
  hipLaunchKernelGGL(k_x2h, dim3(256), dim3(256), 0, stream, feat_s, feat_t, Xh, nrm);
  // 3) freq gram from fp16 panel
  hipLaunchKernelGGL(k_simg, dim3(2048), dim3(256), 0, stream, Xh, simg);
  // 4) time gram via MFMA -> simh fp16
  hipLaunchKernelGGL((k_mfma<0, false, false>), dim3(4, 4, 64), dim3(256), 0, stream,
                     Xh, Xh, (const float*)nullptr, simh);
  // 5) cosine outputs
  hipLaunchKernelGGL(k_cos_time2, dim3(16384), dim3(256), 0, stream, simh, nrm,
                     out_stu_time, out_tea_time);
  hipLaunchKernelGGL(k_cos_freq2, dim3(64), dim3(256), 0, stream, simg, nrm,
                     out_stu_freq, out_tea_freq);
  // 6) freq MLPs (tensor0 = student -> fq, tensor1 = teacher -> fk)
  hipLaunchKernelGGL(k_fmlp2, dim3(64), dim3(256), 0, stream, simg,
                     fq_w1, fq_b1, fq_w2, fq_b2, fk_w1, fk_b1, fk_w2, fk_b2, fqb, fkb);
  // 7) frame MLPs via MFMA (h and Z alias the now-dead Xh region)
  hipLaunchKernelGGL((k_mfma<1, true, true>), dim3(32, 8, 8), dim3(256), 0, stream,
                     simh, W1t, Bc1, hbuf);
  hipLaunchKernelGGL((k_mfma<2, false, true>), dim3(32, 4, 8), dim3(256), 0, stream,
                     hbuf, W2t, Bc2, Zbuf);
  // 8) column norms (both paths)
  hipLaunchKernelGGL(k_colnorm, dim3(64), dim3(256), 0, stream, Zbuf, cnbuf);
  // 9) attention
  hipLaunchKernelGGL(k_att_time, dim3(2048), dim3(64), 0, stream,
                     Zbuf + (size_t)4 * 2048 * 256, Zbuf, tqcn, tkcn, out_time_att);
  hipLaunchKernelGGL(k_att_freq, dim3(1024), dim3(64), 0, stream, fqb, fkb, out_freq_att);
}

// Round 4
// 166.358 us; speedup vs baseline: 3.4077x; 1.2641x over previous
//
#include <hip/hip_runtime.h>
#include <math.h>

// Problem constants: s_len=t_len=4, B=8, C=64, T=256, D=16, H=512, F=32
typedef _Float16 half_t;
typedef _Float16 h2 __attribute__((ext_vector_type(2)));
typedef _Float16 h4 __attribute__((ext_vector_type(4)));
typedef _Float16 h8 __attribute__((ext_vector_type(8)));
typedef float f4 __attribute__((ext_vector_type(4)));
static constexpr float REPS = 1e-6f;

// ---------------------------------------------------------------------------
// k_wconv: transpose+convert weights to fp16 [z][N][K] (z = tk l0-3, tq l4-7)
// and concat biases to fp32 [z][N]. blocks 0-255: W1; 256-511: W2; 512: biases.
// ---------------------------------------------------------------------------
__global__ __launch_bounds__(256) void k_wconv(const float* __restrict__ tkw1, const float* __restrict__ tqw1,
                                               const float* __restrict__ tkw2, const float* __restrict__ tqw2,
                                               const float* __restrict__ tkb1, const float* __restrict__ tqb1,
                                               const float* __restrict__ tkb2, const float* __restrict__ tqb2,
                                               half_t* __restrict__ W1t, half_t* __restrict__ W2t,
                                               float* __restrict__ Bc1, float* __restrict__ Bc2) {
  __shared__ float T[64][65];
  int bid = blockIdx.x;
  int tid = threadIdx.x;
  if (bid < 256) {  // W1: [l][256 k][512 n] -> [z][512 n][256 k]
    int z = bid >> 5, tile = bid & 31;
    int kt = tile >> 3, ntile = tile & 7;
    const float* src = (z < 4 ? tkw1 : tqw1) + (size_t)(z & 3) * 256 * 512;
#pragma unroll
    for (int q = 0; q < 16; q++) {
      int e = q * 256 + tid;
      int r = e >> 6, c = e & 63;
      T[r][c] = src[(size_t)(kt * 64 + r) * 512 + ntile * 64 + c];
    }
    __syncthreads();
#pragma unroll
    for (int q = 0; q < 16; q++) {
      int e = q * 256 + tid;
      int nn = e >> 6, kk = e & 63;
      W1t[(size_t)z * 512 * 256 + (size_t)(ntile * 64 + nn) * 256 + kt * 64 + kk] = (half_t)T[kk][nn];
    }
  } else if (bid < 512) {  // W2: [l][512 k][256 n] -> [z][256 n][512 k]
    int bb = bid - 256;
    int z = bb >> 5, tile = bb & 31;
    int kt = tile >> 2, ntile = tile & 3;
    const float* src = (z < 4 ? tkw2 : tqw2) + (size_t)(z & 3) * 512 * 256;
#pragma unroll
    for (int q = 0; q < 16; q++) {
      int e = q * 256 + tid;
      int r = e >> 6, c = e & 63;
      T[r][c] = src[(size_t)(kt * 64 + r) * 256 + ntile * 64 + c];
    }
    __syncthreads();
#pragma unroll
    for (int q = 0; q < 16; q++) {
      int e = q * 256 + tid;
      int nn = e >> 6, kk = e & 63;
      W2t[(size_t)z * 256 * 512 + (size_t)(ntile * 64 + nn) * 512 + kt * 64 + kk] = (half_t)T[kk][nn];
    }
  } else {
    for (int e = tid; e < 4096; e += 256) {
      int z = e >> 9, n = e & 511;
      Bc1[e] = (z < 4 ? tkb1 : tqb1)[(z & 3) * 512 + n];
    }
    for (int e = tid; e < 2048; e += 256) {
      int z = e >> 8, n = e & 255;
      Bc2[e] = (z < 4 ? tkb2 : tqb2)[(z & 3) * 256 + n];
    }
  }
}

// ---------------------------------------------------------------------------
// k_x2h: LDS-free transpose/convert feat [l,b,c,t,d] -> Xh fp16 [row][k=c*16+d]
// + fp32 sumsq per row -> nrm. Thread owns one t; lane quad covers 16 d's.
// grid 256 = tensor*128 + l*32 + b*4 + tc
// ---------------------------------------------------------------------------
__global__ __launch_bounds__(256) void k_x2h(const float* __restrict__ fs,
                                             const float* __restrict__ ft,
                                             half_t* __restrict__ Xh,
                                             float* __restrict__ nrm) {
  int bid = blockIdx.x;
  int tensor = bid >> 7;
  int l = (bid >> 5) & 3;
  int b = (bid >> 2) & 7;
  int tc = bid & 3;
  int tid = threadIdx.x;
  int tl = tid >> 2;           // 0..63
  int d0 = (tid & 3) * 4;
  int t = tc * 64 + tl;
  const float* base = (tensor ? ft : fs) + (size_t)((l * 8 + b) * 64) * 4096 + t * 16 + d0;
  size_t row = (size_t)(tensor * 32 + l * 8 + b) * 256 + t;
  half_t* xrow = Xh + row * 1024 + d0;
  float acc = 0.f;
#pragma unroll 8
  for (int c = 0; c < 64; c++) {
    float4 v = *(const float4*)(base + (size_t)c * 4096);
    acc += v.x * v.x + v.y * v.y + v.z * v.z + v.w * v.w;
    h4 hv;
    hv[0] = (half_t)v.x; hv[1] = (half_t)v.y; hv[2] = (half_t)v.z; hv[3] = (half_t)v.w;
    *(h4*)(xrow + c * 16) = hv;
  }
  acc += __shfl_xor(acc, 1);
  acc += __shfl_xor(acc, 2);
  if ((tid & 3) == 0) nrm[row] = sqrtf(acc);
}

// ---------------------------------------------------------------------------
// k_simg (v2): freq gram via LDS staging + v_dot2_f32_f16.
// Block = (tensor, l, 4 t's); grid 512; 256 threads.
// LDS rows ordered r = tl*8 + b, stride 1032 halves (+8 pad -> conflict-free
// broadcast reads: row r lands on bank 4*(r&7)). One dot-1024 per thread.
// ---------------------------------------------------------------------------
__global__ __launch_bounds__(256) void k_simg(const half_t* __restrict__ Xh,
                                              float* __restrict__ simg) {
  __shared__ __align__(16) half_t X[32 * 1032];
  int bid = blockIdx.x;
  int tensor = bid >> 8;
  int l = (bid >> 6) & 3;
  int tc = bid & 63;
  int t0 = tc * 4;
  int tid = threadIdx.x;
  {  // stage 32 rows x 2KB; thread (r=tid>>3, q=tid&7) loads 16 XOR-permuted
     // 16B chunks (128B-contiguous per 8-lane group; LDS write 2-way = free)
    int r = tid >> 3, q = tid & 7;
    int b = r & 7, tl = r >> 3;
    const half_t* src = Xh + ((size_t)(tensor * 32 + l * 8 + b) * 256 + t0 + tl) * 1024;
    half_t* dst = X + (tl * 8 + b) * 1032;
    int c0 = q ^ (r & 7);
#pragma unroll
    for (int j = 0; j < 16; j++) {
      int c = c0 + 8 * j;
      *(h8*)(dst + c * 8) = *(const h8*)(src + c * 8);
    }
  }
  __syncthreads();
  int tl = tid >> 6;   // 0..3
  int ab = tid & 63;
  int b = ab >> 3, a = ab & 7;
  const half_t* xa = X + (tl * 8 + b) * 1032;
  const half_t* xb = X + (tl * 8 + a) * 1032;
  float acc = 0.f;
#pragma unroll 8
  for (int k = 0; k < 1024; k += 8) {
    h8 va = *(const h8*)(xa + k);
    h8 vb = *(const h8*)(xb + k);
#if __has_builtin(__builtin_amdgcn_fdot2)
#pragma unroll
    for (int i = 0; i < 4; i++) {
      h2 pa, pb;
      pa[0] = va[2 * i]; pa[1] = va[2 * i + 1];
      pb[0] = vb[2 * i]; pb[1] = vb[2 * i + 1];
      acc = __builtin_amdgcn_fdot2(pa, pb, acc, false);
    }
#else
#pragma unroll
    for (int e = 0; e < 8; e++) acc += (float)va[e] * (float)vb[e];
#endif
  }
  simg[(size_t)tensor * 65536 + ((size_t)(l * 8 + b) * 256 + t0 + tl) * 8 + a] = acc;
}

// ---------------------------------------------------------------------------
// Unified fp16 MFMA GEMM: out = [relu](A @ Bt^T + bias). MODE 0: gram
// (K=1024,N=256,batch 64); MODE 1: h=relu(simh@W1t^T+b1); MODE 2: Z=h@W2t^T+b2.
// 64x64 tile, BK=64, 4 waves x (32x32), XOR-swizzled LDS.
// ---------------------------------------------------------------------------
template <int MODE, bool RELU, bool BIAS>
__global__ __launch_bounds__(256) void k_mfma(const half_t* __restrict__ A,
                                              const half_t* __restrict__ Bt,
                                              const float* __restrict__ bias,
                                              half_t* __restrict__ out) {
  constexpr int K = (MODE == 0) ? 1024 : (MODE == 1) ? 256 : 512;
  constexpr int N = (MODE == 0) ? 256 : (MODE == 1) ? 512 : 256;
  __shared__ __align__(16) half_t Asm[64 * 64];
  __shared__ __align__(16) half_t Bsm[64 * 64];
  int z = blockIdx.z;
  size_t Aoff, Boff, Ooff;
  if (MODE == 0) {
    Aoff = (size_t)z * 256 * 1024; Boff = Aoff; Ooff = (size_t)z * 256 * 256;
  } else if (MODE == 1) {
    int l = z & 3, path = z >> 2;  // path0 = tk (teacher sim), path1 = tq (student)
    Aoff = ((size_t)((path == 0 ? 32 : 0) + l * 8)) * 256 * 256;
    Boff = (size_t)z * 512 * 256;
    Ooff = (size_t)z * 2048 * 512;
  } else {
    Aoff = (size_t)z * 2048 * 512; Boff = (size_t)z * 256 * 512; Ooff = (size_t)z * 2048 * 256;
  }
  const half_t* Ab = A + Aoff;
  const half_t* Bb = Bt + Boff;
  int mt = blockIdx.x, nt = blockIdx.y;
  int tid = threadIdx.x;
  int wave = tid >> 6, lane = tid & 63;
  int wm = (wave >> 1) * 32, wn = (wave & 1) * 32;
  int lr = lane & 15, lg = lane >> 4;
  f4 acc[2][2] = {};
  int r0 = tid >> 3, seg0 = tid & 7;
  int sw0 = (seg0 ^ (r0 & 7)) * 8;
  for (int kc = 0; kc < K; kc += 64) {
    h8 a0 = *(const h8*)(Ab + (size_t)(mt * 64 + r0) * K + kc + seg0 * 8);
    h8 a1 = *(const h8*)(Ab + (size_t)(mt * 64 + r0 + 32) * K + kc + seg0 * 8);
    h8 b0 = *(const h8*)(Bb + (size_t)(nt * 64 + r0) * K + kc + seg0 * 8);
    h8 b1 = *(const h8*)(Bb + (size_t)(nt * 64 + r0 + 32) * K + kc + seg0 * 8);
    __syncthreads();
    *(h8*)(Asm + r0 * 64 + sw0) = a0;
    *(h8*)(Asm + (r0 + 32) * 64 + sw0) = a1;
    *(h8*)(Bsm + r0 * 64 + sw0) = b0;
    *(h8*)(Bsm + (r0 + 32) * 64 + sw0) = b1;
    __syncthreads();
#pragma unroll
    for (int kk = 0; kk < 2; kk++) {
      h8 af[2], bf[2];
#pragma unroll
      for (int mf = 0; mf < 2; mf++) {
        int r = wm + mf * 16 + lr;
        int g = kk * 4 + lg;
        af[mf] = *(const h8*)(Asm + r * 64 + ((g ^ (r & 7)) * 8));
      }
#pragma unroll
      for (int nf = 0; nf < 2; nf++) {
        int r = wn + nf * 16 + lr;
        int g = kk * 4 + lg;
        bf[nf] = *(const h8*)(Bsm + r * 64 + ((g ^ (r & 7)) * 8));
      }
#pragma unroll
      for (int mf = 0; mf < 2; mf++)
#pragma unroll
        for (int nf = 0; nf < 2; nf++)
          acc[mf][nf] = __builtin_amdgcn_mfma_f32_16x16x32_f16(af[mf], bf[nf], acc[mf][nf], 0, 0, 0);
    }
  }
  half_t* Ob = out + Ooff;
#pragma unroll
  for (int mf = 0; mf < 2; mf++)
#pragma unroll
    for (int nf = 0; nf < 2; nf++) {
      int col = nt * 64 + wn + nf * 16 + lr;
      float bv = BIAS ? bias[z * N + col] : 0.f;
#pragma unroll
      for (int rg = 0; rg < 4; rg++) {
        int row = mt * 64 + wm + mf * 16 + lg * 4 + rg;
        float v = acc[mf][nf][rg] + bv;
        if (RELU) v = fmaxf(v, 0.f);
        Ob[(size_t)row * N + col] = (half_t)v;
      }
    }
}

// ---------------------------------------------------------------------------
// k_cos_time2: both tensors in one launch. grid 16384 (tensor = bid>>13).
// ---------------------------------------------------------------------------
__global__ __launch_bounds__(256) void k_cos_time2(const half_t* __restrict__ simh,
                                                   const float* __restrict__ n,
                                                   float* __restrict__ out_stu,
                                                   float* __restrict__ out_tea) {
  __shared__ float red[4];
  __shared__ float rs;
  int tensor = blockIdx.x >> 13;
  int bid = blockIdx.x & 8191;  // lb*256 + t
  const half_t* sh = simh + (size_t)tensor * 2097152;
  const float* nb2 = n + tensor * 8192;
  float* out = tensor ? out_tea : out_stu;
  int t = bid & 255;
  int lb = bid >> 8;
  int l = lb >> 3, b = lb & 7;
  int s = threadIdx.x;
  float nt = nb2[lb * 256 + t] + REPS;
  float ns = nb2[lb * 256 + s] + REPS;
  float v = ((float)sh[(size_t)bid * 256 + s] / (nt * ns) + 1.f) * 0.5f;
  float w = v;
  for (int m = 32; m >= 1; m >>= 1) w += __shfl_xor(w, m);
  if ((threadIdx.x & 63) == 0) red[threadIdx.x >> 6] = w;
  __syncthreads();
  if (threadIdx.x == 0) rs = red[0] + red[1] + red[2] + red[3];
  __syncthreads();
  v /= rs;
  size_t inner = ((size_t)(b * 256 + t)) * 256 + s;
  if (tensor == 0) {
    size_t base = (size_t)l * 4 * 524288;
#pragma unroll
    for (int j = 0; j < 4; j++) out[base + (size_t)j * 524288 + inner] = v;
  } else {
#pragma unroll
    for (int i = 0; i < 4; i++) out[((size_t)(i * 4 + l)) * 524288 + inner] = v;
  }
}

__global__ __launch_bounds__(256) void k_cos_freq2(const float* __restrict__ simg,
                                                   const float* __restrict__ n,
                                                   float* __restrict__ out_stu,
                                                   float* __restrict__ out_tea) {
  int tensor = blockIdx.x >> 5;
  int lb = blockIdx.x & 31;
  const float* sg = simg + (size_t)tensor * 65536;
  const float* nb2 = n + tensor * 8192;
  float* out = tensor ? out_tea : out_stu;
  int l = lb >> 3, b = lb & 7;
  int tid = threadIdx.x;
  int a = tid & 7;
  for (int tc = 0; tc < 8; tc++) {
    int t = tc * 32 + (tid >> 3);
    float nb = nb2[lb * 256 + t] + REPS;
    float na = nb2[(l * 8 + a) * 256 + t] + REPS;
    float v = (sg[((size_t)lb * 256 + t) * 8 + a] / (nb * na) + 1.f) * 0.5f;
    float w = v;
    for (int m = 1; m < 8; m <<= 1) w += __shfl_xor(w, m);
    v /= w;
    size_t inner = ((size_t)(b * 256 + t)) * 8 + a;
    if (tensor == 0) {
#pragma unroll
      for (int j = 0; j < 4; j++) out[((size_t)(l * 4 + j)) * 16384 + inner] = v;
    } else {
#pragma unroll
      for (int i = 0; i < 4; i++) out[((size_t)(i * 4 + l)) * 16384 + inner] = v;
    }
  }
}

// ---------------------------------------------------------------------------
// Fused freq MLP, both tensors: tensor0 = student->fq weights, 1 = teacher->fk.
// ---------------------------------------------------------------------------
__global__ __launch_bounds__(256) void k_fmlp2(const float* __restrict__ simg,
                                               const float* __restrict__ qw1, const float* __restrict__ qb1,
                                               const float* __restrict__ qw2, const float* __restrict__ qb2,
                                               const float* __restrict__ kw1, const float* __restrict__ kb1,
                                               const float* __restrict__ kw2, const float* __restrict__ kb2,
                                               float* __restrict__ qout, float* __restrict__ kout) {
  __shared__ float sw1[8 * 32], sb1[32], sw2[32 * 32], sb2[32];
  __shared__ float zs[256][33];
  __shared__ float pcn[8][33];
  __shared__ float cn[32];
  int tensor = blockIdx.x >> 5;
  int lb = blockIdx.x & 31;
  int l = lb >> 3;
  const float* w1 = tensor ? kw1 : qw1;
  const float* b1 = tensor ? kb1 : qb1;
  const float* w2 = tensor ? kw2 : qw2;
  const float* b2 = tensor ? kb2 : qb2;
  const float* sg = simg + (size_t)tensor * 65536;
  float* outp = tensor ? kout : qout;
  int t = threadIdx.x;
  sw1[t] = w1[l * 256 + t];
  if (t < 32) { sb1[t] = b1[l * 32 + t]; sb2[t] = b2[l * 32 + t]; }
  for (int q = t; q < 1024; q += 256) sw2[q] = w2[l * 1024 + q];
  __syncthreads();
  float x[8];
#pragma unroll
  for (int a = 0; a < 8; a++) x[a] = sg[((size_t)lb * 256 + t) * 8 + a];
  float h[32];
#pragma unroll
  for (int f = 0; f < 32; f++) {
    float acc = sb1[f];
#pragma unroll
    for (int a = 0; a < 8; a++) acc += x[a] * sw1[a * 32 + f];
    h[f] = fmaxf(acc, 0.f);
  }
#pragma unroll
  for (int g = 0; g < 32; g++) {
    float acc = sb2[g];
#pragma unroll
    for (int f = 0; f < 32; f++) acc += h[f] * sw2[f * 32 + g];
    zs[t][g] = acc;
  }
  __syncthreads();
  {
    int col = t & 31, ch = t >> 5;
    float sq = 0.f;
    for (int r = ch * 32; r < ch * 32 + 32; r++) { float v = zs[r][col]; sq += v * v; }
    pcn[ch][col] = sq;
  }
  __syncthreads();
  if (t < 32) {
    float ssum = 0.f;
#pragma unroll
    for (int c = 0; c < 8; c++) ssum += pcn[c][t];
    cn[t] = sqrtf(ssum);
  }
  __syncthreads();
#pragma unroll
  for (int g = 0; g < 32; g++)
    outp[((size_t)lb * 256 + t) * 32 + g] = zs[t][g] / cn[g];
}

// Fused column sumsq + sqrt over t for both paths; grid 64 (lb<32 = tk, else tq)
__global__ __launch_bounds__(256) void k_colnorm(const half_t* __restrict__ Z, float* __restrict__ cn) {
  int lbg = blockIdx.x;
  int path = lbg >> 5, lb = lbg & 31;
  const half_t* Zb = Z + (size_t)path * 4 * 2048 * 256;
  int s = threadIdx.x;
  float acc = 0.f;
  for (int t = 0; t < 256; t++) {
    float v = (float)Zb[((size_t)lb * 256 + t) * 256 + s];
    acc += v * v;
  }
  cn[lbg * 256 + s] = sqrtf(acc);
}

// time attention: att[b,t,i,j] = softmax_j( sum_s (Zq/qcn)(Zk/kcn) )
__global__ __launch_bounds__(64) void k_att_time(const half_t* __restrict__ Zq,
                                                 const half_t* __restrict__ Zk,
                                                 const float* __restrict__ qcn,
                                                 const float* __restrict__ kcn,
                                                 float* __restrict__ outp) {
  int bt = blockIdx.x;
  int b = bt >> 8, t = bt & 255;
  int lane = threadIdx.x;
  float acc[4][4];
#pragma unroll
  for (int i = 0; i < 4; i++)
#pragma unroll
    for (int j = 0; j < 4; j++) acc[i][j] = 0.f;
  for (int it = 0; it < 4; it++) {
    int s = lane + it * 64;
    float qv[4], kv[4];
#pragma unroll
    for (int i = 0; i < 4; i++) {
      size_t lbO = (size_t)(i * 8 + b);
      qv[i] = (float)Zq[(lbO * 256 + t) * 256 + s] / qcn[lbO * 256 + s];
      kv[i] = (float)Zk[(lbO * 256 + t) * 256 + s] / kcn[lbO * 256 + s];
    }
#pragma unroll
    for (int i = 0; i < 4; i++)
#pragma unroll
      for (int j = 0; j < 4; j++) acc[i][j] += qv[i] * kv[j];
  }
#pragma unroll
  for (int i = 0; i < 4; i++)
#pragma unroll
    for (int j = 0; j < 4; j++)
      for (int m = 32; m >= 1; m >>= 1) acc[i][j] += __shfl_xor(acc[i][j], m);
  if (lane < 16) {
    int i = lane >> 2, j = lane & 3;
    float mx = fmaxf(fmaxf(acc[i][0], acc[i][1]), fmaxf(acc[i][2], acc[i][3]));
    float sum = expf(acc[i][0] - mx) + expf(acc[i][1] - mx) + expf(acc[i][2] - mx) + expf(acc[i][3] - mx);
    outp[(size_t)bt * 16 + lane] = expf(acc[i][j] - mx) / sum;
  }
}

__global__ __launch_bounds__(64) void k_att_freq(const float* __restrict__ fq,
                                                 const float* __restrict__ fk,
                                                 float* __restrict__ outp) {
  int pair = blockIdx.x;
  int b = pair >> 7, tp = pair & 127;
  int lane = threadIdx.x;
  int t = tp * 2 + (lane >> 5);
  int f = lane & 31;
  float qv[4], kv[4];
#pragma unroll
  for (int i = 0; i < 4; i++) {
    size_t lbO = (size_t)(i * 8 + b);
    qv[i] = fq[(lbO * 256 + t) * 32 + f];
    kv[i] = fk[(lbO * 256 + t) * 32 + f];
  }
  float acc[4][4];
#pragma unroll
  for (int i = 0; i < 4; i++)
#pragma unroll
    for (int j = 0; j < 4; j++) acc[i][j] = qv[i] * kv[j];
#pragma unroll
  for (int i = 0; i < 4; i++)
#pragma unroll
    for (int j = 0; j < 4; j++)
      for (int m = 16; m >= 1; m >>= 1) acc[i][j] += __shfl_xor(acc[i][j], m);
  int fl = lane & 31;
  if (fl < 16) {
    int i = fl >> 2, j = fl & 3;
    float mx = fmaxf(fmaxf(acc[i][0], acc[i][1]), fmaxf(acc[i][2], acc[i][3]));
    float sum = expf(acc[i][0] - mx) + expf(acc[i][1] - mx) + expf(acc[i][2] - mx) + expf(acc[i][3] - mx);
    outp[((size_t)(b * 256 + t)) * 16 + fl] = expf(acc[i][j] - mx) / sum;
  }
}

// ---------------------------------------------------------------------------
extern "C" void kernel_launch(void* const* d_in, const int* in_sizes, int n_in,
                              void* d_out, int out_size, void* d_ws, size_t ws_size,
                              hipStream_t stream) {
  (void)in_sizes; (void)n_in; (void)out_size; (void)ws_size;
  const float* feat_s = (const float*)d_in[0];
  const float* feat_t = (const float*)d_in[1];
  const float* tk_w1 = (const float*)d_in[2];
  const float* tk_b1 = (const float*)d_in[3];
  const float* tk_w2 = (const float*)d_in[4];
  const float* tk_b2 = (const float*)d_in[5];
  const float* fk_w1 = (const float*)d_in[6];
  const float* fk_b1 = (const float*)d_in[7];
  const float* fk_w2 = (const float*)d_in[8];
  const float* fk_b2 = (const float*)d_in[9];
  const float* tq_w1 = (const float*)d_in[10];
  const float* tq_b1 = (const float*)d_in[11];
  const float* tq_w2 = (const float*)d_in[12];
  const float* tq_b2 = (const float*)d_in[13];
  const float* fq_w1 = (const float*)d_in[14];
  const float* fq_b1 = (const float*)d_in[15];
  const float* fq_w2 = (const float*)d_in[16];
  const float* fq_b2 = (const float*)d_in[17];

  float* ws = (float*)d_ws;
  // Xh16 region (33.5MB); after k_mfma<0>+k_simg consume it, h and Z alias it.
  half_t* Xh   = (half_t*)ws;                 // 16.8M halves
  half_t* hbuf = (half_t*)ws;                 // 8*2048*512 halves (alias, after gram)
  half_t* Zbuf = (half_t*)(ws + 4194304);     // 8*2048*256 halves (alias, after gram)
  half_t* simh = (half_t*)(ws + 8388608);     // 64*65536 halves
  half_t* W1t  = (half_t*)(ws + 10485760);    // 8*512*256 halves
  half_t* W2t  = (half_t*)(ws + 11010048);    // 8*256*512 halves
  float* Bc1   = ws + 11534336;               // 8*512
  float* Bc2   = ws + 11538432;               // 8*256
  float* simg  = ws + 11540480;               // 2*65536
  float* nrm   = ws + 11671552;               // 2*8192
  float* cnbuf = ws + 11687936;               // 64*256 (tk then tq)
  float* fkb   = ws + 11704320;               // 262144
  float* fqb   = ws + 11966464;               // 262144

  float* tkcn = cnbuf;
  float* tqcn = cnbuf + 8192;

  float* out = (float*)d_out;
  float* out_stu_time = out;               // [4,4,8,256,256]
  float* out_stu_freq = out + 8388608;     // [4,4,8,256,8]
  float* out_tea_time = out + 8650752;     // [4,4,8,256,256]
  float* out_tea_freq = out + 17039360;    // [4,4,8,256,8]
  float* out_time_att = out + 17301504;    // [8,256,4,4]
  float* out_freq_att = out + 17334272;    // [8,256,4,4]

  // 1) weight transpose+convert, bias concat
  hipLaunchKernelGGL(k_wconv, dim3(513), dim3(256), 0, stream,
                     tk_w1, tq_w1, tk_w2, tq_w2, tk_b1, tq_b1, tk_b2, tq_b2,
                     W1t, W2t, Bc1, Bc2);
  // 2) transpose/convert feat -> Xh fp16 + norms
  hipLaunchKernelGGL(k_x2h, dim3(256), dim3(256), 0, stream, feat_s, feat_t, Xh, nrm);
  // 3) freq gram from fp16 panel (LDS + dot2)
  hipLaunchKernelGGL(k_simg, dim3(512), dim3(256), 0, stream, Xh, simg);
  // 4) time gram via MFMA -> simh fp16
  hipLaunchKernelGGL((k_mfma<0, false, false>), dim3(4, 4, 64), dim3(256), 0, stream,
                     Xh, Xh, (const float*)nullptr, simh);
  // 5) cosine outputs
  hipLaunchKernelGGL(k_cos_time2, dim3(16384), dim3(256), 0, stream, simh, nrm,
                     out_stu_time, out_tea_time);
  hipLaunchKernelGGL(k_cos_freq2, dim3(64), dim3(256), 0, stream, simg, nrm,
                     out_stu_freq, out_tea_freq);
  // 6) freq MLPs (tensor0 = student -> fq, tensor1 = teacher -> fk)
  hipLaunchKernelGGL(k_fmlp2, dim3(64), dim3(256), 0, stream, simg,
                     fq_w1, fq_b1, fq_w2, fq_b2, fk_w1, fk_b1, fk_w2, fk_b2, fqb, fkb);
  // 7) frame MLPs via MFMA (h and Z alias the now-dead Xh region)
  hipLaunchKernelGGL((k_mfma<1, true, true>), dim3(32, 8, 8), dim3(256), 0, stream,
                     simh, W1t, Bc1, hbuf);
  hipLaunchKernelGGL((k_mfma<2, false, true>), dim3(32, 4, 8), dim3(256), 0, stream,
                     hbuf, W2t, Bc2, Zbuf);
  // 8) column norms (both paths)
  hipLaunchKernelGGL(k_colnorm, dim3(64), dim3(256), 0, stream, Zbuf, cnbuf);
  // 9) attention
  hipLaunchKernelGGL(k_att_time, dim3(2048), dim3(64), 0, stream,
                     Zbuf + (size_t)4 * 2048 * 256, Zbuf, tqcn, tkcn, out_time_att);
  hipLaunchKernelGGL(k_att_freq, dim3(1024), dim3(64), 0, stream, fqb, fkb, out_freq_att);
}

// Round 5
// 158.539 us; speedup vs baseline: 3.5757x; 1.0493x over previous
//
#include <hip/hip_runtime.h>
#include <math.h>

// Problem constants: s_len=t_len=4, B=8, C=64, T=256, D=16, H=512, F=32
typedef _Float16 half_t;
typedef _Float16 h2 __attribute__((ext_vector_type(2)));
typedef _Float16 h4 __attribute__((ext_vector_type(4)));
typedef _Float16 h8 __attribute__((ext_vector_type(8)));
typedef float f4 __attribute__((ext_vector_type(4)));
static constexpr float REPS = 1e-6f;

// ---------------------------------------------------------------------------
// k_wconv: transpose+convert weights to fp16 [z][N][K] (z = tk l0-3, tq l4-7)
// and concat biases to fp32 [z][N]. blocks 0-255: W1; 256-511: W2;
// block 512: biases + zero the colnorm-partial buffer.
// ---------------------------------------------------------------------------
__global__ __launch_bounds__(256) void k_wconv(const float* __restrict__ tkw1, const float* __restrict__ tqw1,
                                               const float* __restrict__ tkw2, const float* __restrict__ tqw2,
                                               const float* __restrict__ tkb1, const float* __restrict__ tqb1,
                                               const float* __restrict__ tkb2, const float* __restrict__ tqb2,
                                               half_t* __restrict__ W1t, half_t* __restrict__ W2t,
                                               float* __restrict__ Bc1, float* __restrict__ Bc2,
                                               float* __restrict__ part) {
  __shared__ float T[64][65];
  int bid = blockIdx.x;
  int tid = threadIdx.x;
  if (bid < 256) {  // W1: [l][256 k][512 n] -> [z][512 n][256 k]
    int z = bid >> 5, tile = bid & 31;
    int kt = tile >> 3, ntile = tile & 7;
    const float* src = (z < 4 ? tkw1 : tqw1) + (size_t)(z & 3) * 256 * 512;
#pragma unroll
    for (int q = 0; q < 16; q++) {
      int e = q * 256 + tid;
      int r = e >> 6, c = e & 63;
      T[r][c] = src[(size_t)(kt * 64 + r) * 512 + ntile * 64 + c];
    }
    __syncthreads();
#pragma unroll
    for (int q = 0; q < 16; q++) {
      int e = q * 256 + tid;
      int nn = e >> 6, kk = e & 63;
      W1t[(size_t)z * 512 * 256 + (size_t)(ntile * 64 + nn) * 256 + kt * 64 + kk] = (half_t)T[kk][nn];
    }
  } else if (bid < 512) {  // W2: [l][512 k][256 n] -> [z][256 n][512 k]
    int bb = bid - 256;
    int z = bb >> 5, tile = bb & 31;
    int kt = tile >> 2, ntile = tile & 3;
    const float* src = (z < 4 ? tkw2 : tqw2) + (size_t)(z & 3) * 512 * 256;
#pragma unroll
    for (int q = 0; q < 16; q++) {
      int e = q * 256 + tid;
      int r = e >> 6, c = e & 63;
      T[r][c] = src[(size_t)(kt * 64 + r) * 256 + ntile * 64 + c];
    }
    __syncthreads();
#pragma unroll
    for (int q = 0; q < 16; q++) {
      int e = q * 256 + tid;
      int nn = e >> 6, kk = e & 63;
      W2t[(size_t)z * 256 * 512 + (size_t)(ntile * 64 + nn) * 512 + kt * 64 + kk] = (half_t)T[kk][nn];
    }
  } else {
    for (int e = tid; e < 4096; e += 256) {
      int z = e >> 9, n = e & 511;
      Bc1[e] = (z < 4 ? tkb1 : tqb1)[(z & 3) * 512 + n];
    }
    for (int e = tid; e < 2048; e += 256) {
      int z = e >> 8, n = e & 255;
      Bc2[e] = (z < 4 ? tkb2 : tqb2)[(z & 3) * 256 + n];
    }
    for (int e = tid; e < 16384; e += 256) part[e] = 0.f;
  }
}

// ---------------------------------------------------------------------------
// k_x2h: LDS-free transpose/convert feat [l,b,c,t,d] -> Xh fp16 [row][k=c*16+d]
// + fp32 sumsq per row -> nrm. grid 256 = tensor*128 + l*32 + b*4 + tc
// ---------------------------------------------------------------------------
__global__ __launch_bounds__(256) void k_x2h(const float* __restrict__ fs,
                                             const float* __restrict__ ft,
                                             half_t* __restrict__ Xh,
                                             float* __restrict__ nrm) {
  int bid = blockIdx.x;
  int tensor = bid >> 7;
  int l = (bid >> 5) & 3;
  int b = (bid >> 2) & 7;
  int tc = bid & 3;
  int tid = threadIdx.x;
  int tl = tid >> 2;           // 0..63
  int d0 = (tid & 3) * 4;
  int t = tc * 64 + tl;
  const float* base = (tensor ? ft : fs) + (size_t)((l * 8 + b) * 64) * 4096 + t * 16 + d0;
  size_t row = (size_t)(tensor * 32 + l * 8 + b) * 256 + t;
  half_t* xrow = Xh + row * 1024 + d0;
  float acc = 0.f;
#pragma unroll 8
  for (int c = 0; c < 64; c++) {
    float4 v = *(const float4*)(base + (size_t)c * 4096);
    acc += v.x * v.x + v.y * v.y + v.z * v.z + v.w * v.w;
    h4 hv;
    hv[0] = (half_t)v.x; hv[1] = (half_t)v.y; hv[2] = (half_t)v.z; hv[3] = (half_t)v.w;
    *(h4*)(xrow + c * 16) = hv;
  }
  acc += __shfl_xor(acc, 1);
  acc += __shfl_xor(acc, 2);
  if ((tid & 3) == 0) nrm[row] = sqrtf(acc);
}

// ---------------------------------------------------------------------------
// k_simg: freq gram via LDS staging + v_dot2_f32_f16.
// Block = (tensor, l, 4 t's); grid 512; 256 threads.
// ---------------------------------------------------------------------------
__global__ __launch_bounds__(256) void k_simg(const half_t* __restrict__ Xh,
                                              float* __restrict__ simg) {
  __shared__ __align__(16) half_t X[32 * 1032];
  int bid = blockIdx.x;
  int tensor = bid >> 8;
  int l = (bid >> 6) & 3;
  int tc = bid & 63;
  int t0 = tc * 4;
  int tid = threadIdx.x;
  {
    int r = tid >> 3, q = tid & 7;
    int b = r & 7, tl = r >> 3;
    const half_t* src = Xh + ((size_t)(tensor * 32 + l * 8 + b) * 256 + t0 + tl) * 1024;
    half_t* dst = X + (tl * 8 + b) * 1032;
    int c0 = q ^ (r & 7);
#pragma unroll
    for (int j = 0; j < 16; j++) {
      int c = c0 + 8 * j;
      *(h8*)(dst + c * 8) = *(const h8*)(src + c * 8);
    }
  }
  __syncthreads();
  int tl = tid >> 6;   // 0..3
  int ab = tid & 63;
  int b = ab >> 3, a = ab & 7;
  const half_t* xa = X + (tl * 8 + b) * 1032;
  const half_t* xb = X + (tl * 8 + a) * 1032;
  float acc = 0.f;
#pragma unroll 8
  for (int k = 0; k < 1024; k += 8) {
    h8 va = *(const h8*)(xa + k);
    h8 vb = *(const h8*)(xb + k);
#if __has_builtin(__builtin_amdgcn_fdot2)
#pragma unroll
    for (int i = 0; i < 4; i++) {
      h2 pa, pb;
      pa[0] = va[2 * i]; pa[1] = va[2 * i + 1];
      pb[0] = vb[2 * i]; pb[1] = vb[2 * i + 1];
      acc = __builtin_amdgcn_fdot2(pa, pb, acc, false);
    }
#else
#pragma unroll
    for (int e = 0; e < 8; e++) acc += (float)va[e] * (float)vb[e];
#endif
  }
  simg[(size_t)tensor * 65536 + ((size_t)(l * 8 + b) * 256 + t0 + tl) * 8 + a] = acc;
}

// ---------------------------------------------------------------------------
// Unified fp16 MFMA GEMM, 128x128 tile, BK=64, 4 waves x (64x64), XOR swizzle.
// MODE 0: gram (K=1024,N=256,batch 64); MODE 1: h=relu(simh@W1t^T+b1);
// MODE 2: Z=h@W2t^T+b2 + fused column-sumsq partials (atomicAdd into part).
// ---------------------------------------------------------------------------
template <int MODE, bool RELU, bool BIAS>
__global__ __launch_bounds__(256) void k_mfma(const half_t* __restrict__ A,
                                              const half_t* __restrict__ Bt,
                                              const float* __restrict__ bias,
                                              half_t* __restrict__ out,
                                              float* __restrict__ part) {
  constexpr int K = (MODE == 0) ? 1024 : (MODE == 1) ? 256 : 512;
  constexpr int N = (MODE == 0) ? 256 : (MODE == 1) ? 512 : 256;
  __shared__ __align__(16) half_t Asm[128 * 64];
  __shared__ __align__(16) half_t Bsm[128 * 64];
  int z = blockIdx.z;
  size_t Aoff, Boff, Ooff;
  if (MODE == 0) {
    Aoff = (size_t)z * 256 * 1024; Boff = Aoff; Ooff = (size_t)z * 256 * 256;
  } else if (MODE == 1) {
    int l = z & 3, path = z >> 2;  // path0 = tk (teacher sim), path1 = tq (student)
    Aoff = ((size_t)((path == 0 ? 32 : 0) + l * 8)) * 256 * 256;
    Boff = (size_t)z * 512 * 256;
    Ooff = (size_t)z * 2048 * 512;
  } else {
    Aoff = (size_t)z * 2048 * 512; Boff = (size_t)z * 256 * 512; Ooff = (size_t)z * 2048 * 256;
  }
  const half_t* Ab = A + Aoff;
  const half_t* Bb = Bt + Boff;
  int mt = blockIdx.x, nt = blockIdx.y;
  int tid = threadIdx.x;
  int wave = tid >> 6, lane = tid & 63;
  int wm = (wave >> 1) * 64, wn = (wave & 1) * 64;
  int lr = lane & 15, lg = lane >> 4;
  f4 acc[4][4] = {};
  int r0 = tid >> 3, seg0 = tid & 7;
  int sw0 = (seg0 ^ (r0 & 7)) * 8;     // (r0+32j)&7 == r0&7
  for (int kc = 0; kc < K; kc += 64) {
    h8 av[4], bv[4];
#pragma unroll
    for (int j = 0; j < 4; j++) {
      av[j] = *(const h8*)(Ab + (size_t)(mt * 128 + r0 + 32 * j) * K + kc + seg0 * 8);
      bv[j] = *(const h8*)(Bb + (size_t)(nt * 128 + r0 + 32 * j) * K + kc + seg0 * 8);
    }
    __syncthreads();
#pragma unroll
    for (int j = 0; j < 4; j++) {
      *(h8*)(Asm + (r0 + 32 * j) * 64 + sw0) = av[j];
      *(h8*)(Bsm + (r0 + 32 * j) * 64 + sw0) = bv[j];
    }
    __syncthreads();
#pragma unroll
    for (int kk = 0; kk < 2; kk++) {
      h8 af[4], bf[4];
#pragma unroll
      for (int mf = 0; mf < 4; mf++) {
        int r = wm + mf * 16 + lr;
        af[mf] = *(const h8*)(Asm + r * 64 + (((kk * 4 + lg) ^ (r & 7)) * 8));
      }
#pragma unroll
      for (int nf = 0; nf < 4; nf++) {
        int r = wn + nf * 16 + lr;
        bf[nf] = *(const h8*)(Bsm + r * 64 + (((kk * 4 + lg) ^ (r & 7)) * 8));
      }
#pragma unroll
      for (int mf = 0; mf < 4; mf++)
#pragma unroll
        for (int nf = 0; nf < 4; nf++)
          acc[mf][nf] = __builtin_amdgcn_mfma_f32_16x16x32_f16(af[mf], bf[nf], acc[mf][nf], 0, 0, 0);
    }
  }
  half_t* Ob = out + Ooff;
#pragma unroll
  for (int nf = 0; nf < 4; nf++) {
    int col = nt * 128 + wn + nf * 16 + lr;
    float bv2 = BIAS ? bias[z * N + col] : 0.f;
    float colsq = 0.f;
#pragma unroll
    for (int mf = 0; mf < 4; mf++) {
#pragma unroll
      for (int rg = 0; rg < 4; rg++) {
        int row = mt * 128 + wm + mf * 16 + lg * 4 + rg;
        float v = acc[mf][nf][rg] + bv2;
        if (RELU) v = fmaxf(v, 0.f);
        Ob[(size_t)row * N + col] = (half_t)v;
        if (MODE == 2) colsq += v * v;
      }
    }
    if (MODE == 2) {
      colsq += __shfl_xor(colsq, 16);
      colsq += __shfl_xor(colsq, 32);
      if (lg == 0) {
        int b = mt >> 1;  // 128-row tile sits inside one 256-row b-group
        atomicAdd(&part[((z * 8 + b) << 8) + col], colsq);
      }
    }
  }
}

// ---------------------------------------------------------------------------
// k_cos_time2: both tensors in one launch. grid 16384 (tensor = bid>>13).
// ---------------------------------------------------------------------------
__global__ __launch_bounds__(256) void k_cos_time2(const half_t* __restrict__ simh,
                                                   const float* __restrict__ n,
                                                   float* __restrict__ out_stu,
                                                   float* __restrict__ out_tea) {
  __shared__ float red[4];
  __shared__ float rs;
  int tensor = blockIdx.x >> 13;
  int bid = blockIdx.x & 8191;  // lb*256 + t
  const half_t* sh = simh + (size_t)tensor * 2097152;
  const float* nb2 = n + tensor * 8192;
  float* out = tensor ? out_tea : out_stu;
  int t = bid & 255;
  int lb = bid >> 8;
  int l = lb >> 3, b = lb & 7;
  int s = threadIdx.x;
  float nt = nb2[lb * 256 + t] + REPS;
  float ns = nb2[lb * 256 + s] + REPS;
  float v = ((float)sh[(size_t)bid * 256 + s] / (nt * ns) + 1.f) * 0.5f;
  float w = v;
  for (int m = 32; m >= 1; m >>= 1) w += __shfl_xor(w, m);
  if ((threadIdx.x & 63) == 0) red[threadIdx.x >> 6] = w;
  __syncthreads();
  if (threadIdx.x == 0) rs = red[0] + red[1] + red[2] + red[3];
  __syncthreads();
  v /= rs;
  size_t inner = ((size_t)(b * 256 + t)) * 256 + s;
  if (tensor == 0) {
    size_t base = (size_t)l * 4 * 524288;
#pragma unroll
    for (int j = 0; j < 4; j++) out[base + (size_t)j * 524288 + inner] = v;
  } else {
#pragma unroll
    for (int i = 0; i < 4; i++) out[((size_t)(i * 4 + l)) * 524288 + inner] = v;
  }
}

__global__ __launch_bounds__(256) void k_cos_freq2(const float* __restrict__ simg,
                                                   const float* __restrict__ n,
                                                   float* __restrict__ out_stu,
                                                   float* __restrict__ out_tea) {
  int tensor = blockIdx.x >> 5;
  int lb = blockIdx.x & 31;
  const float* sg = simg + (size_t)tensor * 65536;
  const float* nb2 = n + tensor * 8192;
  float* out = tensor ? out_tea : out_stu;
  int l = lb >> 3, b = lb & 7;
  int tid = threadIdx.x;
  int a = tid & 7;
  for (int tc = 0; tc < 8; tc++) {
    int t = tc * 32 + (tid >> 3);
    float nb = nb2[lb * 256 + t] + REPS;
    float na = nb2[(l * 8 + a) * 256 + t] + REPS;
    float v = (sg[((size_t)lb * 256 + t) * 8 + a] / (nb * na) + 1.f) * 0.5f;
    float w = v;
    for (int m = 1; m < 8; m <<= 1) w += __shfl_xor(w, m);
    v /= w;
    size_t inner = ((size_t)(b * 256 + t)) * 8 + a;
    if (tensor == 0) {
#pragma unroll
      for (int j = 0; j < 4; j++) out[((size_t)(l * 4 + j)) * 16384 + inner] = v;
    } else {
#pragma unroll
      for (int i = 0; i < 4; i++) out[((size_t)(i * 4 + l)) * 16384 + inner] = v;
    }
  }
}

// ---------------------------------------------------------------------------
// Fused freq MLP, both tensors: tensor0 = student->fq weights, 1 = teacher->fk.
// ---------------------------------------------------------------------------
__global__ __launch_bounds__(256) void k_fmlp2(const float* __restrict__ simg,
                                               const float* __restrict__ qw1, const float* __restrict__ qb1,
                                               const float* __restrict__ qw2, const float* __restrict__ qb2,
                                               const float* __restrict__ kw1, const float* __restrict__ kb1,
                                               const float* __restrict__ kw2, const float* __restrict__ kb2,
                                               float* __restrict__ qout, float* __restrict__ kout) {
  __shared__ float sw1[8 * 32], sb1[32], sw2[32 * 32], sb2[32];
  __shared__ float zs[256][33];
  __shared__ float pcn[8][33];
  __shared__ float cn[32];
  int tensor = blockIdx.x >> 5;
  int lb = blockIdx.x & 31;
  int l = lb >> 3;
  const float* w1 = tensor ? kw1 : qw1;
  const float* b1 = tensor ? kb1 : qb1;
  const float* w2 = tensor ? kw2 : qw2;
  const float* b2 = tensor ? kb2 : qb2;
  const float* sg = simg + (size_t)tensor * 65536;
  float* outp = tensor ? kout : qout;
  int t = threadIdx.x;
  sw1[t] = w1[l * 256 + t];
  if (t < 32) { sb1[t] = b1[l * 32 + t]; sb2[t] = b2[l * 32 + t]; }
  for (int q = t; q < 1024; q += 256) sw2[q] = w2[l * 1024 + q];
  __syncthreads();
  float x[8];
#pragma unroll
  for (int a = 0; a < 8; a++) x[a] = sg[((size_t)lb * 256 + t) * 8 + a];
  float h[32];
#pragma unroll
  for (int f = 0; f < 32; f++) {
    float acc = sb1[f];
#pragma unroll
    for (int a = 0; a < 8; a++) acc += x[a] * sw1[a * 32 + f];
    h[f] = fmaxf(acc, 0.f);
  }
#pragma unroll
  for (int g = 0; g < 32; g++) {
    float acc = sb2[g];
#pragma unroll
    for (int f = 0; f < 32; f++) acc += h[f] * sw2[f * 32 + g];
    zs[t][g] = acc;
  }
  __syncthreads();
  {
    int col = t & 31, ch = t >> 5;
    float sq = 0.f;
    for (int r = ch * 32; r < ch * 32 + 32; r++) { float v = zs[r][col]; sq += v * v; }
    pcn[ch][col] = sq;
  }
  __syncthreads();
  if (t < 32) {
    float ssum = 0.f;
#pragma unroll
    for (int c = 0; c < 8; c++) ssum += pcn[c][t];
    cn[t] = sqrtf(ssum);
  }
  __syncthreads();
#pragma unroll
  for (int g = 0; g < 32; g++)
    outp[((size_t)lb * 256 + t) * 32 + g] = zs[t][g] / cn[g];
}

// time attention: att[b,t,i,j] = softmax_j( sum_s (Zq*rsqrt(pq))(Zk*rsqrt(pk)) )
// part: [z(8)][b(8)][s(256)] column sumsq from k_mfma<2> epilogue.
__global__ __launch_bounds__(64) void k_att_time(const half_t* __restrict__ Zq,
                                                 const half_t* __restrict__ Zk,
                                                 const float* __restrict__ part,
                                                 float* __restrict__ outp) {
  int bt = blockIdx.x;
  int b = bt >> 8, t = bt & 255;
  int lane = threadIdx.x;
  float acc[4][4];
#pragma unroll
  for (int i = 0; i < 4; i++)
#pragma unroll
    for (int j = 0; j < 4; j++) acc[i][j] = 0.f;
  for (int it = 0; it < 4; it++) {
    int s = lane + it * 64;
    float qv[4], kv[4];
#pragma unroll
    for (int i = 0; i < 4; i++) {
      size_t lbO = (size_t)(i * 8 + b);
      float pq = part[(((4 + i) * 8 + b) << 8) + s];
      float pk = part[(((i) * 8 + b) << 8) + s];
      qv[i] = (float)Zq[(lbO * 256 + t) * 256 + s] * rsqrtf(pq);
      kv[i] = (float)Zk[(lbO * 256 + t) * 256 + s] * rsqrtf(pk);
    }
#pragma unroll
    for (int i = 0; i < 4; i++)
#pragma unroll
      for (int j = 0; j < 4; j++) acc[i][j] += qv[i] * kv[j];
  }
#pragma unroll
  for (int i = 0; i < 4; i++)
#pragma unroll
    for (int j = 0; j < 4; j++)
      for (int m = 32; m >= 1; m >>= 1) acc[i][j] += __shfl_xor(acc[i][j], m);
  if (lane < 16) {
    int i = lane >> 2, j = lane & 3;
    float mx = fmaxf(fmaxf(acc[i][0], acc[i][1]), fmaxf(acc[i][2], acc[i][3]));
    float sum = expf(acc[i][0] - mx) + expf(acc[i][1] - mx) + expf(acc[i][2] - mx) + expf(acc[i][3] - mx);
    outp[(size_t)bt * 16 + lane] = expf(acc[i][j] - mx) / sum;
  }
}

__global__ __launch_bounds__(64) void k_att_freq(const float* __restrict__ fq,
                                                 const float* __restrict__ fk,
                                                 float* __restrict__ outp) {
  int pair = blockIdx.x;
  int b = pair >> 7, tp = pair & 127;
  int lane = threadIdx.x;
  int t = tp * 2 + (lane >> 5);
  int f = lane & 31;
  float qv[4], kv[4];
#pragma unroll
  for (int i = 0; i < 4; i++) {
    size_t lbO = (size_t)(i * 8 + b);
    qv[i] = fq[(lbO * 256 + t) * 32 + f];
    kv[i] = fk[(lbO * 256 + t) * 32 + f];
  }
  float acc[4][4];
#pragma unroll
  for (int i = 0; i < 4; i++)
#pragma unroll
    for (int j = 0; j < 4; j++) acc[i][j] = qv[i] * kv[j];
#pragma unroll
  for (int i = 0; i < 4; i++)
#pragma unroll
    for (int j = 0; j < 4; j++)
      for (int m = 16; m >= 1; m >>= 1) acc[i][j] += __shfl_xor(acc[i][j], m);
  int fl = lane & 31;
  if (fl < 16) {
    int i = fl >> 2, j = fl & 3;
    float mx = fmaxf(fmaxf(acc[i][0], acc[i][1]), fmaxf(acc[i][2], acc[i][3]));
    float sum = expf(acc[i][0] - mx) + expf(acc[i][1] - mx) + expf(acc[i][2] - mx) + expf(acc[i][3] - mx);
    outp[((size_t)(b * 256 + t)) * 16 + fl] = expf(acc[i][j] - mx) / sum;
  }
}

// ---------------------------------------------------------------------------
extern "C" void kernel_launch(void* const* d_in, const int* in_sizes, int n_in,
                              void* d_out, int out_size, void* d_ws, size_t ws_size,
                              hipStream_t stream) {
  (void)in_sizes; (void)n_in; (void)out_size; (void)ws_size;
  const float* feat_s = (const float*)d_in[0];
  const float* feat_t = (const float*)d_in[1];
  const float* tk_w1 = (const float*)d_in[2];
  const float* tk_b1 = (const float*)d_in[3];
  const float* tk_w2 = (const float*)d_in[4];
  const float* tk_b2 = (const float*)d_in[5];
  const float* fk_w1 = (const float*)d_in[6];
  const float* fk_b1 = (const float*)d_in[7];
  const float* fk_w2 = (const float*)d_in[8];
  const float* fk_b2 = (const float*)d_in[9];
  const float* tq_w1 = (const float*)d_in[10];
  const float* tq_b1 = (const float*)d_in[11];
  const float* tq_w2 = (const float*)d_in[12];
  const float* tq_b2 = (const float*)d_in[13];
  const float* fq_w1 = (const float*)d_in[14];
  const float* fq_b1 = (const float*)d_in[15];
  const float* fq_w2 = (const float*)d_in[16];
  const float* fq_b2 = (const float*)d_in[17];

  float* ws = (float*)d_ws;
  // Xh16 region (33.5MB); after k_mfma<0>+k_simg consume it, h and Z alias it.
  half_t* Xh   = (half_t*)ws;                 // 16.8M halves
  half_t* hbuf = (half_t*)ws;                 // 8*2048*512 halves (alias, after gram)
  half_t* Zbuf = (half_t*)(ws + 4194304);     // 8*2048*256 halves (alias, after gram)
  half_t* simh = (half_t*)(ws + 8388608);     // 64*65536 halves
  half_t* W1t  = (half_t*)(ws + 10485760);    // 8*512*256 halves
  half_t* W2t  = (half_t*)(ws + 11010048);    // 8*256*512 halves
  float* Bc1   = ws + 11534336;               // 8*512
  float* Bc2   = ws + 11538432;               // 8*256
  float* simg  = ws + 11540480;               // 2*65536
  float* nrm   = ws + 11671552;               // 2*8192
  float* part  = ws + 11687936;               // 8*8*256 = 16384 (colnorm sumsq)
  float* fkb   = ws + 11704320;               // 262144
  float* fqb   = ws + 11966464;               // 262144

  float* out = (float*)d_out;
  float* out_stu_time = out;               // [4,4,8,256,256]
  float* out_stu_freq = out + 8388608;     // [4,4,8,256,8]
  float* out_tea_time = out + 8650752;     // [4,4,8,256,256]
  float* out_tea_freq = out + 17039360;    // [4,4,8,256,8]
  float* out_time_att = out + 17301504;    // [8,256,4,4]
  float* out_freq_att = out + 17334272;    // [8,256,4,4]

  // 1) weight transpose+convert, bias concat, zero part
  hipLaunchKernelGGL(k_wconv, dim3(513), dim3(256), 0, stream,
                     tk_w1, tq_w1, tk_w2, tq_w2, tk_b1, tq_b1, tk_b2, tq_b2,
                     W1t, W2t, Bc1, Bc2, part);
  // 2) transpose/convert feat -> Xh fp16 + norms
  hipLaunchKernelGGL(k_x2h, dim3(256), dim3(256), 0, stream, feat_s, feat_t, Xh, nrm);
  // 3) freq gram from fp16 panel (LDS + dot2)
  hipLaunchKernelGGL(k_simg, dim3(512), dim3(256), 0, stream, Xh, simg);
  // 4) time gram via MFMA (128x128 tile) -> simh fp16
  hipLaunchKernelGGL((k_mfma<0, false, false>), dim3(2, 2, 64), dim3(256), 0, stream,
                     Xh, Xh, (const float*)nullptr, simh, (float*)nullptr);
  // 5) cosine outputs
  hipLaunchKernelGGL(k_cos_time2, dim3(16384), dim3(256), 0, stream, simh, nrm,
                     out_stu_time, out_tea_time);
  hipLaunchKernelGGL(k_cos_freq2, dim3(64), dim3(256), 0, stream, simg, nrm,
                     out_stu_freq, out_tea_freq);
  // 6) freq MLPs (tensor0 = student -> fq, tensor1 = teacher -> fk)
  hipLaunchKernelGGL(k_fmlp2, dim3(64), dim3(256), 0, stream, simg,
                     fq_w1, fq_b1, fq_w2, fq_b2, fk_w1, fk_b1, fk_w2, fk_b2, fqb, fkb);
  // 7) frame MLPs via MFMA 128x128 (h and Z alias the now-dead Xh region);
  //    mode2 epilogue accumulates column sumsq into part.
  hipLaunchKernelGGL((k_mfma<1, true, true>), dim3(16, 4, 8), dim3(256), 0, stream,
                     simh, W1t, Bc1, hbuf, (float*)nullptr);
  hipLaunchKernelGGL((k_mfma<2, false, true>), dim3(16, 2, 8), dim3(256), 0, stream,
                     hbuf, W2t, Bc2, Zbuf, part);
  // 8) attention (norms from part, inline rsqrt)
  hipLaunchKernelGGL(k_att_time, dim3(2048), dim3(64), 0, stream,
                     Zbuf + (size_t)4 * 2048 * 256, Zbuf, part, out_time_att);
  hipLaunchKernelGGL(k_att_freq, dim3(1024), dim3(64), 0, stream, fqb, fkb, out_freq_att);
}

// Round 6
// 129.843 us; speedup vs baseline: 4.3660x; 1.2210x over previous
//
#include <hip/hip_runtime.h>
#include <math.h>

// Problem constants: s_len=t_len=4, B=8, C=64, T=256, D=16, H=512, F=32
typedef _Float16 half_t;
typedef _Float16 h2 __attribute__((ext_vector_type(2)));
typedef _Float16 h4 __attribute__((ext_vector_type(4)));
typedef _Float16 h8 __attribute__((ext_vector_type(8)));
typedef float f4 __attribute__((ext_vector_type(4)));
static constexpr float REPS = 1e-6f;

// ---------------------------------------------------------------------------
// k_prep2 = wconv (blocks 0-512) + x2h (blocks 513-768).
// wconv: transpose+convert weights to fp16 [z][N][K] (z = tk l0-3, tq l4-7),
// concat biases fp32, zero colnorm-partials.
// x2h: LDS-free transpose/convert feat -> Xh fp16 [row][k=c*16+d] + row norms.
// ---------------------------------------------------------------------------
__global__ __launch_bounds__(256) void k_prep2(const float* __restrict__ tkw1, const float* __restrict__ tqw1,
                                               const float* __restrict__ tkw2, const float* __restrict__ tqw2,
                                               const float* __restrict__ tkb1, const float* __restrict__ tqb1,
                                               const float* __restrict__ tkb2, const float* __restrict__ tqb2,
                                               half_t* __restrict__ W1t, half_t* __restrict__ W2t,
                                               float* __restrict__ Bc1, float* __restrict__ Bc2,
                                               float* __restrict__ part,
                                               const float* __restrict__ fs, const float* __restrict__ ft,
                                               half_t* __restrict__ Xh, float* __restrict__ nrm) {
  __shared__ float T[64][65];
  int bid = blockIdx.x;
  int tid = threadIdx.x;
  if (bid < 256) {  // W1: [l][256 k][512 n] -> [z][512 n][256 k]
    int z = bid >> 5, tile = bid & 31;
    int kt = tile >> 3, ntile = tile & 7;
    const float* src = (z < 4 ? tkw1 : tqw1) + (size_t)(z & 3) * 256 * 512;
#pragma unroll
    for (int q = 0; q < 16; q++) {
      int e = q * 256 + tid;
      int r = e >> 6, c = e & 63;
      T[r][c] = src[(size_t)(kt * 64 + r) * 512 + ntile * 64 + c];
    }
    __syncthreads();
#pragma unroll
    for (int q = 0; q < 16; q++) {
      int e = q * 256 + tid;
      int nn = e >> 6, kk = e & 63;
      W1t[(size_t)z * 512 * 256 + (size_t)(ntile * 64 + nn) * 256 + kt * 64 + kk] = (half_t)T[kk][nn];
    }
  } else if (bid < 512) {  // W2: [l][512 k][256 n] -> [z][256 n][512 k]
    int bb = bid - 256;
    int z = bb >> 5, tile = bb & 31;
    int kt = tile >> 2, ntile = tile & 3;
    const float* src = (z < 4 ? tkw2 : tqw2) + (size_t)(z & 3) * 512 * 256;
#pragma unroll
    for (int q = 0; q < 16; q++) {
      int e = q * 256 + tid;
      int r = e >> 6, c = e & 63;
      T[r][c] = src[(size_t)(kt * 64 + r) * 256 + ntile * 64 + c];
    }
    __syncthreads();
#pragma unroll
    for (int q = 0; q < 16; q++) {
      int e = q * 256 + tid;
      int nn = e >> 6, kk = e & 63;
      W2t[(size_t)z * 256 * 512 + (size_t)(ntile * 64 + nn) * 512 + kt * 64 + kk] = (half_t)T[kk][nn];
    }
  } else if (bid == 512) {
    for (int e = tid; e < 4096; e += 256) {
      int z = e >> 9, n = e & 511;
      Bc1[e] = (z < 4 ? tkb1 : tqb1)[(z & 3) * 512 + n];
    }
    for (int e = tid; e < 2048; e += 256) {
      int z = e >> 8, n = e & 255;
      Bc2[e] = (z < 4 ? tkb2 : tqb2)[(z & 3) * 256 + n];
    }
    for (int e = tid; e < 16384; e += 256) part[e] = 0.f;
  } else {  // x2h: bid2 = tensor*128 + l*32 + b*4 + tc
    int bid2 = bid - 513;
    int tensor = bid2 >> 7;
    int l = (bid2 >> 5) & 3;
    int b = (bid2 >> 2) & 7;
    int tc = bid2 & 3;
    int tl = tid >> 2;           // 0..63
    int d0 = (tid & 3) * 4;
    int t = tc * 64 + tl;
    const float* base = (tensor ? ft : fs) + (size_t)((l * 8 + b) * 64) * 4096 + t * 16 + d0;
    size_t row = (size_t)(tensor * 32 + l * 8 + b) * 256 + t;
    half_t* xrow = Xh + row * 1024 + d0;
    float acc = 0.f;
#pragma unroll 8
    for (int c = 0; c < 64; c++) {
      float4 v = *(const float4*)(base + (size_t)c * 4096);
      acc += v.x * v.x + v.y * v.y + v.z * v.z + v.w * v.w;
      h4 hv;
      hv[0] = (half_t)v.x; hv[1] = (half_t)v.y; hv[2] = (half_t)v.z; hv[3] = (half_t)v.w;
      *(h4*)(xrow + c * 16) = hv;
    }
    acc += __shfl_xor(acc, 1);
    acc += __shfl_xor(acc, 2);
    if ((tid & 3) == 0) nrm[row] = sqrtf(acc);
  }
}

// ---------------------------------------------------------------------------
// k_simg: freq gram via LDS staging + v_dot2_f32_f16.
// Block = (tensor, l, 4 t's); grid 512; 256 threads.
// ---------------------------------------------------------------------------
__global__ __launch_bounds__(256) void k_simg(const half_t* __restrict__ Xh,
                                              float* __restrict__ simg) {
  __shared__ __align__(16) half_t X[32 * 1032];
  int bid = blockIdx.x;
  int tensor = bid >> 8;
  int l = (bid >> 6) & 3;
  int tc = bid & 63;
  int t0 = tc * 4;
  int tid = threadIdx.x;
  {
    int r = tid >> 3, q = tid & 7;
    int b = r & 7, tl = r >> 3;
    const half_t* src = Xh + ((size_t)(tensor * 32 + l * 8 + b) * 256 + t0 + tl) * 1024;
    half_t* dst = X + (tl * 8 + b) * 1032;
    int c0 = q ^ (r & 7);
#pragma unroll
    for (int j = 0; j < 16; j++) {
      int c = c0 + 8 * j;
      *(h8*)(dst + c * 8) = *(const h8*)(src + c * 8);
    }
  }
  __syncthreads();
  int tl = tid >> 6;   // 0..3
  int ab = tid & 63;
  int b = ab >> 3, a = ab & 7;
  const half_t* xa = X + (tl * 8 + b) * 1032;
  const half_t* xb = X + (tl * 8 + a) * 1032;
  float acc = 0.f;
#pragma unroll 8
  for (int k = 0; k < 1024; k += 8) {
    h8 va = *(const h8*)(xa + k);
    h8 vb = *(const h8*)(xb + k);
#if __has_builtin(__builtin_amdgcn_fdot2)
#pragma unroll
    for (int i = 0; i < 4; i++) {
      h2 pa, pb;
      pa[0] = va[2 * i]; pa[1] = va[2 * i + 1];
      pb[0] = vb[2 * i]; pb[1] = vb[2 * i + 1];
      acc = __builtin_amdgcn_fdot2(pa, pb, acc, false);
    }
#else
#pragma unroll
    for (int e = 0; e < 8; e++) acc += (float)va[e] * (float)vb[e];
#endif
  }
  simg[(size_t)tensor * 65536 + ((size_t)(l * 8 + b) * 256 + t0 + tl) * 8 + a] = acc;
}

// ---------------------------------------------------------------------------
// k_gram_cos: time gram + cosine output, fused. BM=64 x BN=256 tile, BK=64,
// 8 waves (512 thr), wave tile 32x64. A-fragments read from the symmetric
// B-panel (all 256 rows staged). Epilogue: simh fp16 + full-row cosine
// normalize + rowsum + 4x broadcast write to out_stu/out_tea.
// grid (4 mt, 64 z); z = tensor*32 + l*8 + b.
// ---------------------------------------------------------------------------
__global__ __launch_bounds__(512) void k_gram_cos(const half_t* __restrict__ Xh,
                                                  const float* __restrict__ nrm,
                                                  half_t* __restrict__ simh,
                                                  float* __restrict__ out_stu,
                                                  float* __restrict__ out_tea) {
  __shared__ __align__(16) half_t Bsm[256 * 64];
  __shared__ float rspart[64][4];
  __shared__ float rowsumS[64];
  int mt = blockIdx.x;   // 0..3
  int z = blockIdx.y;    // 0..63
  const half_t* Bb = Xh + (size_t)z * 256 * 1024;
  int tid = threadIdx.x;
  int w = tid >> 6, lane = tid & 63;
  int wm = w >> 2, wn = w & 3;     // wave tile: rows wm*32, cols wn*64
  int lr = lane & 15, lg = lane >> 4;
  f4 acc[2][4] = {};
  int r0 = tid >> 3, seg0 = tid & 7;
  int sw0 = (seg0 ^ (r0 & 7)) * 8;
  for (int kc = 0; kc < 1024; kc += 64) {
    h8 bv[4];
#pragma unroll
    for (int it = 0; it < 4; it++)
      bv[it] = *(const h8*)(Bb + (size_t)(it * 64 + r0) * 1024 + kc + seg0 * 8);
    __syncthreads();
#pragma unroll
    for (int it = 0; it < 4; it++)
      *(h8*)(Bsm + (it * 64 + r0) * 64 + sw0) = bv[it];
    __syncthreads();
#pragma unroll
    for (int kk = 0; kk < 2; kk++) {
      int g = kk * 4 + lg;
      h8 af[2], bf[4];
#pragma unroll
      for (int mf = 0; mf < 2; mf++) {
        int rA = mt * 64 + wm * 32 + mf * 16 + lr;
        af[mf] = *(const h8*)(Bsm + rA * 64 + ((g ^ (rA & 7)) * 8));
      }
#pragma unroll
      for (int nf = 0; nf < 4; nf++) {
        int rB = wn * 64 + nf * 16 + lr;
        bf[nf] = *(const h8*)(Bsm + rB * 64 + ((g ^ (rB & 7)) * 8));
      }
#pragma unroll
      for (int mf = 0; mf < 2; mf++)
#pragma unroll
        for (int nf = 0; nf < 4; nf++)
          acc[mf][nf] = __builtin_amdgcn_mfma_f32_16x16x32_f16(af[mf], bf[nf], acc[mf][nf], 0, 0, 0);
    }
  }
  // --- epilogue ---
  int tensor = z >> 5, l = (z >> 3) & 3, b = z & 7;
  const float* nz = nrm + z * 256;
  float nc[4];
  int cols[4];
#pragma unroll
  for (int nf = 0; nf < 4; nf++) {
    cols[nf] = wn * 64 + nf * 16 + lr;
    nc[nf] = nz[cols[nf]] + REPS;
  }
  float v[2][4][4];
  float rowpart[2][4];
#pragma unroll
  for (int mf = 0; mf < 2; mf++) {
#pragma unroll
    for (int rg = 0; rg < 4; rg++) {
      int rib = wm * 32 + mf * 16 + lg * 4 + rg;          // row in block
      float nr = nz[mt * 64 + rib] + REPS;
      float p = 0.f;
#pragma unroll
      for (int nf = 0; nf < 4; nf++) {
        float S = acc[mf][nf][rg];
        float vv = fmaf(S / (nr * nc[nf]), 0.5f, 0.5f);
        v[mf][nf][rg] = vv;
        p += vv;
        // raw gram for MLP input
        simh[(size_t)z * 65536 + (size_t)(mt * 64 + rib) * 256 + cols[nf]] = (half_t)S;
      }
      rowpart[mf][rg] = p;
    }
  }
  // reduce rowpart over the 16 lr lanes (lane bits 0-3)
#pragma unroll
  for (int mf = 0; mf < 2; mf++)
#pragma unroll
    for (int rg = 0; rg < 4; rg++) {
      float p = rowpart[mf][rg];
      p += __shfl_xor(p, 1); p += __shfl_xor(p, 2);
      p += __shfl_xor(p, 4); p += __shfl_xor(p, 8);
      rowpart[mf][rg] = p;
    }
  if (lr == 0) {
#pragma unroll
    for (int mf = 0; mf < 2; mf++)
#pragma unroll
      for (int rg = 0; rg < 4; rg++)
        rspart[wm * 32 + mf * 16 + lg * 4 + rg][wn] = rowpart[mf][rg];
  }
  __syncthreads();
  if (tid < 64)
    rowsumS[tid] = rspart[tid][0] + rspart[tid][1] + rspart[tid][2] + rspart[tid][3];
  __syncthreads();
  float* outp = tensor ? out_tea : out_stu;
#pragma unroll
  for (int mf = 0; mf < 2; mf++) {
#pragma unroll
    for (int rg = 0; rg < 4; rg++) {
      int rib = wm * 32 + mf * 16 + lg * 4 + rg;
      int t = mt * 64 + rib;
      float inv = 1.f / rowsumS[rib];
#pragma unroll
      for (int nf = 0; nf < 4; nf++) {
        float val = v[mf][nf][rg] * inv;
        size_t inner = ((size_t)(b * 256 + t)) * 256 + cols[nf];
        if (tensor == 0) {
          size_t base = (size_t)l * 4 * 524288;
#pragma unroll
          for (int j = 0; j < 4; j++) outp[base + (size_t)j * 524288 + inner] = val;
        } else {
#pragma unroll
          for (int i = 0; i < 4; i++) outp[((size_t)(i * 4 + l)) * 524288 + inner] = val;
        }
      }
    }
  }
}

// ---------------------------------------------------------------------------
// Unified fp16 MFMA GEMM, 128x128 tile, BK=64, 4 waves x (64x64), XOR swizzle.
// MODE 1: h=relu(simh@W1t^T+b1); MODE 2: Z=h@W2t^T+b2 + column-sumsq atomics.
// ---------------------------------------------------------------------------
template <int MODE, bool RELU, bool BIAS>
__global__ __launch_bounds__(256) void k_mfma(const half_t* __restrict__ A,
                                              const half_t* __restrict__ Bt,
                                              const float* __restrict__ bias,
                                              half_t* __restrict__ out,
                                              float* __restrict__ part) {
  constexpr int K = (MODE == 1) ? 256 : 512;
  constexpr int N = (MODE == 1) ? 512 : 256;
  __shared__ __align__(16) half_t Asm[128 * 64];
  __shared__ __align__(16) half_t Bsm[128 * 64];
  int z = blockIdx.z;
  size_t Aoff, Boff, Ooff;
  if (MODE == 1) {
    int l = z & 3, path = z >> 2;  // path0 = tk (teacher sim), path1 = tq (student)
    Aoff = ((size_t)((path == 0 ? 32 : 0) + l * 8)) * 256 * 256;
    Boff = (size_t)z * 512 * 256;
    Ooff = (size_t)z * 2048 * 512;
  } else {
    Aoff = (size_t)z * 2048 * 512; Boff = (size_t)z * 256 * 512; Ooff = (size_t)z * 2048 * 256;
  }
  const half_t* Ab = A + Aoff;
  const half_t* Bb = Bt + Boff;
  int mt = blockIdx.x, nt = blockIdx.y;
  int tid = threadIdx.x;
  int wave = tid >> 6, lane = tid & 63;
  int wm = (wave >> 1) * 64, wn = (wave & 1) * 64;
  int lr = lane & 15, lg = lane >> 4;
  f4 acc[4][4] = {};
  int r0 = tid >> 3, seg0 = tid & 7;
  int sw0 = (seg0 ^ (r0 & 7)) * 8;
  for (int kc = 0; kc < K; kc += 64) {
    h8 av[4], bv[4];
#pragma unroll
    for (int j = 0; j < 4; j++) {
      av[j] = *(const h8*)(Ab + (size_t)(mt * 128 + r0 + 32 * j) * K + kc + seg0 * 8);
      bv[j] = *(const h8*)(Bb + (size_t)(nt * 128 + r0 + 32 * j) * K + kc + seg0 * 8);
    }
    __syncthreads();
#pragma unroll
    for (int j = 0; j < 4; j++) {
      *(h8*)(Asm + (r0 + 32 * j) * 64 + sw0) = av[j];
      *(h8*)(Bsm + (r0 + 32 * j) * 64 + sw0) = bv[j];
    }
    __syncthreads();
#pragma unroll
    for (int kk = 0; kk < 2; kk++) {
      h8 af[4], bf[4];
#pragma unroll
      for (int mf = 0; mf < 4; mf++) {
        int r = wm + mf * 16 + lr;
        af[mf] = *(const h8*)(Asm + r * 64 + (((kk * 4 + lg) ^ (r & 7)) * 8));
      }
#pragma unroll
      for (int nf = 0; nf < 4; nf++) {
        int r = wn + nf * 16 + lr;
        bf[nf] = *(const h8*)(Bsm + r * 64 + (((kk * 4 + lg) ^ (r & 7)) * 8));
      }
#pragma unroll
      for (int mf = 0; mf < 4; mf++)
#pragma unroll
        for (int nf = 0; nf < 4; nf++)
          acc[mf][nf] = __builtin_amdgcn_mfma_f32_16x16x32_f16(af[mf], bf[nf], acc[mf][nf], 0, 0, 0);
    }
  }
  half_t* Ob = out + Ooff;
#pragma unroll
  for (int nf = 0; nf < 4; nf++) {
    int col = nt * 128 + wn + nf * 16 + lr;
    float bv2 = BIAS ? bias[z * N + col] : 0.f;
    float colsq = 0.f;
#pragma unroll
    for (int mf = 0; mf < 4; mf++) {
#pragma unroll
      for (int rg = 0; rg < 4; rg++) {
        int row = mt * 128 + wm + mf * 16 + lg * 4 + rg;
        float v = acc[mf][nf][rg] + bv2;
        if (RELU) v = fmaxf(v, 0.f);
        Ob[(size_t)row * N + col] = (half_t)v;
        if (MODE == 2) colsq += v * v;
      }
    }
    if (MODE == 2) {
      colsq += __shfl_xor(colsq, 16);
      colsq += __shfl_xor(colsq, 32);
      if (lg == 0) {
        int b = mt >> 1;  // 128-row tile sits inside one 256-row b-group
        atomicAdd(&part[((z * 8 + b) << 8) + col], colsq);
      }
    }
  }
}

// ---------------------------------------------------------------------------
// k_small = cos_freq (blocks 0-63) + freq MLP (blocks 64-127).
// ---------------------------------------------------------------------------
__global__ __launch_bounds__(256) void k_small(const float* __restrict__ simg,
                                               const float* __restrict__ n,
                                               float* __restrict__ out_stu, float* __restrict__ out_tea,
                                               const float* __restrict__ qw1, const float* __restrict__ qb1,
                                               const float* __restrict__ qw2, const float* __restrict__ qb2,
                                               const float* __restrict__ kw1, const float* __restrict__ kb1,
                                               const float* __restrict__ kw2, const float* __restrict__ kb2,
                                               float* __restrict__ qout, float* __restrict__ kout) {
  __shared__ float sw1[8 * 32], sb1[32], sw2[32 * 32], sb2[32];
  __shared__ float zs[256][33];
  __shared__ float pcn[8][33];
  __shared__ float cn[32];
  int bid = blockIdx.x;
  int tid = threadIdx.x;
  if (bid < 64) {  // cos_freq
    int tensor = bid >> 5;
    int lb = bid & 31;
    const float* sg = simg + (size_t)tensor * 65536;
    const float* nb2 = n + tensor * 8192;
    float* out = tensor ? out_tea : out_stu;
    int l = lb >> 3, b = lb & 7;
    int a = tid & 7;
    for (int tc = 0; tc < 8; tc++) {
      int t = tc * 32 + (tid >> 3);
      float nb = nb2[lb * 256 + t] + REPS;
      float na = nb2[(l * 8 + a) * 256 + t] + REPS;
      float v = (sg[((size_t)lb * 256 + t) * 8 + a] / (nb * na) + 1.f) * 0.5f;
      float w = v;
      for (int m = 1; m < 8; m <<= 1) w += __shfl_xor(w, m);
      v /= w;
      size_t inner = ((size_t)(b * 256 + t)) * 8 + a;
      if (tensor == 0) {
#pragma unroll
        for (int j = 0; j < 4; j++) out[((size_t)(l * 4 + j)) * 16384 + inner] = v;
      } else {
#pragma unroll
        for (int i = 0; i < 4; i++) out[((size_t)(i * 4 + l)) * 16384 + inner] = v;
      }
    }
  } else {  // fmlp: tensor0 = student -> fq, tensor1 = teacher -> fk
    int bb = bid - 64;
    int tensor = bb >> 5;
    int lb = bb & 31;
    int l = lb >> 3;
    const float* w1 = tensor ? kw1 : qw1;
    const float* b1 = tensor ? kb1 : qb1;
    const float* w2 = tensor ? kw2 : qw2;
    const float* b2 = tensor ? kb2 : qb2;
    const float* sg = simg + (size_t)tensor * 65536;
    float* outp = tensor ? kout : qout;
    int t = tid;
    sw1[t] = w1[l * 256 + t];
    if (t < 32) { sb1[t] = b1[l * 32 + t]; sb2[t] = b2[l * 32 + t]; }
    for (int q = t; q < 1024; q += 256) sw2[q] = w2[l * 1024 + q];
    __syncthreads();
    float x[8];
#pragma unroll
    for (int a = 0; a < 8; a++) x[a] = sg[((size_t)lb * 256 + t) * 8 + a];
    float h[32];
#pragma unroll
    for (int f = 0; f < 32; f++) {
      float acc = sb1[f];
#pragma unroll
      for (int a = 0; a < 8; a++) acc += x[a] * sw1[a * 32 + f];
      h[f] = fmaxf(acc, 0.f);
    }
#pragma unroll
    for (int g = 0; g < 32; g++) {
      float acc = sb2[g];
#pragma unroll
      for (int f = 0; f < 32; f++) acc += h[f] * sw2[f * 32 + g];
      zs[t][g] = acc;
    }
    __syncthreads();
    {
      int col = t & 31, ch = t >> 5;
      float sq = 0.f;
      for (int r = ch * 32; r < ch * 32 + 32; r++) { float v = zs[r][col]; sq += v * v; }
      pcn[ch][col] = sq;
    }
    __syncthreads();
    if (t < 32) {
      float ssum = 0.f;
#pragma unroll
      for (int c = 0; c < 8; c++) ssum += pcn[c][t];
      cn[t] = sqrtf(ssum);
    }
    __syncthreads();
#pragma unroll
    for (int g = 0; g < 32; g++)
      outp[((size_t)lb * 256 + t) * 32 + g] = zs[t][g] / cn[g];
  }
}

// ---------------------------------------------------------------------------
// k_att = time attention (blocks 0-2047) + freq attention (blocks 2048-3071).
// ---------------------------------------------------------------------------
__global__ __launch_bounds__(64) void k_att(const half_t* __restrict__ Zq,
                                            const half_t* __restrict__ Zk,
                                            const float* __restrict__ part,
                                            const float* __restrict__ fq,
                                            const float* __restrict__ fk,
                                            float* __restrict__ out_time,
                                            float* __restrict__ out_freq) {
  int bid = blockIdx.x;
  int lane = threadIdx.x;
  if (bid < 2048) {
    int b = bid >> 8, t = bid & 255;
    float acc[4][4];
#pragma unroll
    for (int i = 0; i < 4; i++)
#pragma unroll
      for (int j = 0; j < 4; j++) acc[i][j] = 0.f;
    for (int it = 0; it < 4; it++) {
      int s = lane + it * 64;
      float qv[4], kv[4];
#pragma unroll
      for (int i = 0; i < 4; i++) {
        size_t lbO = (size_t)(i * 8 + b);
        float pq = part[(((4 + i) * 8 + b) << 8) + s];
        float pk = part[(((i) * 8 + b) << 8) + s];
        qv[i] = (float)Zq[(lbO * 256 + t) * 256 + s] * rsqrtf(pq);
        kv[i] = (float)Zk[(lbO * 256 + t) * 256 + s] * rsqrtf(pk);
      }
#pragma unroll
      for (int i = 0; i < 4; i++)
#pragma unroll
        for (int j = 0; j < 4; j++) acc[i][j] += qv[i] * kv[j];
    }
#pragma unroll
    for (int i = 0; i < 4; i++)
#pragma unroll
      for (int j = 0; j < 4; j++)
        for (int m = 32; m >= 1; m >>= 1) acc[i][j] += __shfl_xor(acc[i][j], m);
    if (lane < 16) {
      int i = lane >> 2, j = lane & 3;
      float mx = fmaxf(fmaxf(acc[i][0], acc[i][1]), fmaxf(acc[i][2], acc[i][3]));
      float sum = expf(acc[i][0] - mx) + expf(acc[i][1] - mx) + expf(acc[i][2] - mx) + expf(acc[i][3] - mx);
      out_time[(size_t)bid * 16 + lane] = expf(acc[i][j] - mx) / sum;
    }
  } else {
    int pair = bid - 2048;
    int b = pair >> 7, tp = pair & 127;
    int t = tp * 2 + (lane >> 5);
    int f = lane & 31;
    float qv[4], kv[4];
#pragma unroll
    for (int i = 0; i < 4; i++) {
      size_t lbO = (size_t)(i * 8 + b);
      qv[i] = fq[(lbO * 256 + t) * 32 + f];
      kv[i] = fk[(lbO * 256 + t) * 32 + f];
    }
    float acc[4][4];
#pragma unroll
    for (int i = 0; i < 4; i++)
#pragma unroll
      for (int j = 0; j < 4; j++) acc[i][j] = qv[i] * kv[j];
#pragma unroll
    for (int i = 0; i < 4; i++)
#pragma unroll
      for (int j = 0; j < 4; j++)
        for (int m = 16; m >= 1; m >>= 1) acc[i][j] += __shfl_xor(acc[i][j], m);
    int fl = lane & 31;
    if (fl < 16) {
      int i = fl >> 2, j = fl & 3;
      float mx = fmaxf(fmaxf(acc[i][0], acc[i][1]), fmaxf(acc[i][2], acc[i][3]));
      float sum = expf(acc[i][0] - mx) + expf(acc[i][1] - mx) + expf(acc[i][2] - mx) + expf(acc[i][3] - mx);
      out_freq[((size_t)(b * 256 + t)) * 16 + fl] = expf(acc[i][j] - mx) / sum;
    }
  }
}

// ---------------------------------------------------------------------------
extern "C" void kernel_launch(void* const* d_in, const int* in_sizes, int n_in,
                              void* d_out, int out_size, void* d_ws, size_t ws_size,
                              hipStream_t stream) {
  (void)in_sizes; (void)n_in; (void)out_size; (void)ws_size;
  const float* feat_s = (const float*)d_in[0];
  const float* feat_t = (const float*)d_in[1];
  const float* tk_w1 = (const float*)d_in[2];
  const float* tk_b1 = (const float*)d_in[3];
  const float* tk_w2 = (const float*)d_in[4];
  const float* tk_b2 = (const float*)d_in[5];
  const float* fk_w1 = (const float*)d_in[6];
  const float* fk_b1 = (const float*)d_in[7];
  const float* fk_w2 = (const float*)d_in[8];
  const float* fk_b2 = (const float*)d_in[9];
  const float* tq_w1 = (const float*)d_in[10];
  const float* tq_b1 = (const float*)d_in[11];
  const float* tq_w2 = (const float*)d_in[12];
  const float* tq_b2 = (const float*)d_in[13];
  const float* fq_w1 = (const float*)d_in[14];
  const float* fq_b1 = (const float*)d_in[15];
  const float* fq_w2 = (const float*)d_in[16];
  const float* fq_b2 = (const float*)d_in[17];

  float* ws = (float*)d_ws;
  // Xh16 region (33.5MB); after k_simg+k_gram_cos consume it, h and Z alias it.
  half_t* Xh   = (half_t*)ws;                 // 16.8M halves
  half_t* hbuf = (half_t*)ws;                 // 8*2048*512 halves (alias, after gram)
  half_t* Zbuf = (half_t*)(ws + 4194304);     // 8*2048*256 halves (alias, after gram)
  half_t* simh = (half_t*)(ws + 8388608);     // 64*65536 halves
  half_t* W1t  = (half_t*)(ws + 10485760);    // 8*512*256 halves
  half_t* W2t  = (half_t*)(ws + 11010048);    // 8*256*512 halves
  float* Bc1   = ws + 11534336;               // 8*512
  float* Bc2   = ws + 11538432;               // 8*256
  float* simg  = ws + 11540480;               // 2*65536
  float* nrm   = ws + 11671552;               // 2*8192
  float* part  = ws + 11687936;               // 8*8*256 = 16384 (colnorm sumsq)
  float* fkb   = ws + 11704320;               // 262144
  float* fqb   = ws + 11966464;               // 262144

  float* out = (float*)d_out;
  float* out_stu_time = out;               // [4,4,8,256,256]
  float* out_stu_freq = out + 8388608;     // [4,4,8,256,8]
  float* out_tea_time = out + 8650752;     // [4,4,8,256,256]
  float* out_tea_freq = out + 17039360;    // [4,4,8,256,8]
  float* out_time_att = out + 17301504;    // [8,256,4,4]
  float* out_freq_att = out + 17334272;    // [8,256,4,4]

  // 1) weights + feat transpose/convert + norms + zero part (fused)
  hipLaunchKernelGGL(k_prep2, dim3(769), dim3(256), 0, stream,
                     tk_w1, tq_w1, tk_w2, tq_w2, tk_b1, tq_b1, tk_b2, tq_b2,
                     W1t, W2t, Bc1, Bc2, part, feat_s, feat_t, Xh, nrm);
  // 2) freq gram from fp16 panel (LDS + dot2)
  hipLaunchKernelGGL(k_simg, dim3(512), dim3(256), 0, stream, Xh, simg);
  // 3) time gram + cosine outputs fused (simh + stu/tea time writes)
  hipLaunchKernelGGL(k_gram_cos, dim3(4, 64), dim3(512), 0, stream,
                     Xh, nrm, simh, out_stu_time, out_tea_time);
  // 4) cos_freq + freq MLPs (fused)
  hipLaunchKernelGGL(k_small, dim3(128), dim3(256), 0, stream, simg, nrm,
                     out_stu_freq, out_tea_freq,
                     fq_w1, fq_b1, fq_w2, fq_b2, fk_w1, fk_b1, fk_w2, fk_b2, fqb, fkb);
  // 5) frame MLPs via MFMA 128x128 (h and Z alias the now-dead Xh region);
  //    mode2 epilogue accumulates column sumsq into part.
  hipLaunchKernelGGL((k_mfma<1, true, true>), dim3(16, 4, 8), dim3(256), 0, stream,
                     simh, W1t, Bc1, hbuf, (float*)nullptr);
  hipLaunchKernelGGL((k_mfma<2, false, true>), dim3(16, 2, 8), dim3(256), 0, stream,
                     hbuf, W2t, Bc2, Zbuf, part);
  // 6) attention (time + freq fused; norms from part, inline rsqrt)
  hipLaunchKernelGGL(k_att, dim3(3072), dim3(64), 0, stream,
                     Zbuf + (size_t)4 * 2048 * 256, Zbuf, part, fqb, fkb,
                     out_time_att, out_freq_att);
}

// Round 7
// 124.211 us; speedup vs baseline: 4.5640x; 1.0453x over previous
//
#include <hip/hip_runtime.h>
#include <math.h>

// Problem constants: s_len=t_len=4, B=8, C=64, T=256, D=16, H=512, F=32
typedef _Float16 half_t;
typedef _Float16 h2 __attribute__((ext_vector_type(2)));
typedef _Float16 h4 __attribute__((ext_vector_type(4)));
typedef _Float16 h8 __attribute__((ext_vector_type(8)));
typedef float f4 __attribute__((ext_vector_type(4)));
static constexpr float REPS = 1e-6f;

// ---------------------------------------------------------------------------
// k_prep2 = wconv (blocks 0-512) + x2h (blocks 513-768).
// ---------------------------------------------------------------------------
__global__ __launch_bounds__(256) void k_prep2(const float* __restrict__ tkw1, const float* __restrict__ tqw1,
                                               const float* __restrict__ tkw2, const float* __restrict__ tqw2,
                                               const float* __restrict__ tkb1, const float* __restrict__ tqb1,
                                               const float* __restrict__ tkb2, const float* __restrict__ tqb2,
                                               half_t* __restrict__ W1t, half_t* __restrict__ W2t,
                                               float* __restrict__ Bc1, float* __restrict__ Bc2,
                                               float* __restrict__ part,
                                               const float* __restrict__ fs, const float* __restrict__ ft,
                                               half_t* __restrict__ Xh, float* __restrict__ nrm) {
  __shared__ float T[64][65];
  int bid = blockIdx.x;
  int tid = threadIdx.x;
  if (bid < 256) {  // W1: [l][256 k][512 n] -> [z][512 n][256 k]
    int z = bid >> 5, tile = bid & 31;
    int kt = tile >> 3, ntile = tile & 7;
    const float* src = (z < 4 ? tkw1 : tqw1) + (size_t)(z & 3) * 256 * 512;
#pragma unroll
    for (int q = 0; q < 16; q++) {
      int e = q * 256 + tid;
      int r = e >> 6, c = e & 63;
      T[r][c] = src[(size_t)(kt * 64 + r) * 512 + ntile * 64 + c];
    }
    __syncthreads();
#pragma unroll
    for (int q = 0; q < 16; q++) {
      int e = q * 256 + tid;
      int nn = e >> 6, kk = e & 63;
      W1t[(size_t)z * 512 * 256 + (size_t)(ntile * 64 + nn) * 256 + kt * 64 + kk] = (half_t)T[kk][nn];
    }
  } else if (bid < 512) {  // W2: [l][512 k][256 n] -> [z][256 n][512 k]
    int bb = bid - 256;
    int z = bb >> 5, tile = bb & 31;
    int kt = tile >> 2, ntile = tile & 3;
    const float* src = (z < 4 ? tkw2 : tqw2) + (size_t)(z & 3) * 512 * 256;
#pragma unroll
    for (int q = 0; q < 16; q++) {
      int e = q * 256 + tid;
      int r = e >> 6, c = e & 63;
      T[r][c] = src[(size_t)(kt * 64 + r) * 256 + ntile * 64 + c];
    }
    __syncthreads();
#pragma unroll
    for (int q = 0; q < 16; q++) {
      int e = q * 256 + tid;
      int nn = e >> 6, kk = e & 63;
      W2t[(size_t)z * 256 * 512 + (size_t)(ntile * 64 + nn) * 512 + kt * 64 + kk] = (half_t)T[kk][nn];
    }
  } else if (bid == 512) {
    for (int e = tid; e < 4096; e += 256) {
      int z = e >> 9, n = e & 511;
      Bc1[e] = (z < 4 ? tkb1 : tqb1)[(z & 3) * 512 + n];
    }
    for (int e = tid; e < 2048; e += 256) {
      int z = e >> 8, n = e & 255;
      Bc2[e] = (z < 4 ? tkb2 : tqb2)[(z & 3) * 256 + n];
    }
    for (int e = tid; e < 16384; e += 256) part[e] = 0.f;
  } else {  // x2h: bid2 = tensor*128 + l*32 + b*4 + tc
    int bid2 = bid - 513;
    int tensor = bid2 >> 7;
    int l = (bid2 >> 5) & 3;
    int b = (bid2 >> 2) & 7;
    int tc = bid2 & 3;
    int tl = tid >> 2;           // 0..63
    int d0 = (tid & 3) * 4;
    int t = tc * 64 + tl;
    const float* base = (tensor ? ft : fs) + (size_t)((l * 8 + b) * 64) * 4096 + t * 16 + d0;
    size_t row = (size_t)(tensor * 32 + l * 8 + b) * 256 + t;
    half_t* xrow = Xh + row * 1024 + d0;
    float acc = 0.f;
#pragma unroll 8
    for (int c = 0; c < 64; c++) {
      float4 v = *(const float4*)(base + (size_t)c * 4096);
      acc += v.x * v.x + v.y * v.y + v.z * v.z + v.w * v.w;
      h4 hv;
      hv[0] = (half_t)v.x; hv[1] = (half_t)v.y; hv[2] = (half_t)v.z; hv[3] = (half_t)v.w;
      *(h4*)(xrow + c * 16) = hv;
    }
    acc += __shfl_xor(acc, 1);
    acc += __shfl_xor(acc, 2);
    if ((tid & 3) == 0) nrm[row] = sqrtf(acc);
  }
}

// ---------------------------------------------------------------------------
// k_gs = gram_cos (blocks 0-255) + simg (blocks 256-767). 512 threads.
// LDS union: gram_cos needs 34 KB; simg needs 66 KB.
// ---------------------------------------------------------------------------
__global__ __launch_bounds__(512) void k_gs(const half_t* __restrict__ Xh,
                                            const float* __restrict__ nrm,
                                            half_t* __restrict__ simh,
                                            float* __restrict__ out_stu,
                                            float* __restrict__ out_tea,
                                            float* __restrict__ simg) {
  __shared__ __align__(16) char smem[66048];
  int bid = blockIdx.x;
  int tid = threadIdx.x;
  if (bid < 256) {
    // ---- gram_cos: BM=64 x BN=256, BK=64, 8 waves, wave tile 32x64 ----
    half_t* Bsm = (half_t*)smem;                       // 256*64 halves = 32 KB
    float* rspart = (float*)(smem + 32768);            // [64][4]
    float* rowsumS = (float*)(smem + 32768 + 1024);    // [64]
    int mt = bid & 3;      // 0..3
    int z = bid >> 2;      // 0..63
    const half_t* Bb = Xh + (size_t)z * 256 * 1024;
    int w = tid >> 6, lane = tid & 63;
    int wm = w >> 2, wn = w & 3;
    int lr = lane & 15, lg = lane >> 4;
    f4 acc[2][4] = {};
    int r0 = tid >> 3, seg0 = tid & 7;
    int sw0 = (seg0 ^ (r0 & 7)) * 8;
    for (int kc = 0; kc < 1024; kc += 64) {
      h8 bv[4];
#pragma unroll
      for (int it = 0; it < 4; it++)
        bv[it] = *(const h8*)(Bb + (size_t)(it * 64 + r0) * 1024 + kc + seg0 * 8);
      __syncthreads();
#pragma unroll
      for (int it = 0; it < 4; it++)
        *(h8*)(Bsm + (it * 64 + r0) * 64 + sw0) = bv[it];
      __syncthreads();
#pragma unroll
      for (int kk = 0; kk < 2; kk++) {
        int g = kk * 4 + lg;
        h8 af[2], bf[4];
#pragma unroll
        for (int mf = 0; mf < 2; mf++) {
          int rA = mt * 64 + wm * 32 + mf * 16 + lr;
          af[mf] = *(const h8*)(Bsm + rA * 64 + ((g ^ (rA & 7)) * 8));
        }
#pragma unroll
        for (int nf = 0; nf < 4; nf++) {
          int rB = wn * 64 + nf * 16 + lr;
          bf[nf] = *(const h8*)(Bsm + rB * 64 + ((g ^ (rB & 7)) * 8));
        }
#pragma unroll
        for (int mf = 0; mf < 2; mf++)
#pragma unroll
          for (int nf = 0; nf < 4; nf++)
            acc[mf][nf] = __builtin_amdgcn_mfma_f32_16x16x32_f16(af[mf], bf[nf], acc[mf][nf], 0, 0, 0);
      }
    }
    // epilogue
    int tensor = z >> 5, l = (z >> 3) & 3, b = z & 7;
    const float* nz = nrm + z * 256;
    float nc[4];
    int cols[4];
#pragma unroll
    for (int nf = 0; nf < 4; nf++) {
      cols[nf] = wn * 64 + nf * 16 + lr;
      nc[nf] = nz[cols[nf]] + REPS;
    }
    float v[2][4][4];
    float rowpart[2][4];
#pragma unroll
    for (int mf = 0; mf < 2; mf++) {
#pragma unroll
      for (int rg = 0; rg < 4; rg++) {
        int rib = wm * 32 + mf * 16 + lg * 4 + rg;
        float nr = nz[mt * 64 + rib] + REPS;
        float p = 0.f;
#pragma unroll
        for (int nf = 0; nf < 4; nf++) {
          float S = acc[mf][nf][rg];
          float vv = fmaf(S / (nr * nc[nf]), 0.5f, 0.5f);
          v[mf][nf][rg] = vv;
          p += vv;
          simh[(size_t)z * 65536 + (size_t)(mt * 64 + rib) * 256 + cols[nf]] = (half_t)S;
        }
        rowpart[mf][rg] = p;
      }
    }
#pragma unroll
    for (int mf = 0; mf < 2; mf++)
#pragma unroll
      for (int rg = 0; rg < 4; rg++) {
        float p = rowpart[mf][rg];
        p += __shfl_xor(p, 1); p += __shfl_xor(p, 2);
        p += __shfl_xor(p, 4); p += __shfl_xor(p, 8);
        rowpart[mf][rg] = p;
      }
    if (lr == 0) {
#pragma unroll
      for (int mf = 0; mf < 2; mf++)
#pragma unroll
        for (int rg = 0; rg < 4; rg++)
          rspart[(wm * 32 + mf * 16 + lg * 4 + rg) * 4 + wn] = rowpart[mf][rg];
    }
    __syncthreads();
    if (tid < 64)
      rowsumS[tid] = rspart[tid * 4] + rspart[tid * 4 + 1] + rspart[tid * 4 + 2] + rspart[tid * 4 + 3];
    __syncthreads();
    float* outp = tensor ? out_tea : out_stu;
#pragma unroll
    for (int mf = 0; mf < 2; mf++) {
#pragma unroll
      for (int rg = 0; rg < 4; rg++) {
        int rib = wm * 32 + mf * 16 + lg * 4 + rg;
        int t = mt * 64 + rib;
        float inv = 1.f / rowsumS[rib];
#pragma unroll
        for (int nf = 0; nf < 4; nf++) {
          float val = v[mf][nf][rg] * inv;
          size_t inner = ((size_t)(b * 256 + t)) * 256 + cols[nf];
          if (tensor == 0) {
            size_t base = (size_t)l * 4 * 524288;
#pragma unroll
            for (int j = 0; j < 4; j++) outp[base + (size_t)j * 524288 + inner] = val;
          } else {
#pragma unroll
            for (int i = 0; i < 4; i++) outp[((size_t)(i * 4 + l)) * 524288 + inner] = val;
          }
        }
      }
    }
  } else {
    // ---- simg: freq gram. 32 LDS rows (tl*8+b) x 1032 halves. ----
    half_t* X = (half_t*)smem;
    int sb = bid - 256;       // 0..511
    int tensor = sb >> 8;
    int l = (sb >> 6) & 3;
    int tc = sb & 63;
    int t0 = tc * 4;
    // stage 4096 h8 with all 512 threads, linear (conflict-free b128 writes)
#pragma unroll
    for (int j = 0; j < 8; j++) {
      int i = j * 512 + tid;
      int r = i >> 7, col = i & 127;
      int b = r & 7, tl = r >> 3;
      const half_t* src = Xh + ((size_t)(tensor * 32 + l * 8 + b) * 256 + t0 + tl) * 1024 + col * 8;
      *(h8*)(X + r * 1032 + col * 8) = *(const h8*)src;
    }
    __syncthreads();
    if (tid < 256) {
      int tl = tid >> 6;
      int ab = tid & 63;
      int b = ab >> 3, a = ab & 7;
      const half_t* xa = X + (tl * 8 + b) * 1032;
      const half_t* xb = X + (tl * 8 + a) * 1032;
      float acc = 0.f;
#pragma unroll 8
      for (int k = 0; k < 1024; k += 8) {
        h8 va = *(const h8*)(xa + k);
        h8 vb = *(const h8*)(xb + k);
#if __has_builtin(__builtin_amdgcn_fdot2)
#pragma unroll
        for (int i = 0; i < 4; i++) {
          h2 pa, pb;
          pa[0] = va[2 * i]; pa[1] = va[2 * i + 1];
          pb[0] = vb[2 * i]; pb[1] = vb[2 * i + 1];
          acc = __builtin_amdgcn_fdot2(pa, pb, acc, false);
        }
#else
#pragma unroll
        for (int e = 0; e < 8; e++) acc += (float)va[e] * (float)vb[e];
#endif
      }
      simg[(size_t)tensor * 65536 + ((size_t)(l * 8 + b) * 256 + t0 + tl) * 8 + a] = acc;
    }
  }
}

// ---------------------------------------------------------------------------
// k_m1s = MLP GEMM1 (blocks 0-511) + cos_freq/fmlp (blocks 512-639). 256 thr.
// GEMM1: h = relu(simh @ W1t^T + b1), 128x128 tile, K=256, N=512.
// ---------------------------------------------------------------------------
__global__ __launch_bounds__(256) void k_m1s(const half_t* __restrict__ simh,
                                             const half_t* __restrict__ W1t,
                                             const float* __restrict__ Bc1,
                                             half_t* __restrict__ hbuf,
                                             const float* __restrict__ simg,
                                             const float* __restrict__ n,
                                             float* __restrict__ out_stu, float* __restrict__ out_tea,
                                             const float* __restrict__ qw1, const float* __restrict__ qb1,
                                             const float* __restrict__ qw2, const float* __restrict__ qb2,
                                             const float* __restrict__ kw1, const float* __restrict__ kb1,
                                             const float* __restrict__ kw2, const float* __restrict__ kb2,
                                             float* __restrict__ qout, float* __restrict__ kout) {
  __shared__ __align__(16) char smem[40352];
  int bid = blockIdx.x;
  int tid = threadIdx.x;
  if (bid < 512) {
    // ---- GEMM1: mt=bid&15, nt=(bid>>4)&3, z=bid>>6 ----
    constexpr int K = 256, N = 512;
    half_t* Asm = (half_t*)smem;             // 128*64
    half_t* Bsm = (half_t*)(smem + 16384);   // 128*64
    int mt = bid & 15, nt = (bid >> 4) & 3, z = bid >> 6;
    int l = z & 3, path = z >> 2;  // path0 = tk (teacher sim), path1 = tq (student)
    const half_t* Ab = simh + ((size_t)((path == 0 ? 32 : 0) + l * 8)) * 256 * 256;
    const half_t* Bb = W1t + (size_t)z * 512 * 256;
    half_t* Ob = hbuf + (size_t)z * 2048 * 512;
    int wave = tid >> 6, lane = tid & 63;
    int wm = (wave >> 1) * 64, wn = (wave & 1) * 64;
    int lr = lane & 15, lg = lane >> 4;
    f4 acc[4][4] = {};
    int r0 = tid >> 3, seg0 = tid & 7;
    int sw0 = (seg0 ^ (r0 & 7)) * 8;
    for (int kc = 0; kc < K; kc += 64) {
      h8 av[4], bv[4];
#pragma unroll
      for (int j = 0; j < 4; j++) {
        av[j] = *(const h8*)(Ab + (size_t)(mt * 128 + r0 + 32 * j) * K + kc + seg0 * 8);
        bv[j] = *(const h8*)(Bb + (size_t)(nt * 128 + r0 + 32 * j) * K + kc + seg0 * 8);
      }
      __syncthreads();
#pragma unroll
      for (int j = 0; j < 4; j++) {
        *(h8*)(Asm + (r0 + 32 * j) * 64 + sw0) = av[j];
        *(h8*)(Bsm + (r0 + 32 * j) * 64 + sw0) = bv[j];
      }
      __syncthreads();
#pragma unroll
      for (int kk = 0; kk < 2; kk++) {
        h8 af[4], bf[4];
#pragma unroll
        for (int mf = 0; mf < 4; mf++) {
          int r = wm + mf * 16 + lr;
          af[mf] = *(const h8*)(Asm + r * 64 + (((kk * 4 + lg) ^ (r & 7)) * 8));
        }
#pragma unroll
        for (int nf = 0; nf < 4; nf++) {
          int r = wn + nf * 16 + lr;
          bf[nf] = *(const h8*)(Bsm + r * 64 + (((kk * 4 + lg) ^ (r & 7)) * 8));
        }
#pragma unroll
        for (int mf = 0; mf < 4; mf++)
#pragma unroll
          for (int nf = 0; nf < 4; nf++)
            acc[mf][nf] = __builtin_amdgcn_mfma_f32_16x16x32_f16(af[mf], bf[nf], acc[mf][nf], 0, 0, 0);
      }
    }
#pragma unroll
    for (int nf = 0; nf < 4; nf++) {
      int col = nt * 128 + wn + nf * 16 + lr;
      float bv2 = Bc1[z * N + col];
#pragma unroll
      for (int mf = 0; mf < 4; mf++) {
#pragma unroll
        for (int rg = 0; rg < 4; rg++) {
          int row = mt * 128 + wm + mf * 16 + lg * 4 + rg;
          float v = fmaxf(acc[mf][nf][rg] + bv2, 0.f);
          Ob[(size_t)row * N + col] = (half_t)v;
        }
      }
    }
  } else if (bid < 576) {
    // ---- cos_freq ----
    int bb = bid - 512;
    int tensor = bb >> 5;
    int lb = bb & 31;
    const float* sg = simg + (size_t)tensor * 65536;
    const float* nb2 = n + tensor * 8192;
    float* out = tensor ? out_tea : out_stu;
    int l = lb >> 3, b = lb & 7;
    int a = tid & 7;
    for (int tc = 0; tc < 8; tc++) {
      int t = tc * 32 + (tid >> 3);
      float nb = nb2[lb * 256 + t] + REPS;
      float na = nb2[(l * 8 + a) * 256 + t] + REPS;
      float v = (sg[((size_t)lb * 256 + t) * 8 + a] / (nb * na) + 1.f) * 0.5f;
      float w = v;
      for (int m = 1; m < 8; m <<= 1) w += __shfl_xor(w, m);
      v /= w;
      size_t inner = ((size_t)(b * 256 + t)) * 8 + a;
      if (tensor == 0) {
#pragma unroll
        for (int j = 0; j < 4; j++) out[((size_t)(l * 4 + j)) * 16384 + inner] = v;
      } else {
#pragma unroll
        for (int i = 0; i < 4; i++) out[((size_t)(i * 4 + l)) * 16384 + inner] = v;
      }
    }
  } else {
    // ---- freq MLP (tensor0 = student -> fq, tensor1 = teacher -> fk) ----
    float* sw1 = (float*)smem;                 // 256
    float* sb1 = (float*)(smem + 1024);        // 32
    float* sw2 = (float*)(smem + 1152);        // 1024
    float* sb2 = (float*)(smem + 5248);        // 32
    float* zs  = (float*)(smem + 5376);        // [256][33]
    float* pcn = (float*)(smem + 39168);       // [8][33]
    float* cn  = (float*)(smem + 40224);       // 32
    int bb = bid - 576;
    int tensor = bb >> 5;
    int lb = bb & 31;
    int l = lb >> 3;
    const float* w1 = tensor ? kw1 : qw1;
    const float* b1 = tensor ? kb1 : qb1;
    const float* w2 = tensor ? kw2 : qw2;
    const float* b2 = tensor ? kb2 : qb2;
    const float* sg = simg + (size_t)tensor * 65536;
    float* outp = tensor ? kout : qout;
    int t = tid;
    sw1[t] = w1[l * 256 + t];
    if (t < 32) { sb1[t] = b1[l * 32 + t]; sb2[t] = b2[l * 32 + t]; }
    for (int q = t; q < 1024; q += 256) sw2[q] = w2[l * 1024 + q];
    __syncthreads();
    float x[8];
#pragma unroll
    for (int a = 0; a < 8; a++) x[a] = sg[((size_t)lb * 256 + t) * 8 + a];
    float h[32];
#pragma unroll
    for (int f = 0; f < 32; f++) {
      float acc = sb1[f];
#pragma unroll
      for (int a = 0; a < 8; a++) acc += x[a] * sw1[a * 32 + f];
      h[f] = fmaxf(acc, 0.f);
    }
#pragma unroll
    for (int g = 0; g < 32; g++) {
      float acc = sb2[g];
#pragma unroll
      for (int f = 0; f < 32; f++) acc += h[f] * sw2[f * 32 + g];
      zs[t * 33 + g] = acc;
    }
    __syncthreads();
    {
      int col = t & 31, ch = t >> 5;
      float sq = 0.f;
      for (int r = ch * 32; r < ch * 32 + 32; r++) { float v = zs[r * 33 + col]; sq += v * v; }
      pcn[ch * 33 + col] = sq;
    }
    __syncthreads();
    if (t < 32) {
      float ssum = 0.f;
#pragma unroll
      for (int c = 0; c < 8; c++) ssum += pcn[c * 33 + t];
      cn[t] = sqrtf(ssum);
    }
    __syncthreads();
#pragma unroll
    for (int g = 0; g < 32; g++)
      outp[((size_t)lb * 256 + t) * 32 + g] = zs[t * 33 + g] / cn[g];
  }
}

// ---------------------------------------------------------------------------
// k_mfma2: Z = hbuf @ W2t^T + b2, 128x128 tile, K=512, N=256, + column-sumsq.
// ---------------------------------------------------------------------------
__global__ __launch_bounds__(256) void k_mfma2(const half_t* __restrict__ A,
                                               const half_t* __restrict__ Bt,
                                               const float* __restrict__ bias,
                                               half_t* __restrict__ out,
                                               float* __restrict__ part) {
  constexpr int K = 512, N = 256;
  __shared__ __align__(16) half_t Asm[128 * 64];
  __shared__ __align__(16) half_t Bsm[128 * 64];
  int z = blockIdx.z;
  const half_t* Ab = A + (size_t)z * 2048 * 512;
  const half_t* Bb = Bt + (size_t)z * 256 * 512;
  half_t* Ob = out + (size_t)z * 2048 * 256;
  int mt = blockIdx.x, nt = blockIdx.y;
  int tid = threadIdx.x;
  int wave = tid >> 6, lane = tid & 63;
  int wm = (wave >> 1) * 64, wn = (wave & 1) * 64;
  int lr = lane & 15, lg = lane >> 4;
  f4 acc[4][4] = {};
  int r0 = tid >> 3, seg0 = tid & 7;
  int sw0 = (seg0 ^ (r0 & 7)) * 8;
  for (int kc = 0; kc < K; kc += 64) {
    h8 av[4], bv[4];
#pragma unroll
    for (int j = 0; j < 4; j++) {
      av[j] = *(const h8*)(Ab + (size_t)(mt * 128 + r0 + 32 * j) * K + kc + seg0 * 8);
      bv[j] = *(const h8*)(Bb + (size_t)(nt * 128 + r0 + 32 * j) * K + kc + seg0 * 8);
    }
    __syncthreads();
#pragma unroll
    for (int j = 0; j < 4; j++) {
      *(h8*)(Asm + (r0 + 32 * j) * 64 + sw0) = av[j];
      *(h8*)(Bsm + (r0 + 32 * j) * 64 + sw0) = bv[j];
    }
    __syncthreads();
#pragma unroll
    for (int kk = 0; kk < 2; kk++) {
      h8 af[4], bf[4];
#pragma unroll
      for (int mf = 0; mf < 4; mf++) {
        int r = wm + mf * 16 + lr;
        af[mf] = *(const h8*)(Asm + r * 64 + (((kk * 4 + lg) ^ (r & 7)) * 8));
      }
#pragma unroll
      for (int nf = 0; nf < 4; nf++) {
        int r = wn + nf * 16 + lr;
        bf[nf] = *(const h8*)(Bsm + r * 64 + (((kk * 4 + lg) ^ (r & 7)) * 8));
      }
#pragma unroll
      for (int mf = 0; mf < 4; mf++)
#pragma unroll
        for (int nf = 0; nf < 4; nf++)
          acc[mf][nf] = __builtin_amdgcn_mfma_f32_16x16x32_f16(af[mf], bf[nf], acc[mf][nf], 0, 0, 0);
    }
  }
#pragma unroll
  for (int nf = 0; nf < 4; nf++) {
    int col = nt * 128 + wn + nf * 16 + lr;
    float bv2 = bias[z * N + col];
    float colsq = 0.f;
#pragma unroll
    for (int mf = 0; mf < 4; mf++) {
#pragma unroll
      for (int rg = 0; rg < 4; rg++) {
        int row = mt * 128 + wm + mf * 16 + lg * 4 + rg;
        float v = acc[mf][nf][rg] + bv2;
        Ob[(size_t)row * N + col] = (half_t)v;
        colsq += v * v;
      }
    }
    colsq += __shfl_xor(colsq, 16);
    colsq += __shfl_xor(colsq, 32);
    if (lg == 0) {
      int b = mt >> 1;
      atomicAdd(&part[((z * 8 + b) << 8) + col], colsq);
    }
  }
}

// ---------------------------------------------------------------------------
// k_att = time attention (blocks 0-2047) + freq attention (blocks 2048-3071).
// ---------------------------------------------------------------------------
__global__ __launch_bounds__(64) void k_att(const half_t* __restrict__ Zq,
                                            const half_t* __restrict__ Zk,
                                            const float* __restrict__ part,
                                            const float* __restrict__ fq,
                                            const float* __restrict__ fk,
                                            float* __restrict__ out_time,
                                            float* __restrict__ out_freq) {
  int bid = blockIdx.x;
  int lane = threadIdx.x;
  if (bid < 2048) {
    int b = bid >> 8, t = bid & 255;
    float acc[4][4];
#pragma unroll
    for (int i = 0; i < 4; i++)
#pragma unroll
      for (int j = 0; j < 4; j++) acc[i][j] = 0.f;
    for (int it = 0; it < 4; it++) {
      int s = lane + it * 64;
      float qv[4], kv[4];
#pragma unroll
      for (int i = 0; i < 4; i++) {
        size_t lbO = (size_t)(i * 8 + b);
        float pq = part[(((4 + i) * 8 + b) << 8) + s];
        float pk = part[(((i) * 8 + b) << 8) + s];
        qv[i] = (float)Zq[(lbO * 256 + t) * 256 + s] * rsqrtf(pq);
        kv[i] = (float)Zk[(lbO * 256 + t) * 256 + s] * rsqrtf(pk);
      }
#pragma unroll
      for (int i = 0; i < 4; i++)
#pragma unroll
        for (int j = 0; j < 4; j++) acc[i][j] += qv[i] * kv[j];
    }
#pragma unroll
    for (int i = 0; i < 4; i++)
#pragma unroll
      for (int j = 0; j < 4; j++)
        for (int m = 32; m >= 1; m >>= 1) acc[i][j] += __shfl_xor(acc[i][j], m);
    if (lane < 16) {
      int i = lane >> 2, j = lane & 3;
      float mx = fmaxf(fmaxf(acc[i][0], acc[i][1]), fmaxf(acc[i][2], acc[i][3]));
      float sum = expf(acc[i][0] - mx) + expf(acc[i][1] - mx) + expf(acc[i][2] - mx) + expf(acc[i][3] - mx);
      out_time[(size_t)bid * 16 + lane] = expf(acc[i][j] - mx) / sum;
    }
  } else {
    int pair = bid - 2048;
    int b = pair >> 7, tp = pair & 127;
    int t = tp * 2 + (lane >> 5);
    int f = lane & 31;
    float qv[4], kv[4];
#pragma unroll
    for (int i = 0; i < 4; i++) {
      size_t lbO = (size_t)(i * 8 + b);
      qv[i] = fq[(lbO * 256 + t) * 32 + f];
      kv[i] = fk[(lbO * 256 + t) * 32 + f];
    }
    float acc[4][4];
#pragma unroll
    for (int i = 0; i < 4; i++)
#pragma unroll
      for (int j = 0; j < 4; j++) acc[i][j] = qv[i] * kv[j];
#pragma unroll
    for (int i = 0; i < 4; i++)
#pragma unroll
      for (int j = 0; j < 4; j++)
        for (int m = 16; m >= 1; m >>= 1) acc[i][j] += __shfl_xor(acc[i][j], m);
    int fl = lane & 31;
    if (fl < 16) {
      int i = fl >> 2, j = fl & 3;
      float mx = fmaxf(fmaxf(acc[i][0], acc[i][1]), fmaxf(acc[i][2], acc[i][3]));
      float sum = expf(acc[i][0] - mx) + expf(acc[i][1] - mx) + expf(acc[i][2] - mx) + expf(acc[i][3] - mx);
      out_freq[((size_t)(b * 256 + t)) * 16 + fl] = expf(acc[i][j] - mx) / sum;
    }
  }
}

// ---------------------------------------------------------------------------
extern "C" void kernel_launch(void* const* d_in, const int* in_sizes, int n_in,
                              void* d_out, int out_size, void* d_ws, size_t ws_size,
                              hipStream_t stream) {
  (void)in_sizes; (void)n_in; (void)out_size; (void)ws_size;
  const float* feat_s = (const float*)d_in[0];
  const float* feat_t = (const float*)d_in[1];
  const float* tk_w1 = (const float*)d_in[2];
  const float* tk_b1 = (const float*)d_in[3];
  const float* tk_w2 = (const float*)d_in[4];
  const float* tk_b2 = (const float*)d_in[5];
  const float* fk_w1 = (const float*)d_in[6];
  const float* fk_b1 = (const float*)d_in[7];
  const float* fk_w2 = (const float*)d_in[8];
  const float* fk_b2 = (const float*)d_in[9];
  const float* tq_w1 = (const float*)d_in[10];
  const float* tq_b1 = (const float*)d_in[11];
  const float* tq_w2 = (const float*)d_in[12];
  const float* tq_b2 = (const float*)d_in[13];
  const float* fq_w1 = (const float*)d_in[14];
  const float* fq_b1 = (const float*)d_in[15];
  const float* fq_w2 = (const float*)d_in[16];
  const float* fq_b2 = (const float*)d_in[17];

  float* ws = (float*)d_ws;
  // Xh16 region (33.5MB); after k_gs consumes it, h and Z alias it.
  half_t* Xh   = (half_t*)ws;                 // 16.8M halves
  half_t* hbuf = (half_t*)ws;                 // 8*2048*512 halves (alias, after gram)
  half_t* Zbuf = (half_t*)(ws + 4194304);     // 8*2048*256 halves (alias, after gram)
  half_t* simh = (half_t*)(ws + 8388608);     // 64*65536 halves
  half_t* W1t  = (half_t*)(ws + 10485760);    // 8*512*256 halves
  half_t* W2t  = (half_t*)(ws + 11010048);    // 8*256*512 halves
  float* Bc1   = ws + 11534336;               // 8*512
  float* Bc2   = ws + 11538432;               // 8*256
  float* simg  = ws + 11540480;               // 2*65536
  float* nrm   = ws + 11671552;               // 2*8192
  float* part  = ws + 11687936;               // 8*8*256 = 16384 (colnorm sumsq)
  float* fkb   = ws + 11704320;               // 262144
  float* fqb   = ws + 11966464;               // 262144

  float* out = (float*)d_out;
  float* out_stu_time = out;               // [4,4,8,256,256]
  float* out_stu_freq = out + 8388608;     // [4,4,8,256,8]
  float* out_tea_time = out + 8650752;     // [4,4,8,256,256]
  float* out_tea_freq = out + 17039360;    // [4,4,8,256,8]
  float* out_time_att = out + 17301504;    // [8,256,4,4]
  float* out_freq_att = out + 17334272;    // [8,256,4,4]

  // 1) weights + feat transpose/convert + norms + zero part (fused)
  hipLaunchKernelGGL(k_prep2, dim3(769), dim3(256), 0, stream,
                     tk_w1, tq_w1, tk_w2, tq_w2, tk_b1, tq_b1, tk_b2, tq_b2,
                     W1t, W2t, Bc1, Bc2, part, feat_s, feat_t, Xh, nrm);
  // 2) time gram + cosine outputs fused, alongside freq gram (mixed blocks)
  hipLaunchKernelGGL(k_gs, dim3(768), dim3(512), 0, stream,
                     Xh, nrm, simh, out_stu_time, out_tea_time, simg);
  // 3) MLP GEMM1 alongside cos_freq + freq MLP (mixed blocks; h aliases Xh)
  hipLaunchKernelGGL(k_m1s, dim3(640), dim3(256), 0, stream,
                     simh, W1t, Bc1, hbuf, simg, nrm,
                     out_stu_freq, out_tea_freq,
                     fq_w1, fq_b1, fq_w2, fq_b2, fk_w1, fk_b1, fk_w2, fk_b2, fqb, fkb);
  // 4) MLP GEMM2 + fused column-sumsq atomics
  hipLaunchKernelGGL(k_mfma2, dim3(16, 2, 8), dim3(256), 0, stream,
                     hbuf, W2t, Bc2, Zbuf, part);
  // 5) attention (time + freq fused; norms from part, inline rsqrt)
  hipLaunchKernelGGL(k_att, dim3(3072), dim3(64), 0, stream,
                     Zbuf + (size_t)4 * 2048 * 256, Zbuf, part, fqb, fkb,
                     out_time_att, out_freq_att);
}

// Round 8
// 111.899 us; speedup vs baseline: 5.0661x; 1.1100x over previous
//
#include <hip/hip_runtime.h>
#include <math.h>

// Problem constants: s_len=t_len=4, B=8, C=64, T=256, D=16, H=512, F=32
typedef _Float16 half_t;
typedef _Float16 h2 __attribute__((ext_vector_type(2)));
typedef _Float16 h4 __attribute__((ext_vector_type(4)));
typedef _Float16 h8 __attribute__((ext_vector_type(8)));
typedef float f4 __attribute__((ext_vector_type(4)));
static constexpr float REPS = 1e-6f;

// ---------------------------------------------------------------------------
// k_prep2 = wconv (blocks 0-512) + x2h (blocks 513-768).
// ---------------------------------------------------------------------------
__global__ __launch_bounds__(256) void k_prep2(const float* __restrict__ tkw1, const float* __restrict__ tqw1,
                                               const float* __restrict__ tkw2, const float* __restrict__ tqw2,
                                               const float* __restrict__ tkb1, const float* __restrict__ tqb1,
                                               const float* __restrict__ tkb2, const float* __restrict__ tqb2,
                                               half_t* __restrict__ W1t, half_t* __restrict__ W2t,
                                               float* __restrict__ Bc1, float* __restrict__ Bc2,
                                               float* __restrict__ part,
                                               const float* __restrict__ fs, const float* __restrict__ ft,
                                               half_t* __restrict__ Xh, float* __restrict__ nrm) {
  __shared__ float T[64][65];
  int bid = blockIdx.x;
  int tid = threadIdx.x;
  if (bid < 256) {  // W1: [l][256 k][512 n] -> [z][512 n][256 k]
    int z = bid >> 5, tile = bid & 31;
    int kt = tile >> 3, ntile = tile & 7;
    const float* src = (z < 4 ? tkw1 : tqw1) + (size_t)(z & 3) * 256 * 512;
#pragma unroll
    for (int q = 0; q < 16; q++) {
      int e = q * 256 + tid;
      int r = e >> 6, c = e & 63;
      T[r][c] = src[(size_t)(kt * 64 + r) * 512 + ntile * 64 + c];
    }
    __syncthreads();
#pragma unroll
    for (int q = 0; q < 16; q++) {
      int e = q * 256 + tid;
      int nn = e >> 6, kk = e & 63;
      W1t[(size_t)z * 512 * 256 + (size_t)(ntile * 64 + nn) * 256 + kt * 64 + kk] = (half_t)T[kk][nn];
    }
  } else if (bid < 512) {  // W2: [l][512 k][256 n] -> [z][256 n][512 k]
    int bb = bid - 256;
    int z = bb >> 5, tile = bb & 31;
    int kt = tile >> 2, ntile = tile & 3;
    const float* src = (z < 4 ? tkw2 : tqw2) + (size_t)(z & 3) * 512 * 256;
#pragma unroll
    for (int q = 0; q < 16; q++) {
      int e = q * 256 + tid;
      int r = e >> 6, c = e & 63;
      T[r][c] = src[(size_t)(kt * 64 + r) * 256 + ntile * 64 + c];
    }
    __syncthreads();
#pragma unroll
    for (int q = 0; q < 16; q++) {
      int e = q * 256 + tid;
      int nn = e >> 6, kk = e & 63;
      W2t[(size_t)z * 256 * 512 + (size_t)(ntile * 64 + nn) * 512 + kt * 64 + kk] = (half_t)T[kk][nn];
    }
  } else if (bid == 512) {
    for (int e = tid; e < 4096; e += 256) {
      int z = e >> 9, n = e & 511;
      Bc1[e] = (z < 4 ? tkb1 : tqb1)[(z & 3) * 512 + n];
    }
    for (int e = tid; e < 2048; e += 256) {
      int z = e >> 8, n = e & 255;
      Bc2[e] = (z < 4 ? tkb2 : tqb2)[(z & 3) * 256 + n];
    }
    for (int e = tid; e < 16384; e += 256) part[e] = 0.f;
  } else {  // x2h: bid2 = tensor*128 + l*32 + b*4 + tc
    int bid2 = bid - 513;
    int tensor = bid2 >> 7;
    int l = (bid2 >> 5) & 3;
    int b = (bid2 >> 2) & 7;
    int tc = bid2 & 3;
    int tl = tid >> 2;           // 0..63
    int d0 = (tid & 3) * 4;
    int t = tc * 64 + tl;
    const float* base = (tensor ? ft : fs) + (size_t)((l * 8 + b) * 64) * 4096 + t * 16 + d0;
    size_t row = (size_t)(tensor * 32 + l * 8 + b) * 256 + t;
    half_t* xrow = Xh + row * 1024 + d0;
    float acc = 0.f;
#pragma unroll 8
    for (int c = 0; c < 64; c++) {
      float4 v = *(const float4*)(base + (size_t)c * 4096);
      acc += v.x * v.x + v.y * v.y + v.z * v.z + v.w * v.w;
      h4 hv;
      hv[0] = (half_t)v.x; hv[1] = (half_t)v.y; hv[2] = (half_t)v.z; hv[3] = (half_t)v.w;
      *(h4*)(xrow + c * 16) = hv;
    }
    acc += __shfl_xor(acc, 1);
    acc += __shfl_xor(acc, 2);
    if ((tid & 3) == 0) nrm[row] = sqrtf(acc);
  }
}

// ---------------------------------------------------------------------------
// k_gs = gram_cos (blocks 0-255) + simg (blocks 256-767). 512 threads.
// LDS union: gram_cos 34 KB; simg 33 KB (two K-half passes) -> 4 blocks/CU.
// ---------------------------------------------------------------------------
__global__ __launch_bounds__(512) void k_gs(const half_t* __restrict__ Xh,
                                            const float* __restrict__ nrm,
                                            half_t* __restrict__ simh,
                                            float* __restrict__ out_stu,
                                            float* __restrict__ out_tea,
                                            float* __restrict__ simg) {
  __shared__ __align__(16) char smem[34048];
  int bid = blockIdx.x;
  int tid = threadIdx.x;
  if (bid < 256) {
    // ---- gram_cos: BM=64 x BN=256, BK=64, 8 waves, wave tile 32x64 ----
    half_t* Bsm = (half_t*)smem;                       // 256*64 halves = 32 KB
    float* rspart = (float*)(smem + 32768);            // [64][4]
    float* rowsumS = (float*)(smem + 32768 + 1024);    // [64]
    int mt = bid & 3;      // 0..3
    int z = bid >> 2;      // 0..63
    const half_t* Bb = Xh + (size_t)z * 256 * 1024;
    int w = tid >> 6, lane = tid & 63;
    int wm = w >> 2, wn = w & 3;
    int lr = lane & 15, lg = lane >> 4;
    f4 acc[2][4] = {};
    int r0 = tid >> 3, seg0 = tid & 7;
    int sw0 = (seg0 ^ (r0 & 7)) * 8;
    for (int kc = 0; kc < 1024; kc += 64) {
      h8 bv[4];
#pragma unroll
      for (int it = 0; it < 4; it++)
        bv[it] = *(const h8*)(Bb + (size_t)(it * 64 + r0) * 1024 + kc + seg0 * 8);
      __syncthreads();
#pragma unroll
      for (int it = 0; it < 4; it++)
        *(h8*)(Bsm + (it * 64 + r0) * 64 + sw0) = bv[it];
      __syncthreads();
#pragma unroll
      for (int kk = 0; kk < 2; kk++) {
        int g = kk * 4 + lg;
        h8 af[2], bf[4];
#pragma unroll
        for (int mf = 0; mf < 2; mf++) {
          int rA = mt * 64 + wm * 32 + mf * 16 + lr;
          af[mf] = *(const h8*)(Bsm + rA * 64 + ((g ^ (rA & 7)) * 8));
        }
#pragma unroll
        for (int nf = 0; nf < 4; nf++) {
          int rB = wn * 64 + nf * 16 + lr;
          bf[nf] = *(const h8*)(Bsm + rB * 64 + ((g ^ (rB & 7)) * 8));
        }
#pragma unroll
        for (int mf = 0; mf < 2; mf++)
#pragma unroll
          for (int nf = 0; nf < 4; nf++)
            acc[mf][nf] = __builtin_amdgcn_mfma_f32_16x16x32_f16(af[mf], bf[nf], acc[mf][nf], 0, 0, 0);
      }
    }
    // epilogue
    int tensor = z >> 5, l = (z >> 3) & 3, b = z & 7;
    const float* nz = nrm + z * 256;
    float nc[4];
    int cols[4];
#pragma unroll
    for (int nf = 0; nf < 4; nf++) {
      cols[nf] = wn * 64 + nf * 16 + lr;
      nc[nf] = nz[cols[nf]] + REPS;
    }
    float v[2][4][4];
    float rowpart[2][4];
#pragma unroll
    for (int mf = 0; mf < 2; mf++) {
#pragma unroll
      for (int rg = 0; rg < 4; rg++) {
        int rib = wm * 32 + mf * 16 + lg * 4 + rg;
        float nr = nz[mt * 64 + rib] + REPS;
        float p = 0.f;
#pragma unroll
        for (int nf = 0; nf < 4; nf++) {
          float S = acc[mf][nf][rg];
          float vv = fmaf(S / (nr * nc[nf]), 0.5f, 0.5f);
          v[mf][nf][rg] = vv;
          p += vv;
          simh[(size_t)z * 65536 + (size_t)(mt * 64 + rib) * 256 + cols[nf]] = (half_t)S;
        }
        rowpart[mf][rg] = p;
      }
    }
#pragma unroll
    for (int mf = 0; mf < 2; mf++)
#pragma unroll
      for (int rg = 0; rg < 4; rg++) {
        float p = rowpart[mf][rg];
        p += __shfl_xor(p, 1); p += __shfl_xor(p, 2);
        p += __shfl_xor(p, 4); p += __shfl_xor(p, 8);
        rowpart[mf][rg] = p;
      }
    if (lr == 0) {
#pragma unroll
      for (int mf = 0; mf < 2; mf++)
#pragma unroll
        for (int rg = 0; rg < 4; rg++)
          rspart[(wm * 32 + mf * 16 + lg * 4 + rg) * 4 + wn] = rowpart[mf][rg];
    }
    __syncthreads();
    if (tid < 64)
      rowsumS[tid] = rspart[tid * 4] + rspart[tid * 4 + 1] + rspart[tid * 4 + 2] + rspart[tid * 4 + 3];
    __syncthreads();
    float* outp = tensor ? out_tea : out_stu;
#pragma unroll
    for (int mf = 0; mf < 2; mf++) {
#pragma unroll
      for (int rg = 0; rg < 4; rg++) {
        int rib = wm * 32 + mf * 16 + lg * 4 + rg;
        int t = mt * 64 + rib;
        float inv = 1.f / rowsumS[rib];
#pragma unroll
        for (int nf = 0; nf < 4; nf++) {
          float val = v[mf][nf][rg] * inv;
          size_t inner = ((size_t)(b * 256 + t)) * 256 + cols[nf];
          if (tensor == 0) {
            size_t base = (size_t)l * 4 * 524288;
#pragma unroll
            for (int j = 0; j < 4; j++) outp[base + (size_t)j * 524288 + inner] = val;
          } else {
#pragma unroll
            for (int i = 0; i < 4; i++) outp[((size_t)(i * 4 + l)) * 524288 + inner] = val;
          }
        }
      }
    }
  } else {
    // ---- simg: freq gram, two K-half passes. 32 LDS rows x 520 halves. ----
    half_t* X = (half_t*)smem;
    int sb = bid - 256;       // 0..511
    int tensor = sb >> 8;
    int l = (sb >> 6) & 3;
    int tc = sb & 63;
    int t0 = tc * 4;
    float acc = 0.f;
    int tl_c = tid >> 6;      // compute indices (tid<256 only)
    int ab = tid & 63;
    int bb = ab >> 3, aa = ab & 7;
    for (int kh = 0; kh < 2; kh++) {
      // stage 2048 h8 with all 512 threads, linear (conflict-free b128 writes)
#pragma unroll
      for (int j = 0; j < 4; j++) {
        int i = j * 512 + tid;
        int r = i >> 6, col = i & 63;
        int b = r & 7, tl = r >> 3;
        const half_t* src = Xh + ((size_t)(tensor * 32 + l * 8 + b) * 256 + t0 + tl) * 1024
                               + kh * 512 + col * 8;
        *(h8*)(X + r * 520 + col * 8) = *(const h8*)src;
      }
      __syncthreads();
      if (tid < 256) {
        const half_t* xa = X + (tl_c * 8 + bb) * 520;
        const half_t* xb = X + (tl_c * 8 + aa) * 520;
#pragma unroll 8
        for (int k = 0; k < 512; k += 8) {
          h8 va = *(const h8*)(xa + k);
          h8 vb = *(const h8*)(xb + k);
#if __has_builtin(__builtin_amdgcn_fdot2)
#pragma unroll
          for (int i = 0; i < 4; i++) {
            h2 pa, pb;
            pa[0] = va[2 * i]; pa[1] = va[2 * i + 1];
            pb[0] = vb[2 * i]; pb[1] = vb[2 * i + 1];
            acc = __builtin_amdgcn_fdot2(pa, pb, acc, false);
          }
#else
#pragma unroll
          for (int e = 0; e < 8; e++) acc += (float)va[e] * (float)vb[e];
#endif
        }
      }
      __syncthreads();
    }
    if (tid < 256)
      simg[(size_t)tensor * 65536 + ((size_t)(l * 8 + bb) * 256 + t0 + tl_c) * 8 + aa] = acc;
  }
}

// ---------------------------------------------------------------------------
// k_m1s = MLP GEMM1 (blocks 0-511) + cos_freq/fmlp (blocks 512-639). 256 thr.
// ---------------------------------------------------------------------------
__global__ __launch_bounds__(256) void k_m1s(const half_t* __restrict__ simh,
                                             const half_t* __restrict__ W1t,
                                             const float* __restrict__ Bc1,
                                             half_t* __restrict__ hbuf,
                                             const float* __restrict__ simg,
                                             const float* __restrict__ n,
                                             float* __restrict__ out_stu, float* __restrict__ out_tea,
                                             const float* __restrict__ qw1, const float* __restrict__ qb1,
                                             const float* __restrict__ qw2, const float* __restrict__ qb2,
                                             const float* __restrict__ kw1, const float* __restrict__ kb1,
                                             const float* __restrict__ kw2, const float* __restrict__ kb2,
                                             float* __restrict__ qout, float* __restrict__ kout) {
  __shared__ __align__(16) char smem[40352];
  int bid = blockIdx.x;
  int tid = threadIdx.x;
  if (bid < 512) {
    constexpr int K = 256, N = 512;
    half_t* Asm = (half_t*)smem;             // 128*64
    half_t* Bsm = (half_t*)(smem + 16384);   // 128*64
    int mt = bid & 15, nt = (bid >> 4) & 3, z = bid >> 6;
    int l = z & 3, path = z >> 2;
    const half_t* Ab = simh + ((size_t)((path == 0 ? 32 : 0) + l * 8)) * 256 * 256;
    const half_t* Bb = W1t + (size_t)z * 512 * 256;
    half_t* Ob = hbuf + (size_t)z * 2048 * 512;
    int wave = tid >> 6, lane = tid & 63;
    int wm = (wave >> 1) * 64, wn = (wave & 1) * 64;
    int lr = lane & 15, lg = lane >> 4;
    f4 acc[4][4] = {};
    int r0 = tid >> 3, seg0 = tid & 7;
    int sw0 = (seg0 ^ (r0 & 7)) * 8;
    for (int kc = 0; kc < K; kc += 64) {
      h8 av[4], bv[4];
#pragma unroll
      for (int j = 0; j < 4; j++) {
        av[j] = *(const h8*)(Ab + (size_t)(mt * 128 + r0 + 32 * j) * K + kc + seg0 * 8);
        bv[j] = *(const h8*)(Bb + (size_t)(nt * 128 + r0 + 32 * j) * K + kc + seg0 * 8);
      }
      __syncthreads();
#pragma unroll
      for (int j = 0; j < 4; j++) {
        *(h8*)(Asm + (r0 + 32 * j) * 64 + sw0) = av[j];
        *(h8*)(Bsm + (r0 + 32 * j) * 64 + sw0) = bv[j];
      }
      __syncthreads();
#pragma unroll
      for (int kk = 0; kk < 2; kk++) {
        h8 af[4], bf[4];
#pragma unroll
        for (int mf = 0; mf < 4; mf++) {
          int r = wm + mf * 16 + lr;
          af[mf] = *(const h8*)(Asm + r * 64 + (((kk * 4 + lg) ^ (r & 7)) * 8));
        }
#pragma unroll
        for (int nf = 0; nf < 4; nf++) {
          int r = wn + nf * 16 + lr;
          bf[nf] = *(const h8*)(Bsm + r * 64 + (((kk * 4 + lg) ^ (r & 7)) * 8));
        }
#pragma unroll
        for (int mf = 0; mf < 4; mf++)
#pragma unroll
          for (int nf = 0; nf < 4; nf++)
            acc[mf][nf] = __builtin_amdgcn_mfma_f32_16x16x32_f16(af[mf], bf[nf], acc[mf][nf], 0, 0, 0);
      }
    }
#pragma unroll
    for (int nf = 0; nf < 4; nf++) {
      int col = nt * 128 + wn + nf * 16 + lr;
      float bv2 = Bc1[z * N + col];
#pragma unroll
      for (int mf = 0; mf < 4; mf++) {
#pragma unroll
        for (int rg = 0; rg < 4; rg++) {
          int row = mt * 128 + wm + mf * 16 + lg * 4 + rg;
          float v = fmaxf(acc[mf][nf][rg] + bv2, 0.f);
          Ob[(size_t)row * N + col] = (half_t)v;
        }
      }
    }
  } else if (bid < 576) {
    // ---- cos_freq ----
    int bb = bid - 512;
    int tensor = bb >> 5;
    int lb = bb & 31;
    const float* sg = simg + (size_t)tensor * 65536;
    const float* nb2 = n + tensor * 8192;
    float* out = tensor ? out_tea : out_stu;
    int l = lb >> 3, b = lb & 7;
    int a = tid & 7;
    for (int tc = 0; tc < 8; tc++) {
      int t = tc * 32 + (tid >> 3);
      float nb = nb2[lb * 256 + t] + REPS;
      float na = nb2[(l * 8 + a) * 256 + t] + REPS;
      float v = (sg[((size_t)lb * 256 + t) * 8 + a] / (nb * na) + 1.f) * 0.5f;
      float w = v;
      for (int m = 1; m < 8; m <<= 1) w += __shfl_xor(w, m);
      v /= w;
      size_t inner = ((size_t)(b * 256 + t)) * 8 + a;
      if (tensor == 0) {
#pragma unroll
        for (int j = 0; j < 4; j++) out[((size_t)(l * 4 + j)) * 16384 + inner] = v;
      } else {
#pragma unroll
        for (int i = 0; i < 4; i++) out[((size_t)(i * 4 + l)) * 16384 + inner] = v;
      }
    }
  } else {
    // ---- freq MLP (tensor0 = student -> fq, tensor1 = teacher -> fk) ----
    float* sw1 = (float*)smem;                 // 256
    float* sb1 = (float*)(smem + 1024);        // 32
    float* sw2 = (float*)(smem + 1152);        // 1024
    float* sb2 = (float*)(smem + 5248);        // 32
    float* zs  = (float*)(smem + 5376);        // [256][33]
    float* pcn = (float*)(smem + 39168);       // [8][33]
    float* cn  = (float*)(smem + 40224);       // 32
    int bb = bid - 576;
    int tensor = bb >> 5;
    int lb = bb & 31;
    int l = lb >> 3;
    const float* w1 = tensor ? kw1 : qw1;
    const float* b1 = tensor ? kb1 : qb1;
    const float* w2 = tensor ? kw2 : qw2;
    const float* b2 = tensor ? kb2 : qb2;
    const float* sg = simg + (size_t)tensor * 65536;
    float* outp = tensor ? kout : qout;
    int t = tid;
    sw1[t] = w1[l * 256 + t];
    if (t < 32) { sb1[t] = b1[l * 32 + t]; sb2[t] = b2[l * 32 + t]; }
    for (int q = t; q < 1024; q += 256) sw2[q] = w2[l * 1024 + q];
    __syncthreads();
    float x[8];
#pragma unroll
    for (int a = 0; a < 8; a++) x[a] = sg[((size_t)lb * 256 + t) * 8 + a];
    float h[32];
#pragma unroll
    for (int f = 0; f < 32; f++) {
      float acc = sb1[f];
#pragma unroll
      for (int a = 0; a < 8; a++) acc += x[a] * sw1[a * 32 + f];
      h[f] = fmaxf(acc, 0.f);
    }
#pragma unroll
    for (int g = 0; g < 32; g++) {
      float acc = sb2[g];
#pragma unroll
      for (int f = 0; f < 32; f++) acc += h[f] * sw2[f * 32 + g];
      zs[t * 33 + g] = acc;
    }
    __syncthreads();
    {
      int col = t & 31, ch = t >> 5;
      float sq = 0.f;
      for (int r = ch * 32; r < ch * 32 + 32; r++) { float v = zs[r * 33 + col]; sq += v * v; }
      pcn[ch * 33 + col] = sq;
    }
    __syncthreads();
    if (t < 32) {
      float ssum = 0.f;
#pragma unroll
      for (int c = 0; c < 8; c++) ssum += pcn[c * 33 + t];
      cn[t] = sqrtf(ssum);
    }
    __syncthreads();
#pragma unroll
    for (int g = 0; g < 32; g++)
      outp[((size_t)lb * 256 + t) * 32 + g] = zs[t * 33 + g] / cn[g];
  }
}

// ---------------------------------------------------------------------------
// k_mfma2: Z = hbuf @ W2t^T + b2, 128x128 tile, K=512, N=256, + column-sumsq.
// ---------------------------------------------------------------------------
__global__ __launch_bounds__(256) void k_mfma2(const half_t* __restrict__ A,
                                               const half_t* __restrict__ Bt,
                                               const float* __restrict__ bias,
                                               half_t* __restrict__ out,
                                               float* __restrict__ part) {
  constexpr int K = 512, N = 256;
  __shared__ __align__(16) half_t Asm[128 * 64];
  __shared__ __align__(16) half_t Bsm[128 * 64];
  int z = blockIdx.z;
  const half_t* Ab = A + (size_t)z * 2048 * 512;
  const half_t* Bb = Bt + (size_t)z * 256 * 512;
  half_t* Ob = out + (size_t)z * 2048 * 256;
  int mt = blockIdx.x, nt = blockIdx.y;
  int tid = threadIdx.x;
  int wave = tid >> 6, lane = tid & 63;
  int wm = (wave >> 1) * 64, wn = (wave & 1) * 64;
  int lr = lane & 15, lg = lane >> 4;
  f4 acc[4][4] = {};
  int r0 = tid >> 3, seg0 = tid & 7;
  int sw0 = (seg0 ^ (r0 & 7)) * 8;
  for (int kc = 0; kc < K; kc += 64) {
    h8 av[4], bv[4];
#pragma unroll
    for (int j = 0; j < 4; j++) {
      av[j] = *(const h8*)(Ab + (size_t)(mt * 128 + r0 + 32 * j) * K + kc + seg0 * 8);
      bv[j] = *(const h8*)(Bb + (size_t)(nt * 128 + r0 + 32 * j) * K + kc + seg0 * 8);
    }
    __syncthreads();
#pragma unroll
    for (int j = 0; j < 4; j++) {
      *(h8*)(Asm + (r0 + 32 * j) * 64 + sw0) = av[j];
      *(h8*)(Bsm + (r0 + 32 * j) * 64 + sw0) = bv[j];
    }
    __syncthreads();
#pragma unroll
    for (int kk = 0; kk < 2; kk++) {
      h8 af[4], bf[4];
#pragma unroll
      for (int mf = 0; mf < 4; mf++) {
        int r = wm + mf * 16 + lr;
        af[mf] = *(const h8*)(Asm + r * 64 + (((kk * 4 + lg) ^ (r & 7)) * 8));
      }
#pragma unroll
      for (int nf = 0; nf < 4; nf++) {
        int r = wn + nf * 16 + lr;
        bf[nf] = *(const h8*)(Bsm + r * 64 + (((kk * 4 + lg) ^ (r & 7)) * 8));
      }
#pragma unroll
      for (int mf = 0; mf < 4; mf++)
#pragma unroll
        for (int nf = 0; nf < 4; nf++)
          acc[mf][nf] = __builtin_amdgcn_mfma_f32_16x16x32_f16(af[mf], bf[nf], acc[mf][nf], 0, 0, 0);
    }
  }
#pragma unroll
  for (int nf = 0; nf < 4; nf++) {
    int col = nt * 128 + wn + nf * 16 + lr;
    float bv2 = bias[z * N + col];
    float colsq = 0.f;
#pragma unroll
    for (int mf = 0; mf < 4; mf++) {
#pragma unroll
      for (int rg = 0; rg < 4; rg++) {
        int row = mt * 128 + wm + mf * 16 + lg * 4 + rg;
        float v = acc[mf][nf][rg] + bv2;
        Ob[(size_t)row * N + col] = (half_t)v;
        colsq += v * v;
      }
    }
    colsq += __shfl_xor(colsq, 16);
    colsq += __shfl_xor(colsq, 32);
    if (lg == 0) {
      int b = mt >> 1;
      atomicAdd(&part[((z * 8 + b) << 8) + col], colsq);
    }
  }
}

// ---------------------------------------------------------------------------
// k_att: blocks 0-127 = time att (block = (b, 16 t's), 256 thr, LDS invnorms);
//        blocks 128-383 = freq att (4 pairs per block).
// ---------------------------------------------------------------------------
__global__ __launch_bounds__(256) void k_att(const half_t* __restrict__ Zq,
                                             const half_t* __restrict__ Zk,
                                             const float* __restrict__ part,
                                             const float* __restrict__ fq,
                                             const float* __restrict__ fk,
                                             float* __restrict__ out_time,
                                             float* __restrict__ out_freq) {
  __shared__ float invq[4][256], invk[4][256];
  int bid = blockIdx.x;
  int tid = threadIdx.x;
  if (bid < 128) {
    int b = bid >> 4, tc = bid & 15;
    for (int e = tid; e < 1024; e += 256) {
      int i = e >> 8, s = e & 255;
      invq[i][s] = rsqrtf(part[(((4 + i) * 8 + b) << 8) + s]);
      invk[i][s] = rsqrtf(part[((i * 8 + b) << 8) + s]);
    }
    __syncthreads();
    int w = tid >> 6, lane = tid & 63;
    int s0 = lane * 4;
#pragma unroll
    for (int tt = 0; tt < 4; tt++) {
      int t = tc * 16 + w * 4 + tt;
      float qv[4][4], kv[4][4];
#pragma unroll
      for (int i = 0; i < 4; i++) {
        size_t lbO = (size_t)(i * 8 + b);
        h4 qh = *(const h4*)(Zq + (lbO * 256 + t) * 256 + s0);
        h4 kh = *(const h4*)(Zk + (lbO * 256 + t) * 256 + s0);
#pragma unroll
        for (int e = 0; e < 4; e++) {
          qv[i][e] = (float)qh[e] * invq[i][s0 + e];
          kv[i][e] = (float)kh[e] * invk[i][s0 + e];
        }
      }
      float acc[4][4];
#pragma unroll
      for (int i = 0; i < 4; i++)
#pragma unroll
        for (int j = 0; j < 4; j++) {
          float a = 0.f;
#pragma unroll
          for (int e = 0; e < 4; e++) a += qv[i][e] * kv[j][e];
          acc[i][j] = a;
        }
#pragma unroll
      for (int i = 0; i < 4; i++)
#pragma unroll
        for (int j = 0; j < 4; j++)
          for (int m = 32; m >= 1; m >>= 1) acc[i][j] += __shfl_xor(acc[i][j], m);
      if (lane < 16) {
        int i = lane >> 2, j = lane & 3;
        float mx = fmaxf(fmaxf(acc[i][0], acc[i][1]), fmaxf(acc[i][2], acc[i][3]));
        float sum = expf(acc[i][0] - mx) + expf(acc[i][1] - mx) + expf(acc[i][2] - mx) + expf(acc[i][3] - mx);
        out_time[((size_t)(b * 256 + t)) * 16 + lane] = expf(acc[i][j] - mx) / sum;
      }
    }
  } else {
    int sub = tid >> 6, lane = tid & 63;
    int pair = (bid - 128) * 4 + sub;     // 0..1023
    int b = pair >> 7, tp = pair & 127;
    int t = tp * 2 + (lane >> 5);
    int f = lane & 31;
    float qv[4], kv[4];
#pragma unroll
    for (int i = 0; i < 4; i++) {
      size_t lbO = (size_t)(i * 8 + b);
      qv[i] = fq[(lbO * 256 + t) * 32 + f];
      kv[i] = fk[(lbO * 256 + t) * 32 + f];
    }
    float acc[4][4];
#pragma unroll
    for (int i = 0; i < 4; i++)
#pragma unroll
      for (int j = 0; j < 4; j++) acc[i][j] = qv[i] * kv[j];
#pragma unroll
    for (int i = 0; i < 4; i++)
#pragma unroll
      for (int j = 0; j < 4; j++)
        for (int m = 16; m >= 1; m >>= 1) acc[i][j] += __shfl_xor(acc[i][j], m);
    int fl = lane & 31;
    if (fl < 16) {
      int i = fl >> 2, j = fl & 3;
      float mx = fmaxf(fmaxf(acc[i][0], acc[i][1]), fmaxf(acc[i][2], acc[i][3]));
      float sum = expf(acc[i][0] - mx) + expf(acc[i][1] - mx) + expf(acc[i][2] - mx) + expf(acc[i][3] - mx);
      out_freq[((size_t)(b * 256 + t)) * 16 + fl] = expf(acc[i][j] - mx) / sum;
    }
  }
}

// ---------------------------------------------------------------------------
extern "C" void kernel_launch(void* const* d_in, const int* in_sizes, int n_in,
                              void* d_out, int out_size, void* d_ws, size_t ws_size,
                              hipStream_t stream) {
  (void)in_sizes; (void)n_in; (void)out_size; (void)ws_size;
  const float* feat_s = (const float*)d_in[0];
  const float* feat_t = (const float*)d_in[1];
  const float* tk_w1 = (const float*)d_in[2];
  const float* tk_b1 = (const float*)d_in[3];
  const float* tk_w2 = (const float*)d_in[4];
  const float* tk_b2 = (const float*)d_in[5];
  const float* fk_w1 = (const float*)d_in[6];
  const float* fk_b1 = (const float*)d_in[7];
  const float* fk_w2 = (const float*)d_in[8];
  const float* fk_b2 = (const float*)d_in[9];
  const float* tq_w1 = (const float*)d_in[10];
  const float* tq_b1 = (const float*)d_in[11];
  const float* tq_w2 = (const float*)d_in[12];
  const float* tq_b2 = (const float*)d_in[13];
  const float* fq_w1 = (const float*)d_in[14];
  const float* fq_b1 = (const float*)d_in[15];
  const float* fq_w2 = (const float*)d_in[16];
  const float* fq_b2 = (const float*)d_in[17];

  float* ws = (float*)d_ws;
  // Xh16 region (33.5MB); after k_gs consumes it, h and Z alias it.
  half_t* Xh   = (half_t*)ws;                 // 16.8M halves
  half_t* hbuf = (half_t*)ws;                 // 8*2048*512 halves (alias, after gram)
  half_t* Zbuf = (half_t*)(ws + 4194304);     // 8*2048*256 halves (alias, after gram)
  half_t* simh = (half_t*)(ws + 8388608);     // 64*65536 halves
  half_t* W1t  = (half_t*)(ws + 10485760);    // 8*512*256 halves
  half_t* W2t  = (half_t*)(ws + 11010048);    // 8*256*512 halves
  float* Bc1   = ws + 11534336;               // 8*512
  float* Bc2   = ws + 11538432;               // 8*256
  float* simg  = ws + 11540480;               // 2*65536
  float* nrm   = ws + 11671552;               // 2*8192
  float* part  = ws + 11687936;               // 8*8*256 = 16384 (colnorm sumsq)
  float* fkb   = ws + 11704320;               // 262144
  float* fqb   = ws + 11966464;               // 262144

  float* out = (float*)d_out;
  float* out_stu_time = out;               // [4,4,8,256,256]
  float* out_stu_freq = out + 8388608;     // [4,4,8,256,8]
  float* out_tea_time = out + 8650752;     // [4,4,8,256,256]
  float* out_tea_freq = out + 17039360;    // [4,4,8,256,8]
  float* out_time_att = out + 17301504;    // [8,256,4,4]
  float* out_freq_att = out + 17334272;    // [8,256,4,4]

  // 1) weights + feat transpose/convert + norms + zero part (fused)
  hipLaunchKernelGGL(k_prep2, dim3(769), dim3(256), 0, stream,
                     tk_w1, tq_w1, tk_w2, tq_w2, tk_b1, tq_b1, tk_b2, tq_b2,
                     W1t, W2t, Bc1, Bc2, part, feat_s, feat_t, Xh, nrm);
  // 2) time gram + cosine outputs fused, alongside freq gram (mixed blocks)
  hipLaunchKernelGGL(k_gs, dim3(768), dim3(512), 0, stream,
                     Xh, nrm, simh, out_stu_time, out_tea_time, simg);
  // 3) MLP GEMM1 alongside cos_freq + freq MLP (mixed blocks; h aliases Xh)
  hipLaunchKernelGGL(k_m1s, dim3(640), dim3(256), 0, stream,
                     simh, W1t, Bc1, hbuf, simg, nrm,
                     out_stu_freq, out_tea_freq,
                     fq_w1, fq_b1, fq_w2, fq_b2, fk_w1, fk_b1, fk_w2, fk_b2, fqb, fkb);
  // 4) MLP GEMM2 + fused column-sumsq atomics
  hipLaunchKernelGGL(k_mfma2, dim3(16, 2, 8), dim3(256), 0, stream,
                     hbuf, W2t, Bc2, Zbuf, part);
  // 5) attention (time: LDS invnorms + coalesced; freq: 4 pairs/block)
  hipLaunchKernelGGL(k_att, dim3(384), dim3(256), 0, stream,
                     Zbuf + (size_t)4 * 2048 * 256, Zbuf, part, fqb, fkb,
                     out_time_att, out_freq_att);
}